// Round 1
// baseline (1453.785 us; speedup 1.0000x reference)
//
#include <hip/hip_runtime.h>

#define N_NODES 100000
#define N_EDGES 1600000

// ---------------- graph prep ----------------
__global__ void k_hist(const int* __restrict__ ei, int* __restrict__ cnt) {
  int e = blockIdx.x * 256 + threadIdx.x;
  if (e < N_EDGES) atomicAdd(&cnt[ei[N_EDGES + e]], 1);
}

__global__ void k_dinv(const int* __restrict__ cnt, float* __restrict__ dinv) {
  int i = blockIdx.x * 256 + threadIdx.x;
  if (i < N_NODES) dinv[i] = rsqrtf((float)(cnt[i] + 1));  // +1 = appended self-loop
}

__global__ void k_scan_block(const int* __restrict__ cnt, int* __restrict__ rowoff,
                             int* __restrict__ bsum) {
  __shared__ int s[256];
  int t = threadIdx.x;
  int i = blockIdx.x * 256 + t;
  int v = (i < N_NODES) ? cnt[i] : 0;
  s[t] = v;
  __syncthreads();
  for (int off = 1; off < 256; off <<= 1) {
    int add = (t >= off) ? s[t - off] : 0;
    __syncthreads();
    s[t] += add;
    __syncthreads();
  }
  if (i < N_NODES) rowoff[i] = s[t] - v;       // exclusive
  if (t == 255) bsum[blockIdx.x] = s[255];     // block total
}

__global__ void k_scan_top(int* __restrict__ bsum, int nb) {
  __shared__ int s[512];
  int t = threadIdx.x;
  int v = (t < nb) ? bsum[t] : 0;
  s[t] = v;
  __syncthreads();
  for (int off = 1; off < 512; off <<= 1) {
    int add = (t >= off) ? s[t - off] : 0;
    __syncthreads();
    s[t] += add;
    __syncthreads();
  }
  if (t < nb) bsum[t] = s[t] - v;
}

__global__ void k_scan_add(int* __restrict__ rowoff, int* __restrict__ cursor,
                           const int* __restrict__ bsum) {
  int i = blockIdx.x * 256 + threadIdx.x;
  if (i < N_NODES) {
    int r = rowoff[i] + bsum[blockIdx.x];
    rowoff[i] = r;
    cursor[i] = r;
  }
}

__global__ void k_fill(const int* __restrict__ ei, int* __restrict__ cursor,
                       int* __restrict__ csr) {
  int e = blockIdx.x * 256 + threadIdx.x;
  if (e < N_EDGES) {
    int d = ei[N_EDGES + e];
    int p = atomicAdd(&cursor[d], 1);
    csr[p] = ei[e];
  }
}

// ---------------- conv1 aggregation: aggx = A_norm @ x   [N,21] ----------------
__global__ void k_aggx(const float* __restrict__ x, const float* __restrict__ dinv,
                       const int* __restrict__ rowoff, const int* __restrict__ cnt,
                       const int* __restrict__ csr, float* __restrict__ aggx) {
  int lane = threadIdx.x & 31;
  int i = blockIdx.x * 8 + (threadIdx.x >> 5);
  if (i >= N_NODES || lane >= 21) return;
  float di = dinv[i];
  float acc = di * di * x[i * 21 + lane];     // appended self-loop
  int start = rowoff[i], len = cnt[i];
  for (int e = 0; e < len; ++e) {
    int s = csr[start + e];
    acc += di * dinv[s] * x[s * 21 + lane];
  }
  aggx[i * 21 + lane] = acc;
}

// ---------------- gemm1: h1 = relu(aggx @ W1 + b1)   [N,256], K=21 ----------------
__global__ __launch_bounds__(256) void k_gemm1(const float* __restrict__ aggx,
                                               const float* __restrict__ W1,
                                               const float* __restrict__ b1,
                                               float* __restrict__ h1) {
  __shared__ float As[32][21];
  int t = threadIdx.x;
  int base = blockIdx.x * 32;           // 3125 * 32 == 100000 exactly
  for (int idx = t; idx < 32 * 21; idx += 256) {
    int m = idx / 21, k = idx - m * 21;
    As[m][k] = aggx[(base + m) * 21 + k];
  }
  float w[21];
#pragma unroll
  for (int k = 0; k < 21; ++k) w[k] = W1[k * 256 + t];
  float bias = b1[t];
  __syncthreads();
  for (int m = 0; m < 32; ++m) {
    float acc = bias;
#pragma unroll
    for (int k = 0; k < 21; ++k) acc = fmaf(As[m][k], w[k], acc);
    h1[(size_t)(base + m) * 256 + t] = fmaxf(acc, 0.f);
  }
}

// ---------------- generic fp32 GEMM: C[N,NOUT] = f(A)[N,K] @ W[K,NOUT] (+bias) ----
// f(A) optionally applies BN scale/shift + ReLU at A-staging time.
template <int K, int BK, int NOUT, int NPAD, bool BN>
__global__ __launch_bounds__(256) void k_gemm(const float* __restrict__ A,
                                              const float* __restrict__ W,
                                              const float* __restrict__ bias,
                                              const float* __restrict__ bn_a,
                                              const float* __restrict__ bn_c,
                                              float* __restrict__ C) {
  constexpr int TN = NPAD / 16;
  constexpr int BM = 64;
  constexpr int LDA = BK + 4;              // pad keeps float4 stores 16B-aligned, ~2-way banks
  constexpr bool STRIDED = (TN > 8);       // strided channels avoid 8-way conflicts at NPAD=256
  __shared__ float Ws[BK * NPAD];
  __shared__ float As[BM * LDA];
  const int tid = threadIdx.x;
  const int tx = tid & 15, ty = tid >> 4;
  const int rowbase = blockIdx.x * BM;

  float acc[4][TN];
#pragma unroll
  for (int l = 0; l < 4; ++l)
#pragma unroll
    for (int j = 0; j < TN; ++j) acc[l][j] = 0.f;

  for (int k0 = 0; k0 < K; k0 += BK) {
    const int kb = (K - k0 < BK) ? (K - k0) : BK;
    __syncthreads();
    // stage W chunk [kb][NPAD] (zero-padded channels)
    for (int idx = tid; idx < kb * NPAD; idx += 256) {
      int kk = idx / NPAD, c = idx - kk * NPAD;
      Ws[idx] = (c < NOUT) ? W[(k0 + kk) * NOUT + c] : 0.f;
    }
    // stage A chunk [BM][kb] node-major, float4, fused BN+ReLU
    const int q4 = kb >> 2;
    for (int idx = tid; idx < BM * q4; idx += 256) {
      int m = idx / q4, q = idx - m * q4;
      int gi = rowbase + m;
      float4 v = make_float4(0.f, 0.f, 0.f, 0.f);
      if (gi < N_NODES) {
        v = *(const float4*)(A + (size_t)gi * K + k0 + q * 4);
        if constexpr (BN) {
          float4 a4 = *(const float4*)(bn_a + k0 + q * 4);
          float4 c4 = *(const float4*)(bn_c + k0 + q * 4);
          v.x = fmaxf(fmaf(v.x, a4.x, c4.x), 0.f);
          v.y = fmaxf(fmaf(v.y, a4.y, c4.y), 0.f);
          v.z = fmaxf(fmaf(v.z, a4.z, c4.z), 0.f);
          v.w = fmaxf(fmaf(v.w, a4.w, c4.w), 0.f);
        }
      }
      *(float4*)(&As[m * LDA + q * 4]) = v;
    }
    __syncthreads();
#pragma unroll 2
    for (int kk = 0; kk < kb; ++kk) {
      float a0 = As[(ty * 4 + 0) * LDA + kk];
      float a1 = As[(ty * 4 + 1) * LDA + kk];
      float a2 = As[(ty * 4 + 2) * LDA + kk];
      float a3 = As[(ty * 4 + 3) * LDA + kk];
      const float* wrow = &Ws[kk * NPAD];
#pragma unroll
      for (int j = 0; j < TN; ++j) {
        int c = STRIDED ? (tx + 16 * j) : (tx * TN + j);
        float b = wrow[c];
        acc[0][j] = fmaf(a0, b, acc[0][j]);
        acc[1][j] = fmaf(a1, b, acc[1][j]);
        acc[2][j] = fmaf(a2, b, acc[2][j]);
        acc[3][j] = fmaf(a3, b, acc[3][j]);
      }
    }
  }
#pragma unroll
  for (int l = 0; l < 4; ++l) {
    int gi = rowbase + ty * 4 + l;
    if (gi >= N_NODES) continue;
#pragma unroll
    for (int j = 0; j < TN; ++j) {
      int c = STRIDED ? (tx + 16 * j) : (tx * TN + j);
      if (c < NOUT) {
        float v = acc[l][j];
        if (bias) v += bias[c];
        C[(size_t)gi * NOUT + c] = v;
      }
    }
  }
}

// ---------------- conv2 aggregation: g2 = A_norm @ t2 + b2   [N,112] -------------
__global__ void k_agg2(const float4* __restrict__ t2, const float* __restrict__ dinv,
                       const int* __restrict__ rowoff, const int* __restrict__ cnt,
                       const int* __restrict__ csr, const float* __restrict__ b2,
                       float4* __restrict__ g2) {
  int lane = threadIdx.x & 31;
  int i = blockIdx.x * 8 + (threadIdx.x >> 5);
  if (i >= N_NODES || lane >= 28) return;   // 28 float4 = 112 channels
  float di = dinv[i];
  float4 v = t2[i * 28 + lane];
  float f0 = di * di;
  float4 acc;
  acc.x = f0 * v.x; acc.y = f0 * v.y; acc.z = f0 * v.z; acc.w = f0 * v.w;
  int start = rowoff[i], len = cnt[i];
  for (int e = 0; e < len; ++e) {
    int s = csr[start + e];
    float f = di * dinv[s];
    float4 u = t2[s * 28 + lane];
    acc.x = fmaf(f, u.x, acc.x); acc.y = fmaf(f, u.y, acc.y);
    acc.z = fmaf(f, u.z, acc.z); acc.w = fmaf(f, u.w, acc.w);
  }
  float4 bb = ((const float4*)b2)[lane];
  acc.x += bb.x; acc.y += bb.y; acc.z += bb.z; acc.w += bb.w;
  g2[i * 28 + lane] = acc;
}

// ---------------- BN column stats ----------------
template <int C>
__global__ void k_colstats(const float* __restrict__ X, float* __restrict__ sums,
                           float* __restrict__ sqs) {
  int c = threadIdx.x;
  if (c >= C) return;
  int chunk = (N_NODES + gridDim.x - 1) / gridDim.x;
  int i0 = blockIdx.x * chunk;
  int i1 = min(N_NODES, i0 + chunk);
  float s = 0.f, q = 0.f;
  for (int i = i0; i < i1; ++i) {
    float v = X[(size_t)i * C + c];
    s += v;
    q = fmaf(v, v, q);
  }
  atomicAdd(&sums[c], s);
  atomicAdd(&sqs[c], q);
}

template <int C>
__global__ void k_bnfinal(const float* __restrict__ sums, const float* __restrict__ sqs,
                          const float* __restrict__ gamma, const float* __restrict__ beta,
                          float* __restrict__ bn_a, float* __restrict__ bn_c) {
  int c = threadIdx.x;
  if (c >= C) return;
  const float inv_n = 1.0f / (float)N_NODES;
  float mean = sums[c] * inv_n;
  float var = fmaxf(sqs[c] * inv_n - mean * mean, 0.f);
  float rstd = 1.0f / sqrtf(var + 1e-5f);
  float a = gamma[c] * rstd;
  bn_a[c] = a;
  bn_c[c] = beta[c] - mean * a;
}

// ---------------- final: out = relu(bn3(h4)) @ lin4_w + lin4_b ----------------
__global__ void k_final(const float* __restrict__ h4, const float* __restrict__ bn_a,
                        const float* __restrict__ bn_c, const float* __restrict__ w4,
                        const float* __restrict__ b4, float* __restrict__ out) {
  int lane = threadIdx.x & 63;
  int i = blockIdx.x * 4 + (threadIdx.x >> 6);   // 25000*4 == 100000 exactly
  float acc = fmaxf(fmaf(h4[(size_t)i * 100 + lane], bn_a[lane], bn_c[lane]), 0.f) * w4[lane];
  if (lane < 36) {
    int k = lane + 64;
    acc += fmaxf(fmaf(h4[(size_t)i * 100 + k], bn_a[k], bn_c[k]), 0.f) * w4[k];
  }
#pragma unroll
  for (int off = 32; off >= 1; off >>= 1) acc += __shfl_down(acc, off);
  if (lane == 0) out[i] = acc + b4[0];
}

extern "C" void kernel_launch(void* const* d_in, const int* in_sizes, int n_in,
                              void* d_out, int out_size, void* d_ws, size_t ws_size,
                              hipStream_t stream) {
  const float* x   = (const float*)d_in[0];
  const int*   ei  = (const int*)d_in[1];
  const float* W1  = (const float*)d_in[2];
  const float* b1  = (const float*)d_in[3];
  const float* W2  = (const float*)d_in[4];
  const float* b2  = (const float*)d_in[5];
  const float* l2w = (const float*)d_in[6];
  const float* l2b = (const float*)d_in[7];
  const float* l3w = (const float*)d_in[8];
  const float* l3b = (const float*)d_in[9];
  const float* l4w = (const float*)d_in[10];
  const float* l4b = (const float*)d_in[11];
  const float* g1  = (const float*)d_in[12];
  const float* be1 = (const float*)d_in[13];
  const float* g2w = (const float*)d_in[14];
  const float* be2 = (const float*)d_in[15];
  const float* g3  = (const float*)d_in[16];
  const float* be3 = (const float*)d_in[17];
  float* out = (float*)d_out;

  // ---- workspace carve-up (~209 MB total) ----
  char* base = (char*)d_ws;
  size_t off = 0;
  auto alloc = [&](size_t bytes) -> char* {
    char* p = base + off;
    off = (off + bytes + 255) & ~(size_t)255;
    return p;
  };
  int*   cnt    = (int*)alloc((size_t)N_NODES * 4);
  int*   rowoff = (int*)alloc((size_t)N_NODES * 4);
  int*   cursor = (int*)alloc((size_t)N_NODES * 4);
  int*   bsum   = (int*)alloc(512 * 4);
  float* dinv   = (float*)alloc((size_t)N_NODES * 4);
  int*   csr    = (int*)alloc((size_t)N_EDGES * 4);
  float* stats  = (float*)alloc(960 * 4);   // sums1,sqs1,sums2,sqs2,sums3,sqs3
  float* bnco   = (float*)alloc(960 * 4);   // a1,c1,a2,c2,a3,c3
  float* aggx   = (float*)alloc((size_t)N_NODES * 21 * 4);
  float* h1     = (float*)alloc((size_t)N_NODES * 256 * 4);  // reused as h3
  float* t2     = (float*)alloc((size_t)N_NODES * 112 * 4);  // reused as h4
  float* g2buf  = (float*)alloc((size_t)N_NODES * 112 * 4);

  float* sums1 = stats + 0,   *sqs1 = stats + 112;
  float* sums2 = stats + 224, *sqs2 = stats + 480;
  float* sums3 = stats + 736, *sqs3 = stats + 848;
  float* bn_a1 = bnco + 0,   *bn_c1 = bnco + 112;
  float* bn_a2 = bnco + 224, *bn_c2 = bnco + 480;
  float* bn_a3 = bnco + 736, *bn_c3 = bnco + 848;

  // zero the accumulating buffers (ws is poisoned 0xAA before every call)
  hipMemsetAsync(cnt, 0, (size_t)N_NODES * 4, stream);
  hipMemsetAsync(stats, 0, 960 * 4, stream);

  const int EB = (N_EDGES + 255) / 256;   // 6250
  const int NB = (N_NODES + 255) / 256;   // 391
  k_hist<<<EB, 256, 0, stream>>>(ei, cnt);
  k_dinv<<<NB, 256, 0, stream>>>(cnt, dinv);
  k_scan_block<<<NB, 256, 0, stream>>>(cnt, rowoff, bsum);
  k_scan_top<<<1, 512, 0, stream>>>(bsum, NB);
  k_scan_add<<<NB, 256, 0, stream>>>(rowoff, cursor, bsum);
  k_fill<<<EB, 256, 0, stream>>>(ei, cursor, csr);

  k_aggx<<<12500, 256, 0, stream>>>(x, dinv, rowoff, cnt, csr, aggx);
  k_gemm1<<<3125, 256, 0, stream>>>(aggx, W1, b1, h1);

  // t2 = h1 @ W2  (no bias; bias after aggregation)
  k_gemm<256, 64, 112, 112, false><<<1563, 256, 0, stream>>>(h1, W2, nullptr, nullptr, nullptr, t2);
  k_agg2<<<12500, 256, 0, stream>>>((const float4*)t2, dinv, rowoff, cnt, csr, b2, (float4*)g2buf);

  k_colstats<112><<<200, 128, 0, stream>>>(g2buf, sums1, sqs1);
  k_bnfinal<112><<<1, 128, 0, stream>>>(sums1, sqs1, g1, be1, bn_a1, bn_c1);

  // h3 = relu(bn1(g2)) @ lin2_w + lin2_b   (BN+ReLU fused in A-staging)
  k_gemm<112, 32, 256, 256, true><<<1563, 256, 0, stream>>>(g2buf, l2w, l2b, bn_a1, bn_c1, h1);
  k_colstats<256><<<200, 256, 0, stream>>>(h1, sums2, sqs2);
  k_bnfinal<256><<<1, 256, 0, stream>>>(sums2, sqs2, g2w, be2, bn_a2, bn_c2);

  // h4 = relu(bn2(h3)) @ lin3_w + lin3_b
  k_gemm<256, 64, 100, 112, true><<<1563, 256, 0, stream>>>(h1, l3w, l3b, bn_a2, bn_c2, t2);
  k_colstats<100><<<200, 128, 0, stream>>>(t2, sums3, sqs3);
  k_bnfinal<100><<<1, 128, 0, stream>>>(sums3, sqs3, g3, be3, bn_a3, bn_c3);

  k_final<<<25000, 256, 0, stream>>>(t2, bn_a3, bn_c3, l4w, l4b, out);
}

// Round 2
// 951.917 us; speedup vs baseline: 1.5272x; 1.5272x over previous
//
#include <hip/hip_runtime.h>

#define N_NODES 100000
#define N_EDGES 1600000

typedef _Float16 f16x8 __attribute__((ext_vector_type(8)));
typedef _Float16 f16x4 __attribute__((ext_vector_type(4)));
typedef float fx4 __attribute__((ext_vector_type(4)));

// ---------------- graph prep ----------------
__global__ void k_hist(const int* __restrict__ ei, int* __restrict__ cnt) {
  int e = blockIdx.x * 256 + threadIdx.x;
  if (e < N_EDGES) atomicAdd(&cnt[ei[N_EDGES + e]], 1);
}

__global__ void k_dinv(const int* __restrict__ cnt, float* __restrict__ dinv) {
  int i = blockIdx.x * 256 + threadIdx.x;
  if (i < N_NODES) dinv[i] = rsqrtf((float)(cnt[i] + 1));  // +1 = appended self-loop
}

__global__ void k_scan_block(const int* __restrict__ cnt, int* __restrict__ rowoff,
                             int* __restrict__ bsum) {
  __shared__ int s[256];
  int t = threadIdx.x;
  int i = blockIdx.x * 256 + t;
  int v = (i < N_NODES) ? cnt[i] : 0;
  s[t] = v;
  __syncthreads();
  for (int off = 1; off < 256; off <<= 1) {
    int add = (t >= off) ? s[t - off] : 0;
    __syncthreads();
    s[t] += add;
    __syncthreads();
  }
  if (i < N_NODES) rowoff[i] = s[t] - v;       // exclusive
  if (t == 255) bsum[blockIdx.x] = s[255];     // block total
}

__global__ void k_scan_top(int* __restrict__ bsum, int nb) {
  __shared__ int s[512];
  int t = threadIdx.x;
  int v = (t < nb) ? bsum[t] : 0;
  s[t] = v;
  __syncthreads();
  for (int off = 1; off < 512; off <<= 1) {
    int add = (t >= off) ? s[t - off] : 0;
    __syncthreads();
    s[t] += add;
    __syncthreads();
  }
  if (t < nb) bsum[t] = s[t] - v;
}

__global__ void k_scan_add(int* __restrict__ rowoff, int* __restrict__ cursor,
                           const int* __restrict__ bsum) {
  int i = blockIdx.x * 256 + threadIdx.x;
  if (i < N_NODES) {
    int r = rowoff[i] + bsum[blockIdx.x];
    rowoff[i] = r;
    cursor[i] = r;
  }
}

__global__ void k_fill(const int* __restrict__ ei, int* __restrict__ cursor,
                       int* __restrict__ csr) {
  int e = blockIdx.x * 256 + threadIdx.x;
  if (e < N_EDGES) {
    int d = ei[N_EDGES + e];
    int p = atomicAdd(&cursor[d], 1);
    csr[p] = ei[e];
  }
}

// ---------------- conv1 aggregation: aggx = A_norm @ x   [N,21] ----------------
__global__ void k_aggx(const float* __restrict__ x, const float* __restrict__ dinv,
                       const int* __restrict__ rowoff, const int* __restrict__ cnt,
                       const int* __restrict__ csr, float* __restrict__ aggx) {
  int lane = threadIdx.x & 31;
  int i = blockIdx.x * 8 + (threadIdx.x >> 5);
  if (i >= N_NODES || lane >= 21) return;
  float di = dinv[i];
  float acc = di * di * x[i * 21 + lane];     // appended self-loop
  int start = rowoff[i], len = cnt[i];
  for (int e = 0; e < len; ++e) {
    int s = csr[start + e];
    acc += di * dinv[s] * x[s * 21 + lane];
  }
  aggx[i * 21 + lane] = acc;
}

// ---------------- gemm1: h1 = relu(aggx @ W1 + b1)   [N,256], K=21 ----------------
__global__ __launch_bounds__(256) void k_gemm1(const float* __restrict__ aggx,
                                               const float* __restrict__ W1,
                                               const float* __restrict__ b1,
                                               float* __restrict__ h1) {
  __shared__ float As[32][21];
  int t = threadIdx.x;
  int base = blockIdx.x * 32;           // 3125 * 32 == 100000 exactly
  for (int idx = t; idx < 32 * 21; idx += 256) {
    int m = idx / 21, k = idx - m * 21;
    As[m][k] = aggx[(base + m) * 21 + k];
  }
  float w[21];
#pragma unroll
  for (int k = 0; k < 21; ++k) w[k] = W1[k * 256 + t];
  float bias = b1[t];
  __syncthreads();
  for (int m = 0; m < 32; ++m) {
    float acc = bias;
#pragma unroll
    for (int k = 0; k < 21; ++k) acc = fmaf(As[m][k], w[k], acc);
    h1[(size_t)(base + m) * 256 + t] = fmaxf(acc, 0.f);
  }
}

// ---------------- W prep: split fp32 W[k][n] -> transposed f16 hi/lo Wt[n][kpad] ---
template <int K, int KPAD, int NOUT, int NR>
__global__ void k_wsplit(const float* __restrict__ W, _Float16* __restrict__ Wh,
                         _Float16* __restrict__ Wl) {
  int idx = blockIdx.x * 256 + threadIdx.x;
  if (idx >= NR * KPAD) return;
  int n = idx / KPAD, k = idx % KPAD;
  float v = (n < NOUT && k < K) ? W[k * NOUT + n] : 0.f;
  _Float16 h = (_Float16)v;              // RNE
  Wh[idx] = h;
  Wl[idx] = (_Float16)(v - (float)h);
}

// ---------------- MFMA GEMM: C = f(A)[N,K] @ W[K,NOUT] (+bias), split-f16 -------
// f(A) = optional BN scale/shift + ReLU fused at A-staging. STATS fuses the
// per-column sum/sumsq pass (BN input stats of C) into the epilogue.
// Layouts (m89-verified): A-frag A[m=lane&15][k=quad*8+j] from LDS row-major
// [m][k]; B-frag B[k][n=lane&15] from LDS transposed Wt[n][k]; C/D col=lane&15,
// row=quad*4+reg. Row stride BKP=40 f16 (80 B = 20 banks -> 2-way, free).
template <int K, int KPAD, int NT, int MT, bool BN, bool STATS>
__global__ __launch_bounds__(256) void k_mgemm(
    const float* __restrict__ A, const _Float16* __restrict__ Wth,
    const _Float16* __restrict__ Wtl, const float* __restrict__ bias,
    const float* __restrict__ bn_a, const float* __restrict__ bn_c,
    float* __restrict__ C, int NOUTr, float* __restrict__ sums,
    float* __restrict__ sqs) {
  constexpr int BM = MT * 64;            // 4 waves * MT m-tiles * 16 rows
  constexpr int BKP = 40;                // 32 + 8 pad
  constexpr int NR = NT * 16;
  constexpr int ABYTES = BM * BKP * 2;
  constexpr int BBYTES = NR * BKP * 2;
  __shared__ __align__(16) char smem[2 * ABYTES + 2 * BBYTES];
  _Float16* Ah = (_Float16*)smem;
  _Float16* Al = (_Float16*)(smem + ABYTES);
  _Float16* Bh = (_Float16*)(smem + 2 * ABYTES);
  _Float16* Bl = (_Float16*)(smem + 2 * ABYTES + BBYTES);

  const int tid = threadIdx.x;
  const int lane = tid & 63, wave = tid >> 6;
  const int quad = lane >> 4, ln = lane & 15;
  const int rowbase = blockIdx.x * BM;

  fx4 acc[MT][NT];
#pragma unroll
  for (int mt = 0; mt < MT; ++mt)
#pragma unroll
    for (int j = 0; j < NT; ++j) acc[mt][j] = (fx4){0.f, 0.f, 0.f, 0.f};

  for (int kc = 0; kc < KPAD / 32; ++kc) {
    __syncthreads();
    // stage A chunk: fp32 -> (BN+ReLU) -> f16 hi/lo
    for (int idx = tid; idx < BM * 8; idx += 256) {
      int m = idx >> 3, q = idx & 7;
      int gi = rowbase + m;
      int k = kc * 32 + q * 4;
      float vv[4] = {0.f, 0.f, 0.f, 0.f};
      if (gi < N_NODES && k < K) {
        float4 v = *(const float4*)(A + (size_t)gi * K + k);
        if constexpr (BN) {
          float4 a4 = *(const float4*)(bn_a + k);
          float4 c4 = *(const float4*)(bn_c + k);
          v.x = fmaxf(fmaf(v.x, a4.x, c4.x), 0.f);
          v.y = fmaxf(fmaf(v.y, a4.y, c4.y), 0.f);
          v.z = fmaxf(fmaf(v.z, a4.z, c4.z), 0.f);
          v.w = fmaxf(fmaf(v.w, a4.w, c4.w), 0.f);
        }
        vv[0] = v.x; vv[1] = v.y; vv[2] = v.z; vv[3] = v.w;
      }
      f16x4 hi, lo;
#pragma unroll
      for (int t = 0; t < 4; ++t) {
        _Float16 h = (_Float16)vv[t];
        hi[t] = h;
        lo[t] = (_Float16)(vv[t] - (float)h);
      }
      *(f16x4*)(Ah + m * BKP + q * 4) = hi;
      *(f16x4*)(Al + m * BKP + q * 4) = lo;
    }
    // stage W tiles (pre-split, pre-transposed, zero-padded)
    for (int idx = tid; idx < NR * 4; idx += 256) {
      int n = idx >> 2, p = idx & 3;
      int src = n * KPAD + kc * 32 + p * 8;
      *(f16x8*)(Bh + n * BKP + p * 8) = *(const f16x8*)(Wth + src);
      *(f16x8*)(Bl + n * BKP + p * 8) = *(const f16x8*)(Wtl + src);
    }
    __syncthreads();
    f16x8 ah[MT], al[MT];
#pragma unroll
    for (int mt = 0; mt < MT; ++mt) {
      int r = wave * MT * 16 + mt * 16 + ln;
      ah[mt] = *(const f16x8*)(Ah + r * BKP + quad * 8);
      al[mt] = *(const f16x8*)(Al + r * BKP + quad * 8);
    }
#pragma unroll
    for (int j = 0; j < NT; ++j) {
      f16x8 bh = *(const f16x8*)(Bh + (j * 16 + ln) * BKP + quad * 8);
      f16x8 bl = *(const f16x8*)(Bl + (j * 16 + ln) * BKP + quad * 8);
#pragma unroll
      for (int mt = 0; mt < MT; ++mt)
        acc[mt][j] = __builtin_amdgcn_mfma_f32_16x16x32_f16(ah[mt], bh, acc[mt][j], 0, 0, 0);
#pragma unroll
      for (int mt = 0; mt < MT; ++mt)
        acc[mt][j] = __builtin_amdgcn_mfma_f32_16x16x32_f16(al[mt], bh, acc[mt][j], 0, 0, 0);
#pragma unroll
      for (int mt = 0; mt < MT; ++mt)
        acc[mt][j] = __builtin_amdgcn_mfma_f32_16x16x32_f16(ah[mt], bl, acc[mt][j], 0, 0, 0);
    }
  }

  // epilogue: bias add, store, fused per-column stats partials
  float scA[NT], sqA[NT];
#pragma unroll
  for (int j = 0; j < NT; ++j) {
    int col = j * 16 + ln;
    float bs = (bias != nullptr && col < NOUTr) ? bias[col] : 0.f;
    float sc = 0.f, sq = 0.f;
#pragma unroll
    for (int mt = 0; mt < MT; ++mt) {
      int rb = rowbase + wave * MT * 16 + mt * 16 + quad * 4;
#pragma unroll
      for (int r = 0; r < 4; ++r) {
        int gi = rb + r;
        if (gi < N_NODES && col < NOUTr) {
          float v = acc[mt][j][r] + bs;
          C[(size_t)gi * NOUTr + col] = v;
          sc += v;
          sq = fmaf(v, v, sq);
        }
      }
    }
    scA[j] = sc;
    sqA[j] = sq;
  }
  if constexpr (STATS) {
    float* s_s = (float*)smem;           // reuse A region (safe after barrier)
    float* s_q = s_s + 4 * NR;
    __syncthreads();
#pragma unroll
    for (int j = 0; j < NT; ++j) {
      float sc = scA[j], sq = sqA[j];
      sc += __shfl_xor(sc, 16); sq += __shfl_xor(sq, 16);
      sc += __shfl_xor(sc, 32); sq += __shfl_xor(sq, 32);
      if (quad == 0) {
        s_s[wave * NR + j * 16 + ln] = sc;
        s_q[wave * NR + j * 16 + ln] = sq;
      }
    }
    __syncthreads();
    for (int c = tid; c < NR; c += 256) {
      if (c < NOUTr) {
        atomicAdd(&sums[c], s_s[c] + s_s[NR + c] + s_s[2 * NR + c] + s_s[3 * NR + c]);
        atomicAdd(&sqs[c], s_q[c] + s_q[NR + c] + s_q[2 * NR + c] + s_q[3 * NR + c]);
      }
    }
  }
}

// ---------------- conv2 aggregation: g2 = A_norm @ t2 + b2   [N,112] -------------
__global__ void k_agg2(const float4* __restrict__ t2, const float* __restrict__ dinv,
                       const int* __restrict__ rowoff, const int* __restrict__ cnt,
                       const int* __restrict__ csr, const float* __restrict__ b2,
                       float4* __restrict__ g2) {
  int lane = threadIdx.x & 31;
  int i = blockIdx.x * 8 + (threadIdx.x >> 5);
  if (i >= N_NODES || lane >= 28) return;   // 28 float4 = 112 channels
  float di = dinv[i];
  float4 v = t2[i * 28 + lane];
  float f0 = di * di;
  float4 acc;
  acc.x = f0 * v.x; acc.y = f0 * v.y; acc.z = f0 * v.z; acc.w = f0 * v.w;
  int start = rowoff[i], len = cnt[i];
  for (int e = 0; e < len; ++e) {
    int s = csr[start + e];
    float f = di * dinv[s];
    float4 u = t2[s * 28 + lane];
    acc.x = fmaf(f, u.x, acc.x); acc.y = fmaf(f, u.y, acc.y);
    acc.z = fmaf(f, u.z, acc.z); acc.w = fmaf(f, u.w, acc.w);
  }
  float4 bb = ((const float4*)b2)[lane];
  acc.x += bb.x; acc.y += bb.y; acc.z += bb.z; acc.w += bb.w;
  g2[i * 28 + lane] = acc;
}

// ---------------- BN column stats (standalone, for g2) ----------------
template <int C>
__global__ void k_colstats(const float* __restrict__ X, float* __restrict__ sums,
                           float* __restrict__ sqs) {
  int c = threadIdx.x;
  if (c >= C) return;
  int chunk = (N_NODES + gridDim.x - 1) / gridDim.x;
  int i0 = blockIdx.x * chunk;
  int i1 = min(N_NODES, i0 + chunk);
  float s = 0.f, q = 0.f;
  for (int i = i0; i < i1; ++i) {
    float v = X[(size_t)i * C + c];
    s += v;
    q = fmaf(v, v, q);
  }
  atomicAdd(&sums[c], s);
  atomicAdd(&sqs[c], q);
}

template <int C>
__global__ void k_bnfinal(const float* __restrict__ sums, const float* __restrict__ sqs,
                          const float* __restrict__ gamma, const float* __restrict__ beta,
                          float* __restrict__ bn_a, float* __restrict__ bn_c) {
  int c = threadIdx.x;
  if (c >= C) return;
  const float inv_n = 1.0f / (float)N_NODES;
  float mean = sums[c] * inv_n;
  float var = fmaxf(sqs[c] * inv_n - mean * mean, 0.f);
  float rstd = 1.0f / sqrtf(var + 1e-5f);
  float a = gamma[c] * rstd;
  bn_a[c] = a;
  bn_c[c] = beta[c] - mean * a;
}

// ---------------- final: out = relu(bn3(h4)) @ lin4_w + lin4_b ----------------
__global__ void k_final(const float* __restrict__ h4, const float* __restrict__ bn_a,
                        const float* __restrict__ bn_c, const float* __restrict__ w4,
                        const float* __restrict__ b4, float* __restrict__ out) {
  int lane = threadIdx.x & 63;
  int i = blockIdx.x * 4 + (threadIdx.x >> 6);   // 25000*4 == 100000 exactly
  float acc = fmaxf(fmaf(h4[(size_t)i * 100 + lane], bn_a[lane], bn_c[lane]), 0.f) * w4[lane];
  if (lane < 36) {
    int k = lane + 64;
    acc += fmaxf(fmaf(h4[(size_t)i * 100 + k], bn_a[k], bn_c[k]), 0.f) * w4[k];
  }
#pragma unroll
  for (int off = 32; off >= 1; off >>= 1) acc += __shfl_down(acc, off);
  if (lane == 0) out[i] = acc + b4[0];
}

extern "C" void kernel_launch(void* const* d_in, const int* in_sizes, int n_in,
                              void* d_out, int out_size, void* d_ws, size_t ws_size,
                              hipStream_t stream) {
  const float* x   = (const float*)d_in[0];
  const int*   ei  = (const int*)d_in[1];
  const float* W1  = (const float*)d_in[2];
  const float* b1  = (const float*)d_in[3];
  const float* W2  = (const float*)d_in[4];
  const float* b2  = (const float*)d_in[5];
  const float* l2w = (const float*)d_in[6];
  const float* l2b = (const float*)d_in[7];
  const float* l3w = (const float*)d_in[8];
  const float* l3b = (const float*)d_in[9];
  const float* l4w = (const float*)d_in[10];
  const float* l4b = (const float*)d_in[11];
  const float* g1  = (const float*)d_in[12];
  const float* be1 = (const float*)d_in[13];
  const float* g2w = (const float*)d_in[14];
  const float* be2 = (const float*)d_in[15];
  const float* g3  = (const float*)d_in[16];
  const float* be3 = (const float*)d_in[17];
  float* out = (float*)d_out;

  // ---- workspace carve-up ----
  char* base = (char*)d_ws;
  size_t off = 0;
  auto alloc = [&](size_t bytes) -> char* {
    char* p = base + off;
    off = (off + bytes + 255) & ~(size_t)255;
    return p;
  };
  int*   cnt    = (int*)alloc((size_t)N_NODES * 4);
  int*   rowoff = (int*)alloc((size_t)N_NODES * 4);
  int*   cursor = (int*)alloc((size_t)N_NODES * 4);
  int*   bsum   = (int*)alloc(512 * 4);
  float* dinv   = (float*)alloc((size_t)N_NODES * 4);
  int*   csr    = (int*)alloc((size_t)N_EDGES * 4);
  float* stats  = (float*)alloc(960 * 4);   // sums1,sqs1,sums2,sqs2,sums3,sqs3
  float* bnco   = (float*)alloc(960 * 4);   // a1,c1,a2,c2,a3,c3
  float* aggx   = (float*)alloc((size_t)N_NODES * 21 * 4);
  float* h1     = (float*)alloc((size_t)N_NODES * 256 * 4);  // reused as h3
  float* t2     = (float*)alloc((size_t)N_NODES * 112 * 4);  // reused as h4
  float* g2buf  = (float*)alloc((size_t)N_NODES * 112 * 4);
  _Float16* wt2h = (_Float16*)alloc(112 * 256 * 2);
  _Float16* wt2l = (_Float16*)alloc(112 * 256 * 2);
  _Float16* wt3h = (_Float16*)alloc(256 * 128 * 2);
  _Float16* wt3l = (_Float16*)alloc(256 * 128 * 2);
  _Float16* wt4h = (_Float16*)alloc(112 * 256 * 2);
  _Float16* wt4l = (_Float16*)alloc(112 * 256 * 2);

  float* sums1 = stats + 0,   *sqs1 = stats + 112;
  float* sums2 = stats + 224, *sqs2 = stats + 480;
  float* sums3 = stats + 736, *sqs3 = stats + 848;
  float* bn_a1 = bnco + 0,   *bn_c1 = bnco + 112;
  float* bn_a2 = bnco + 224, *bn_c2 = bnco + 480;
  float* bn_a3 = bnco + 736, *bn_c3 = bnco + 848;

  hipMemsetAsync(cnt, 0, (size_t)N_NODES * 4, stream);
  hipMemsetAsync(stats, 0, 960 * 4, stream);

  const int EB = (N_EDGES + 255) / 256;   // 6250
  const int NB = (N_NODES + 255) / 256;   // 391
  k_hist<<<EB, 256, 0, stream>>>(ei, cnt);
  k_dinv<<<NB, 256, 0, stream>>>(cnt, dinv);
  k_scan_block<<<NB, 256, 0, stream>>>(cnt, rowoff, bsum);
  k_scan_top<<<1, 512, 0, stream>>>(bsum, NB);
  k_scan_add<<<NB, 256, 0, stream>>>(rowoff, cursor, bsum);
  k_fill<<<EB, 256, 0, stream>>>(ei, cursor, csr);

  // W splits (independent, tiny)
  k_wsplit<256, 256, 112, 112><<<112, 256, 0, stream>>>(W2, wt2h, wt2l);
  k_wsplit<112, 128, 256, 256><<<128, 256, 0, stream>>>(l2w, wt3h, wt3l);
  k_wsplit<256, 256, 100, 112><<<112, 256, 0, stream>>>(l3w, wt4h, wt4l);

  k_aggx<<<12500, 256, 0, stream>>>(x, dinv, rowoff, cnt, csr, aggx);
  k_gemm1<<<3125, 256, 0, stream>>>(aggx, W1, b1, h1);

  // t2 = h1 @ W2  (no bias/BN/stats)
  k_mgemm<256, 256, 7, 4, false, false><<<391, 256, 0, stream>>>(
      h1, wt2h, wt2l, nullptr, nullptr, nullptr, t2, 112, nullptr, nullptr);
  k_agg2<<<12500, 256, 0, stream>>>((const float4*)t2, dinv, rowoff, cnt, csr, b2,
                                    (float4*)g2buf);

  k_colstats<112><<<200, 128, 0, stream>>>(g2buf, sums1, sqs1);
  k_bnfinal<112><<<1, 128, 0, stream>>>(sums1, sqs1, g1, be1, bn_a1, bn_c1);

  // h3 = relu(bn1(g2)) @ lin2_w + lin2_b, stats(h3) fused
  k_mgemm<112, 128, 16, 2, true, true><<<782, 256, 0, stream>>>(
      g2buf, wt3h, wt3l, l2b, bn_a1, bn_c1, h1, 256, sums2, sqs2);
  k_bnfinal<256><<<1, 256, 0, stream>>>(sums2, sqs2, g2w, be2, bn_a2, bn_c2);

  // h4 = relu(bn2(h3)) @ lin3_w + lin3_b, stats(h4) fused
  k_mgemm<256, 256, 7, 4, true, true><<<391, 256, 0, stream>>>(
      h1, wt4h, wt4l, l3b, bn_a2, bn_c2, t2, 100, sums3, sqs3);
  k_bnfinal<100><<<1, 128, 0, stream>>>(sums3, sqs3, g3, be3, bn_a3, bn_c3);

  k_final<<<25000, 256, 0, stream>>>(t2, bn_a3, bn_c3, l4w, l4b, out);
}

// Round 4
// 795.492 us; speedup vs baseline: 1.8275x; 1.1966x over previous
//
#include <hip/hip_runtime.h>

#define N_NODES 100000
#define N_EDGES 1600000

typedef _Float16 f16x8 __attribute__((ext_vector_type(8)));
typedef _Float16 f16x4 __attribute__((ext_vector_type(4)));
typedef float fx4 __attribute__((ext_vector_type(4)));

#define NREP 16   // stats-accumulator replication to de-contend atomics

// ---------------- graph prep ----------------
__global__ void k_hist(const int* __restrict__ ei, int* __restrict__ cnt) {
  int e = blockIdx.x * 256 + threadIdx.x;
  if (e < N_EDGES) atomicAdd(&cnt[ei[N_EDGES + e]], 1);
}

__global__ void k_dinv(const int* __restrict__ cnt, float* __restrict__ dinv) {
  int i = blockIdx.x * 256 + threadIdx.x;
  if (i < N_NODES) dinv[i] = rsqrtf((float)(cnt[i] + 1));  // +1 = appended self-loop
}

__global__ void k_scan_block(const int* __restrict__ cnt, int* __restrict__ rowoff,
                             int* __restrict__ bsum) {
  __shared__ int s[256];
  int t = threadIdx.x;
  int i = blockIdx.x * 256 + t;
  int v = (i < N_NODES) ? cnt[i] : 0;
  s[t] = v;
  __syncthreads();
  for (int off = 1; off < 256; off <<= 1) {
    int add = (t >= off) ? s[t - off] : 0;
    __syncthreads();
    s[t] += add;
    __syncthreads();
  }
  if (i < N_NODES) rowoff[i] = s[t] - v;       // exclusive
  if (t == 255) bsum[blockIdx.x] = s[255];     // block total
}

__global__ void k_scan_top(int* __restrict__ bsum, int nb) {
  __shared__ int s[512];
  int t = threadIdx.x;
  int v = (t < nb) ? bsum[t] : 0;
  s[t] = v;
  __syncthreads();
  for (int off = 1; off < 512; off <<= 1) {
    int add = (t >= off) ? s[t - off] : 0;
    __syncthreads();
    s[t] += add;
    __syncthreads();
  }
  if (t < nb) bsum[t] = s[t] - v;
}

__global__ void k_scan_add(int* __restrict__ rowoff, int* __restrict__ cursor,
                           const int* __restrict__ bsum) {
  int i = blockIdx.x * 256 + threadIdx.x;
  if (i < N_NODES) {
    int r = rowoff[i] + bsum[blockIdx.x];
    rowoff[i] = r;
    cursor[i] = r;
  }
}

__global__ void k_fill(const int* __restrict__ ei, int* __restrict__ cursor,
                       int* __restrict__ csr) {
  int e = blockIdx.x * 256 + threadIdx.x;
  if (e < N_EDGES) {
    int d = ei[N_EDGES + e];
    int p = atomicAdd(&cursor[d], 1);
    csr[p] = ei[e];
  }
}

// ---------------- conv1 aggregation: aggx = A_norm @ x   [N,21] ----------------
__global__ void k_aggx(const float* __restrict__ x, const float* __restrict__ dinv,
                       const int* __restrict__ rowoff, const int* __restrict__ cnt,
                       const int* __restrict__ csr, float* __restrict__ aggx) {
  int lane = threadIdx.x & 31;
  int i = blockIdx.x * 8 + (threadIdx.x >> 5);
  if (i >= N_NODES || lane >= 21) return;
  float di = dinv[i];
  float acc0 = di * di * x[i * 21 + lane];     // appended self-loop
  float acc1 = 0.f;
  int start = rowoff[i], len = cnt[i];
  int e = 0;
  for (; e + 1 < len; e += 2) {
    int s0 = csr[start + e], s1 = csr[start + e + 1];
    float f0 = di * dinv[s0], f1 = di * dinv[s1];
    acc0 = fmaf(f0, x[s0 * 21 + lane], acc0);
    acc1 = fmaf(f1, x[s1 * 21 + lane], acc1);
  }
  if (e < len) {
    int s0 = csr[start + e];
    acc0 = fmaf(di * dinv[s0], x[s0 * 21 + lane], acc0);
  }
  aggx[i * 21 + lane] = acc0 + acc1;
}

// ---------------- gemm1: h1 = relu(aggx @ W1 + b1)   [N,256], K=21 ----------------
__global__ __launch_bounds__(256) void k_gemm1(const float* __restrict__ aggx,
                                               const float* __restrict__ W1,
                                               const float* __restrict__ b1,
                                               float* __restrict__ h1) {
  __shared__ float As[32][21];
  int t = threadIdx.x;
  int base = blockIdx.x * 32;           // 3125 * 32 == 100000 exactly
  for (int idx = t; idx < 32 * 21; idx += 256) {
    int m = idx / 21, k = idx - m * 21;
    As[m][k] = aggx[(base + m) * 21 + k];
  }
  float w[21];
#pragma unroll
  for (int k = 0; k < 21; ++k) w[k] = W1[k * 256 + t];
  float bias = b1[t];
  __syncthreads();
  for (int m = 0; m < 32; ++m) {
    float acc = bias;
#pragma unroll
    for (int k = 0; k < 21; ++k) acc = fmaf(As[m][k], w[k], acc);
    h1[(size_t)(base + m) * 256 + t] = fmaxf(acc, 0.f);
  }
}

// ---------------- W prep: split fp32 W[k][n] -> transposed f16 hi/lo Wt[n][kpad] ---
template <int K, int KPAD, int NOUT, int NR>
__global__ void k_wsplit(const float* __restrict__ W, _Float16* __restrict__ Wh,
                         _Float16* __restrict__ Wl) {
  int idx = blockIdx.x * 256 + threadIdx.x;
  if (idx >= NR * KPAD) return;
  int n = idx / KPAD, k = idx % KPAD;
  float v = (n < NOUT && k < K) ? W[k * NOUT + n] : 0.f;
  _Float16 h = (_Float16)v;              // RNE
  Wh[idx] = h;
  Wl[idx] = (_Float16)(v - (float)h);
}

// ---------------- MFMA GEMM: C = f(A)[N,K] @ W[K,NOUT] (+bias), split-f16 -------
// Waves arranged WR x WC over the block tile; per-wave acc = MT*NT*4 regs.
// R2 post-mortem: acc[2][16]=128 regs -> 1 wave/SIMD occupancy cliff. Keep
// MT*NT <= 16 so acc <= 64 and 3+ blocks/CU co-reside.
// R3 bug (fixed): stats flush must use stride NOUTr (consumer k_bnfinal<C>
// reads rep*C + c), NOT the padded NR.
template <int K, int KPAD, int NT, int MT, int WR, int WC, bool BN, bool STATS>
__global__ __launch_bounds__(256, 3) void k_mgemm(
    const float* __restrict__ A, const _Float16* __restrict__ Wth,
    const _Float16* __restrict__ Wtl, const float* __restrict__ bias,
    const float* __restrict__ bn_a, const float* __restrict__ bn_c,
    float* __restrict__ C, int NOUTr, float* __restrict__ sums,
    float* __restrict__ sqs) {
  constexpr int BM = WR * MT * 16;
  constexpr int NR = WC * NT * 16;
  constexpr int BKP = 40;                // 32 + 8 pad (80 B rows)
  constexpr int ABYTES = BM * BKP * 2;
  constexpr int BBYTES = NR * BKP * 2;
  __shared__ __align__(16) char smem[2 * ABYTES + 2 * BBYTES];
  _Float16* Ah = (_Float16*)smem;
  _Float16* Al = (_Float16*)(smem + ABYTES);
  _Float16* Bh = (_Float16*)(smem + 2 * ABYTES);
  _Float16* Bl = (_Float16*)(smem + 2 * ABYTES + BBYTES);

  const int tid = threadIdx.x;
  const int lane = tid & 63, wave = tid >> 6;
  const int wr = wave % WR, wc = wave / WR;
  const int quad = lane >> 4, ln = lane & 15;
  const int rowbase = blockIdx.x * BM;

  fx4 acc[MT][NT];
#pragma unroll
  for (int mt = 0; mt < MT; ++mt)
#pragma unroll
    for (int j = 0; j < NT; ++j) acc[mt][j] = (fx4){0.f, 0.f, 0.f, 0.f};

  for (int kc = 0; kc < KPAD / 32; ++kc) {
    __syncthreads();
    // stage A chunk: fp32 -> (BN+ReLU) -> f16 hi/lo
    for (int idx = tid; idx < BM * 8; idx += 256) {
      int m = idx >> 3, q = idx & 7;
      int gi = rowbase + m;
      int k = kc * 32 + q * 4;
      float vv[4] = {0.f, 0.f, 0.f, 0.f};
      if (gi < N_NODES && k < K) {
        float4 v = *(const float4*)(A + (size_t)gi * K + k);
        if constexpr (BN) {
          float4 a4 = *(const float4*)(bn_a + k);
          float4 c4 = *(const float4*)(bn_c + k);
          v.x = fmaxf(fmaf(v.x, a4.x, c4.x), 0.f);
          v.y = fmaxf(fmaf(v.y, a4.y, c4.y), 0.f);
          v.z = fmaxf(fmaf(v.z, a4.z, c4.z), 0.f);
          v.w = fmaxf(fmaf(v.w, a4.w, c4.w), 0.f);
        }
        vv[0] = v.x; vv[1] = v.y; vv[2] = v.z; vv[3] = v.w;
      }
      f16x4 hi, lo;
#pragma unroll
      for (int t = 0; t < 4; ++t) {
        _Float16 h = (_Float16)vv[t];
        hi[t] = h;
        lo[t] = (_Float16)(vv[t] - (float)h);
      }
      *(f16x4*)(Ah + m * BKP + q * 4) = hi;
      *(f16x4*)(Al + m * BKP + q * 4) = lo;
    }
    // stage W tiles (pre-split, pre-transposed, zero-padded)
    for (int idx = tid; idx < NR * 4; idx += 256) {
      int n = idx >> 2, p = idx & 3;
      int src = n * KPAD + kc * 32 + p * 8;
      *(f16x8*)(Bh + n * BKP + p * 8) = *(const f16x8*)(Wth + src);
      *(f16x8*)(Bl + n * BKP + p * 8) = *(const f16x8*)(Wtl + src);
    }
    __syncthreads();
    f16x8 ah[MT], al[MT];
#pragma unroll
    for (int mt = 0; mt < MT; ++mt) {
      int r = (wr * MT + mt) * 16 + ln;
      ah[mt] = *(const f16x8*)(Ah + r * BKP + quad * 8);
      al[mt] = *(const f16x8*)(Al + r * BKP + quad * 8);
    }
#pragma unroll
    for (int j = 0; j < NT; ++j) {
      int n = (wc * NT + j) * 16 + ln;
      f16x8 bh = *(const f16x8*)(Bh + n * BKP + quad * 8);
      f16x8 bl = *(const f16x8*)(Bl + n * BKP + quad * 8);
#pragma unroll
      for (int mt = 0; mt < MT; ++mt)
        acc[mt][j] = __builtin_amdgcn_mfma_f32_16x16x32_f16(ah[mt], bh, acc[mt][j], 0, 0, 0);
#pragma unroll
      for (int mt = 0; mt < MT; ++mt)
        acc[mt][j] = __builtin_amdgcn_mfma_f32_16x16x32_f16(al[mt], bh, acc[mt][j], 0, 0, 0);
#pragma unroll
      for (int mt = 0; mt < MT; ++mt)
        acc[mt][j] = __builtin_amdgcn_mfma_f32_16x16x32_f16(ah[mt], bl, acc[mt][j], 0, 0, 0);
    }
  }

  // epilogue: bias add, store, fused per-column stats partials
  float scA[NT], sqA[NT];
#pragma unroll
  for (int j = 0; j < NT; ++j) {
    int col = (wc * NT + j) * 16 + ln;
    float bs = (bias != nullptr && col < NOUTr) ? bias[col] : 0.f;
    float sc = 0.f, sq = 0.f;
#pragma unroll
    for (int mt = 0; mt < MT; ++mt) {
      int rb = rowbase + (wr * MT + mt) * 16 + quad * 4;
#pragma unroll
      for (int r = 0; r < 4; ++r) {
        int gi = rb + r;
        if (gi < N_NODES && col < NOUTr) {
          float v = acc[mt][j][r] + bs;
          C[(size_t)gi * NOUTr + col] = v;
          sc += v;
          sq = fmaf(v, v, sq);
        }
      }
    }
    scA[j] = sc;
    sqA[j] = sq;
  }
  if constexpr (STATS) {
    float* s_s = (float*)smem;           // reuse A region (safe after barrier)
    float* s_q = s_s + NR;
    __syncthreads();
    for (int c = tid; c < 2 * NR; c += 256) s_s[c] = 0.f;
    __syncthreads();
#pragma unroll
    for (int j = 0; j < NT; ++j) {
      float sc = scA[j], sq = sqA[j];
      sc += __shfl_xor(sc, 16); sq += __shfl_xor(sq, 16);
      sc += __shfl_xor(sc, 32); sq += __shfl_xor(sq, 32);
      if (quad == 0) {
        int c = (wc * NT + j) * 16 + ln;
        atomicAdd(&s_s[c], sc);
        atomicAdd(&s_q[c], sq);
      }
    }
    __syncthreads();
    int rep = (blockIdx.x & (NREP - 1));
    for (int c = tid; c < NR; c += 256) {
      if (c < NOUTr) {
        atomicAdd(&sums[rep * NOUTr + c], s_s[c]);   // stride NOUTr = consumer stride
        atomicAdd(&sqs[rep * NOUTr + c], s_q[c]);
      }
    }
  }
}

// ---------------- conv2 aggregation: g2 = A_norm @ t2 + b2   [N,112] -------------
__global__ void k_agg2(const float4* __restrict__ t2, const float* __restrict__ dinv,
                       const int* __restrict__ rowoff, const int* __restrict__ cnt,
                       const int* __restrict__ csr, const float* __restrict__ b2,
                       float4* __restrict__ g2) {
  int lane = threadIdx.x & 31;
  int i = blockIdx.x * 8 + (threadIdx.x >> 5);
  if (i >= N_NODES || lane >= 28) return;   // 28 float4 = 112 channels
  float di = dinv[i];
  float4 v = t2[i * 28 + lane];
  float f0 = di * di;
  float4 acc, acc2;
  acc.x = f0 * v.x; acc.y = f0 * v.y; acc.z = f0 * v.z; acc.w = f0 * v.w;
  acc2.x = 0.f; acc2.y = 0.f; acc2.z = 0.f; acc2.w = 0.f;
  int start = rowoff[i], len = cnt[i];
  int e = 0;
  for (; e + 1 < len; e += 2) {
    int s0 = csr[start + e], s1 = csr[start + e + 1];
    float fa = di * dinv[s0], fb = di * dinv[s1];
    float4 u0 = t2[s0 * 28 + lane];
    float4 u1 = t2[s1 * 28 + lane];
    acc.x = fmaf(fa, u0.x, acc.x);  acc.y = fmaf(fa, u0.y, acc.y);
    acc.z = fmaf(fa, u0.z, acc.z);  acc.w = fmaf(fa, u0.w, acc.w);
    acc2.x = fmaf(fb, u1.x, acc2.x); acc2.y = fmaf(fb, u1.y, acc2.y);
    acc2.z = fmaf(fb, u1.z, acc2.z); acc2.w = fmaf(fb, u1.w, acc2.w);
  }
  if (e < len) {
    int s0 = csr[start + e];
    float fa = di * dinv[s0];
    float4 u0 = t2[s0 * 28 + lane];
    acc.x = fmaf(fa, u0.x, acc.x); acc.y = fmaf(fa, u0.y, acc.y);
    acc.z = fmaf(fa, u0.z, acc.z); acc.w = fmaf(fa, u0.w, acc.w);
  }
  float4 bb = ((const float4*)b2)[lane];
  acc.x += acc2.x + bb.x; acc.y += acc2.y + bb.y;
  acc.z += acc2.z + bb.z; acc.w += acc2.w + bb.w;
  g2[i * 28 + lane] = acc;
}

// ---------------- BN column stats (standalone, for g2) ----------------
template <int C>
__global__ void k_colstats(const float* __restrict__ X, float* __restrict__ sums,
                           float* __restrict__ sqs) {
  int c = threadIdx.x;
  if (c >= C) return;
  int chunk = (N_NODES + gridDim.x - 1) / gridDim.x;
  int i0 = blockIdx.x * chunk;
  int i1 = min(N_NODES, i0 + chunk);
  float s = 0.f, q = 0.f;
  for (int i = i0; i < i1; ++i) {
    float v = X[(size_t)i * C + c];
    s += v;
    q = fmaf(v, v, q);
  }
  int rep = (blockIdx.x & (NREP - 1));
  atomicAdd(&sums[rep * C + c], s);
  atomicAdd(&sqs[rep * C + c], q);
}

template <int C>
__global__ void k_bnfinal(const float* __restrict__ sums, const float* __restrict__ sqs,
                          const float* __restrict__ gamma, const float* __restrict__ beta,
                          float* __restrict__ bn_a, float* __restrict__ bn_c) {
  int c = threadIdx.x;
  if (c >= C) return;
  float s = 0.f, q = 0.f;
#pragma unroll
  for (int r = 0; r < NREP; ++r) {
    s += sums[r * C + c];
    q += sqs[r * C + c];
  }
  const float inv_n = 1.0f / (float)N_NODES;
  float mean = s * inv_n;
  float var = fmaxf(q * inv_n - mean * mean, 0.f);
  float rstd = 1.0f / sqrtf(var + 1e-5f);
  float a = gamma[c] * rstd;
  bn_a[c] = a;
  bn_c[c] = beta[c] - mean * a;
}

// ---------------- final: out = relu(bn3(h4)) @ lin4_w + lin4_b ----------------
__global__ void k_final(const float* __restrict__ h4, const float* __restrict__ bn_a,
                        const float* __restrict__ bn_c, const float* __restrict__ w4,
                        const float* __restrict__ b4, float* __restrict__ out) {
  int lane = threadIdx.x & 63;
  int i = blockIdx.x * 4 + (threadIdx.x >> 6);   // 25000*4 == 100000 exactly
  float acc = fmaxf(fmaf(h4[(size_t)i * 100 + lane], bn_a[lane], bn_c[lane]), 0.f) * w4[lane];
  if (lane < 36) {
    int k = lane + 64;
    acc += fmaxf(fmaf(h4[(size_t)i * 100 + k], bn_a[k], bn_c[k]), 0.f) * w4[k];
  }
#pragma unroll
  for (int off = 32; off >= 1; off >>= 1) acc += __shfl_down(acc, off);
  if (lane == 0) out[i] = acc + b4[0];
}

extern "C" void kernel_launch(void* const* d_in, const int* in_sizes, int n_in,
                              void* d_out, int out_size, void* d_ws, size_t ws_size,
                              hipStream_t stream) {
  const float* x   = (const float*)d_in[0];
  const int*   ei  = (const int*)d_in[1];
  const float* W1  = (const float*)d_in[2];
  const float* b1  = (const float*)d_in[3];
  const float* W2  = (const float*)d_in[4];
  const float* b2  = (const float*)d_in[5];
  const float* l2w = (const float*)d_in[6];
  const float* l2b = (const float*)d_in[7];
  const float* l3w = (const float*)d_in[8];
  const float* l3b = (const float*)d_in[9];
  const float* l4w = (const float*)d_in[10];
  const float* l4b = (const float*)d_in[11];
  const float* g1  = (const float*)d_in[12];
  const float* be1 = (const float*)d_in[13];
  const float* g2w = (const float*)d_in[14];
  const float* be2 = (const float*)d_in[15];
  const float* g3  = (const float*)d_in[16];
  const float* be3 = (const float*)d_in[17];
  float* out = (float*)d_out;

  // ---- workspace carve-up ----
  char* base = (char*)d_ws;
  size_t off = 0;
  auto alloc = [&](size_t bytes) -> char* {
    char* p = base + off;
    off = (off + bytes + 255) & ~(size_t)255;
    return p;
  };
  int*   cnt    = (int*)alloc((size_t)N_NODES * 4);
  int*   rowoff = (int*)alloc((size_t)N_NODES * 4);
  int*   cursor = (int*)alloc((size_t)N_NODES * 4);
  int*   bsum   = (int*)alloc(512 * 4);
  float* dinv   = (float*)alloc((size_t)N_NODES * 4);
  int*   csr    = (int*)alloc((size_t)N_EDGES * 4);
  float* stats  = (float*)alloc((size_t)NREP * 960 * 4);  // replicated accumulators
  float* bnco   = (float*)alloc(960 * 4);   // a1,c1,a2,c2,a3,c3
  float* aggx   = (float*)alloc((size_t)N_NODES * 21 * 4);
  float* h1     = (float*)alloc((size_t)N_NODES * 256 * 4);  // reused as h3
  float* t2     = (float*)alloc((size_t)N_NODES * 112 * 4);  // reused as h4
  float* g2buf  = (float*)alloc((size_t)N_NODES * 112 * 4);
  _Float16* wt2h = (_Float16*)alloc(112 * 256 * 2);
  _Float16* wt2l = (_Float16*)alloc(112 * 256 * 2);
  _Float16* wt3h = (_Float16*)alloc(256 * 128 * 2);
  _Float16* wt3l = (_Float16*)alloc(256 * 128 * 2);
  _Float16* wt4h = (_Float16*)alloc(112 * 256 * 2);
  _Float16* wt4l = (_Float16*)alloc(112 * 256 * 2);

  // replicated stats layout: [NREP x C] per array
  float* sums1 = stats;                     // NREP*112
  float* sqs1  = sums1 + NREP * 112;
  float* sums2 = sqs1 + NREP * 112;         // NREP*256
  float* sqs2  = sums2 + NREP * 256;
  float* sums3 = sqs2 + NREP * 256;         // NREP*100
  float* sqs3  = sums3 + NREP * 112;
  float* bn_a1 = bnco + 0,   *bn_c1 = bnco + 112;
  float* bn_a2 = bnco + 224, *bn_c2 = bnco + 480;
  float* bn_a3 = bnco + 736, *bn_c3 = bnco + 848;

  hipMemsetAsync(cnt, 0, (size_t)N_NODES * 4, stream);
  hipMemsetAsync(stats, 0, (size_t)NREP * 960 * 4, stream);

  const int EB = (N_EDGES + 255) / 256;   // 6250
  const int NB = (N_NODES + 255) / 256;   // 391
  k_hist<<<EB, 256, 0, stream>>>(ei, cnt);
  k_dinv<<<NB, 256, 0, stream>>>(cnt, dinv);
  k_scan_block<<<NB, 256, 0, stream>>>(cnt, rowoff, bsum);
  k_scan_top<<<1, 512, 0, stream>>>(bsum, NB);
  k_scan_add<<<NB, 256, 0, stream>>>(rowoff, cursor, bsum);
  k_fill<<<EB, 256, 0, stream>>>(ei, cursor, csr);

  // W splits (independent, tiny)
  k_wsplit<256, 256, 112, 112><<<112, 256, 0, stream>>>(W2, wt2h, wt2l);
  k_wsplit<112, 128, 256, 256><<<128, 256, 0, stream>>>(l2w, wt3h, wt3l);
  k_wsplit<256, 256, 100, 112><<<112, 256, 0, stream>>>(l3w, wt4h, wt4l);

  k_aggx<<<12500, 256, 0, stream>>>(x, dinv, rowoff, cnt, csr, aggx);
  k_gemm1<<<3125, 256, 0, stream>>>(aggx, W1, b1, h1);

  // t2 = h1 @ W2: K=256, NOUT=112; waves 4x1, MT=2,NT=7 -> acc 56, LDS 38.4 KB
  k_mgemm<256, 256, 7, 2, 4, 1, false, false><<<782, 256, 0, stream>>>(
      h1, wt2h, wt2l, nullptr, nullptr, nullptr, t2, 112, nullptr, nullptr);
  k_agg2<<<12500, 256, 0, stream>>>((const float4*)t2, dinv, rowoff, cnt, csr, b2,
                                    (float4*)g2buf);

  k_colstats<112><<<200, 128, 0, stream>>>(g2buf, sums1, sqs1);
  k_bnfinal<112><<<1, 128, 0, stream>>>(sums1, sqs1, g1, be1, bn_a1, bn_c1);

  // h3 = relu(bn1(g2)) @ lin2_w: K=112, NOUT=256; waves 2x2, MT=2,NT=8 -> acc 64
  k_mgemm<112, 128, 8, 2, 2, 2, true, true><<<1563, 256, 0, stream>>>(
      g2buf, wt3h, wt3l, l2b, bn_a1, bn_c1, h1, 256, sums2, sqs2);
  k_bnfinal<256><<<1, 256, 0, stream>>>(sums2, sqs2, g2w, be2, bn_a2, bn_c2);

  // h4 = relu(bn2(h3)) @ lin3_w: K=256, NOUT=100; waves 4x1, MT=2,NT=7
  k_mgemm<256, 256, 7, 2, 4, 1, true, true><<<782, 256, 0, stream>>>(
      h1, wt4h, wt4l, l3b, bn_a2, bn_c2, t2, 100, sums3, sqs3);
  k_bnfinal<100><<<1, 128, 0, stream>>>(sums3, sqs3, g3, be3, bn_a3, bn_c3);

  k_final<<<25000, 256, 0, stream>>>(t2, bn_a3, bn_c3, l4w, l4b, out);
}

// Round 5
// 645.298 us; speedup vs baseline: 2.2529x; 1.2328x over previous
//
#include <hip/hip_runtime.h>

#define N_NODES 100000
#define N_EDGES 1600000

typedef _Float16 f16x8 __attribute__((ext_vector_type(8)));
typedef _Float16 f16x4 __attribute__((ext_vector_type(4)));
typedef float fx4 __attribute__((ext_vector_type(4)));

#define NREP 16   // stats-accumulator replication to de-contend atomics

// ---------------- graph prep ----------------
__global__ void k_hist(const int* __restrict__ ei, int* __restrict__ cnt) {
  int e = blockIdx.x * 256 + threadIdx.x;
  if (e < N_EDGES) atomicAdd(&cnt[ei[N_EDGES + e]], 1);
}

__global__ void k_dinv(const int* __restrict__ cnt, float* __restrict__ dinv) {
  int i = blockIdx.x * 256 + threadIdx.x;
  if (i < N_NODES) dinv[i] = rsqrtf((float)(cnt[i] + 1));  // +1 = appended self-loop
}

__global__ void k_scan_block(const int* __restrict__ cnt, int* __restrict__ rowoff,
                             int* __restrict__ bsum) {
  __shared__ int s[256];
  int t = threadIdx.x;
  int i = blockIdx.x * 256 + t;
  int v = (i < N_NODES) ? cnt[i] : 0;
  s[t] = v;
  __syncthreads();
  for (int off = 1; off < 256; off <<= 1) {
    int add = (t >= off) ? s[t - off] : 0;
    __syncthreads();
    s[t] += add;
    __syncthreads();
  }
  if (i < N_NODES) rowoff[i] = s[t] - v;       // exclusive
  if (t == 255) bsum[blockIdx.x] = s[255];     // block total
}

__global__ void k_scan_top(int* __restrict__ bsum, int nb) {
  __shared__ int s[512];
  int t = threadIdx.x;
  int v = (t < nb) ? bsum[t] : 0;
  s[t] = v;
  __syncthreads();
  for (int off = 1; off < 512; off <<= 1) {
    int add = (t >= off) ? s[t - off] : 0;
    __syncthreads();
    s[t] += add;
    __syncthreads();
  }
  if (t < nb) bsum[t] = s[t] - v;
}

__global__ void k_scan_add(int* __restrict__ rowoff, int* __restrict__ cursor,
                           const int* __restrict__ bsum) {
  int i = blockIdx.x * 256 + threadIdx.x;
  if (i < N_NODES) {
    int r = rowoff[i] + bsum[blockIdx.x];
    rowoff[i] = r;
    cursor[i] = r;
  }
}

__global__ void k_fill(const int* __restrict__ ei, int* __restrict__ cursor,
                       int* __restrict__ csr) {
  int e = blockIdx.x * 256 + threadIdx.x;
  if (e < N_EDGES) {
    int d = ei[N_EDGES + e];
    int p = atomicAdd(&cursor[d], 1);
    csr[p] = ei[e];
  }
}

// ---------------- xs = dinv[i] * x[i], padded [N,24] ----------------
// Folds dinv[src] out of the conv1 edge loop: agg_i = di*(xs_i + sum xs_s).
__global__ void k_xpad(const float* __restrict__ x, const float* __restrict__ dinv,
                       float* __restrict__ xs) {
  int idx = blockIdx.x * 256 + threadIdx.x;
  if (idx >= N_NODES * 24) return;
  int r = idx / 24, c = idx - r * 24;
  xs[idx] = (c < 21) ? x[r * 21 + c] * dinv[r] : 0.f;
}

// ---------------- conv1 aggregation: aggx = A_norm @ x   [N,24 padded] ----------
// 6 lanes x float4 per row, 10 rows per wave (lanes 60-63 idle).
__global__ __launch_bounds__(256) void k_aggx(
    const float4* __restrict__ xs4, const float* __restrict__ dinv,
    const int* __restrict__ rowoff, const int* __restrict__ cnt,
    const int* __restrict__ csr, float4* __restrict__ aggx4) {
  int lane = threadIdx.x & 63, wave = threadIdx.x >> 6;
  int j = lane / 6, c4 = lane - j * 6;
  if (j >= 10) return;
  int i = blockIdx.x * 40 + wave * 10 + j;     // 2500*40 == 100000 exactly
  float di = dinv[i];
  int start = rowoff[i], len = cnt[i];
  float4 a0 = xs4[i * 6 + c4];                 // self-loop term (pre-scaled)
  float4 a1 = make_float4(0.f, 0.f, 0.f, 0.f);
  int e = 0;
  for (; e + 1 < len; e += 2) {
    int s0 = csr[start + e], s1 = csr[start + e + 1];
    float4 u0 = xs4[s0 * 6 + c4];
    float4 u1 = xs4[s1 * 6 + c4];
    a0.x += u0.x; a0.y += u0.y; a0.z += u0.z; a0.w += u0.w;
    a1.x += u1.x; a1.y += u1.y; a1.z += u1.z; a1.w += u1.w;
  }
  if (e < len) {
    int s0 = csr[start + e];
    float4 u0 = xs4[s0 * 6 + c4];
    a0.x += u0.x; a0.y += u0.y; a0.z += u0.z; a0.w += u0.w;
  }
  float4 r;
  r.x = di * (a0.x + a1.x); r.y = di * (a0.y + a1.y);
  r.z = di * (a0.z + a1.z); r.w = di * (a0.w + a1.w);
  aggx4[i * 6 + c4] = r;
}

// ---------------- gemm1: h1 = relu(aggx @ W1 + b1)   [N,256], K=21 (stride 24) ---
__global__ __launch_bounds__(256) void k_gemm1(const float4* __restrict__ aggx4,
                                               const float* __restrict__ W1,
                                               const float* __restrict__ b1,
                                               float* __restrict__ h1) {
  __shared__ float As[32][24];
  int t = threadIdx.x;
  int base = blockIdx.x * 32;           // 3125 * 32 == 100000 exactly
  for (int idx = t; idx < 32 * 6; idx += 256) {
    int m = idx / 6, q = idx - m * 6;
    *(float4*)(&As[m][q * 4]) = aggx4[(base + m) * 6 + q];
  }
  float w[21];
#pragma unroll
  for (int k = 0; k < 21; ++k) w[k] = W1[k * 256 + t];
  float bias = b1[t];
  __syncthreads();
  for (int m = 0; m < 32; ++m) {
    float acc = bias;
#pragma unroll
    for (int k = 0; k < 21; ++k) acc = fmaf(As[m][k], w[k], acc);
    h1[(size_t)(base + m) * 256 + t] = fmaxf(acc, 0.f);
  }
}

// ---------------- W prep: split fp32 W[k][n] -> transposed f16 hi/lo Wt[n][kpad] ---
template <int K, int KPAD, int NOUT, int NR>
__global__ void k_wsplit(const float* __restrict__ W, _Float16* __restrict__ Wh,
                         _Float16* __restrict__ Wl) {
  int idx = blockIdx.x * 256 + threadIdx.x;
  if (idx >= NR * KPAD) return;
  int n = idx / KPAD, k = idx % KPAD;
  float v = (n < NOUT && k < K) ? W[k * NOUT + n] : 0.f;
  _Float16 h = (_Float16)v;              // RNE
  Wh[idx] = h;
  Wl[idx] = (_Float16)(v - (float)h);
}

// ---------------- MFMA GEMM: C = f(A)[N,K] @ W[K,NOUT] (+bias), split-f16 -------
// Waves WR x WC; keep MT*NT <= 16 so acc <= 64 regs and 3 blocks/CU co-reside.
// F16OUT + rowscale: store rowscale[gi]*(acc) as _Float16 (t2s = dinv*h1W2 path).
template <int K, int KPAD, int NT, int MT, int WR, int WC, bool BN, bool STATS, bool F16OUT>
__global__ __launch_bounds__(256, 3) void k_mgemm(
    const float* __restrict__ A, const _Float16* __restrict__ Wth,
    const _Float16* __restrict__ Wtl, const float* __restrict__ bias,
    const float* __restrict__ bn_a, const float* __restrict__ bn_c,
    const float* __restrict__ rowscale, void* __restrict__ Cv, int NOUTr,
    float* __restrict__ sums, float* __restrict__ sqs) {
  constexpr int BM = WR * MT * 16;
  constexpr int NR = WC * NT * 16;
  constexpr int BKP = 40;                // 32 + 8 pad (80 B rows)
  constexpr int ABYTES = BM * BKP * 2;
  constexpr int BBYTES = NR * BKP * 2;
  __shared__ __align__(16) char smem[2 * ABYTES + 2 * BBYTES];
  _Float16* Ah = (_Float16*)smem;
  _Float16* Al = (_Float16*)(smem + ABYTES);
  _Float16* Bh = (_Float16*)(smem + 2 * ABYTES);
  _Float16* Bl = (_Float16*)(smem + 2 * ABYTES + BBYTES);
  float* C = (float*)Cv;
  _Float16* C16 = (_Float16*)Cv;

  const int tid = threadIdx.x;
  const int lane = tid & 63, wave = tid >> 6;
  const int wr = wave % WR, wc = wave / WR;
  const int quad = lane >> 4, ln = lane & 15;
  const int rowbase = blockIdx.x * BM;

  fx4 acc[MT][NT];
#pragma unroll
  for (int mt = 0; mt < MT; ++mt)
#pragma unroll
    for (int j = 0; j < NT; ++j) acc[mt][j] = (fx4){0.f, 0.f, 0.f, 0.f};

  for (int kc = 0; kc < KPAD / 32; ++kc) {
    __syncthreads();
    // stage A chunk: fp32 -> (BN+ReLU) -> f16 hi/lo
    for (int idx = tid; idx < BM * 8; idx += 256) {
      int m = idx >> 3, q = idx & 7;
      int gi = rowbase + m;
      int k = kc * 32 + q * 4;
      float vv[4] = {0.f, 0.f, 0.f, 0.f};
      if (gi < N_NODES && k < K) {
        float4 v = *(const float4*)(A + (size_t)gi * K + k);
        if constexpr (BN) {
          float4 a4 = *(const float4*)(bn_a + k);
          float4 c4 = *(const float4*)(bn_c + k);
          v.x = fmaxf(fmaf(v.x, a4.x, c4.x), 0.f);
          v.y = fmaxf(fmaf(v.y, a4.y, c4.y), 0.f);
          v.z = fmaxf(fmaf(v.z, a4.z, c4.z), 0.f);
          v.w = fmaxf(fmaf(v.w, a4.w, c4.w), 0.f);
        }
        vv[0] = v.x; vv[1] = v.y; vv[2] = v.z; vv[3] = v.w;
      }
      f16x4 hi, lo;
#pragma unroll
      for (int t = 0; t < 4; ++t) {
        _Float16 h = (_Float16)vv[t];
        hi[t] = h;
        lo[t] = (_Float16)(vv[t] - (float)h);
      }
      *(f16x4*)(Ah + m * BKP + q * 4) = hi;
      *(f16x4*)(Al + m * BKP + q * 4) = lo;
    }
    // stage W tiles (pre-split, pre-transposed, zero-padded)
    for (int idx = tid; idx < NR * 4; idx += 256) {
      int n = idx >> 2, p = idx & 3;
      int src = n * KPAD + kc * 32 + p * 8;
      *(f16x8*)(Bh + n * BKP + p * 8) = *(const f16x8*)(Wth + src);
      *(f16x8*)(Bl + n * BKP + p * 8) = *(const f16x8*)(Wtl + src);
    }
    __syncthreads();
    f16x8 ah[MT], al[MT];
#pragma unroll
    for (int mt = 0; mt < MT; ++mt) {
      int r = (wr * MT + mt) * 16 + ln;
      ah[mt] = *(const f16x8*)(Ah + r * BKP + quad * 8);
      al[mt] = *(const f16x8*)(Al + r * BKP + quad * 8);
    }
#pragma unroll
    for (int j = 0; j < NT; ++j) {
      int n = (wc * NT + j) * 16 + ln;
      f16x8 bh = *(const f16x8*)(Bh + n * BKP + quad * 8);
      f16x8 bl = *(const f16x8*)(Bl + n * BKP + quad * 8);
#pragma unroll
      for (int mt = 0; mt < MT; ++mt)
        acc[mt][j] = __builtin_amdgcn_mfma_f32_16x16x32_f16(ah[mt], bh, acc[mt][j], 0, 0, 0);
#pragma unroll
      for (int mt = 0; mt < MT; ++mt)
        acc[mt][j] = __builtin_amdgcn_mfma_f32_16x16x32_f16(al[mt], bh, acc[mt][j], 0, 0, 0);
#pragma unroll
      for (int mt = 0; mt < MT; ++mt)
        acc[mt][j] = __builtin_amdgcn_mfma_f32_16x16x32_f16(ah[mt], bl, acc[mt][j], 0, 0, 0);
    }
  }

  // per-row scale (loaded once per output row)
  float rsv[MT][4];
#pragma unroll
  for (int mt = 0; mt < MT; ++mt)
#pragma unroll
    for (int r = 0; r < 4; ++r) {
      int gi = rowbase + (wr * MT + mt) * 16 + quad * 4 + r;
      rsv[mt][r] = (rowscale != nullptr && gi < N_NODES) ? rowscale[gi] : 1.f;
    }

  // epilogue: bias add, (rowscale), store, fused per-column stats partials
  float scA[NT], sqA[NT];
#pragma unroll
  for (int j = 0; j < NT; ++j) {
    int col = (wc * NT + j) * 16 + ln;
    float bs = (bias != nullptr && col < NOUTr) ? bias[col] : 0.f;
    float sc = 0.f, sq = 0.f;
#pragma unroll
    for (int mt = 0; mt < MT; ++mt) {
      int rb = rowbase + (wr * MT + mt) * 16 + quad * 4;
#pragma unroll
      for (int r = 0; r < 4; ++r) {
        int gi = rb + r;
        if (gi < N_NODES && col < NOUTr) {
          float v = (acc[mt][j][r] + bs) * rsv[mt][r];
          if constexpr (F16OUT)
            C16[(size_t)gi * NOUTr + col] = (_Float16)v;
          else
            C[(size_t)gi * NOUTr + col] = v;
          sc += v;
          sq = fmaf(v, v, sq);
        }
      }
    }
    scA[j] = sc;
    sqA[j] = sq;
  }
  if constexpr (STATS) {
    float* s_s = (float*)smem;           // reuse A region (safe after barrier)
    float* s_q = s_s + NR;
    __syncthreads();
    for (int c = tid; c < 2 * NR; c += 256) s_s[c] = 0.f;
    __syncthreads();
#pragma unroll
    for (int j = 0; j < NT; ++j) {
      float sc = scA[j], sq = sqA[j];
      sc += __shfl_xor(sc, 16); sq += __shfl_xor(sq, 16);
      sc += __shfl_xor(sc, 32); sq += __shfl_xor(sq, 32);
      if (quad == 0) {
        int c = (wc * NT + j) * 16 + ln;
        atomicAdd(&s_s[c], sc);
        atomicAdd(&s_q[c], sq);
      }
    }
    __syncthreads();
    int rep = (blockIdx.x & (NREP - 1));
    for (int c = tid; c < NR; c += 256) {
      if (c < NOUTr) {
        atomicAdd(&sums[rep * NOUTr + c], s_s[c]);   // stride NOUTr = consumer stride
        atomicAdd(&sqs[rep * NOUTr + c], s_q[c]);
      }
    }
  }
}

// ---------------- conv2 aggregation: g2 = A_norm @ t2 + b2   [N,112] -------------
// t2s is f16, pre-scaled by dinv (mgemm F16OUT+rowscale). 14 lanes x f16x8 per
// row, 4 rows per wave (lanes 56-63 idle). g2_i = di*(t2s_i + sum t2s_s) + b2.
__global__ __launch_bounds__(256) void k_agg2(
    const f16x8* __restrict__ t2s8, const float* __restrict__ dinv,
    const int* __restrict__ rowoff, const int* __restrict__ cnt,
    const int* __restrict__ csr, const float* __restrict__ b2,
    float* __restrict__ g2) {
  int lane = threadIdx.x & 63, wave = threadIdx.x >> 6;
  int j = lane / 14, c = lane - j * 14;
  if (j >= 4) return;
  int i = blockIdx.x * 16 + wave * 4 + j;      // 6250*16 == 100000 exactly
  float di = dinv[i];
  int start = rowoff[i], len = cnt[i];
  f16x8 u = t2s8[i * 14 + c];                  // self-loop term
  fx4 a0, a1, b0, b1;
#pragma unroll
  for (int t = 0; t < 4; ++t) { a0[t] = (float)u[t]; b0[t] = (float)u[t + 4]; }
  a1 = (fx4){0.f, 0.f, 0.f, 0.f};
  b1 = (fx4){0.f, 0.f, 0.f, 0.f};
  int e = 0;
  for (; e + 1 < len; e += 2) {
    int s0 = csr[start + e], s1 = csr[start + e + 1];
    f16x8 u0 = t2s8[s0 * 14 + c];
    f16x8 u1 = t2s8[s1 * 14 + c];
#pragma unroll
    for (int t = 0; t < 4; ++t) {
      a0[t] += (float)u0[t]; b0[t] += (float)u0[t + 4];
      a1[t] += (float)u1[t]; b1[t] += (float)u1[t + 4];
    }
  }
  if (e < len) {
    int s0 = csr[start + e];
    f16x8 u0 = t2s8[s0 * 14 + c];
#pragma unroll
    for (int t = 0; t < 4; ++t) { a0[t] += (float)u0[t]; b0[t] += (float)u0[t + 4]; }
  }
  float4 blo = *(const float4*)(b2 + c * 8);
  float4 bhi = *(const float4*)(b2 + c * 8 + 4);
  float4 r0, r1;
  r0.x = fmaf(di, a0[0] + a1[0], blo.x); r0.y = fmaf(di, a0[1] + a1[1], blo.y);
  r0.z = fmaf(di, a0[2] + a1[2], blo.z); r0.w = fmaf(di, a0[3] + a1[3], blo.w);
  r1.x = fmaf(di, b0[0] + b1[0], bhi.x); r1.y = fmaf(di, b0[1] + b1[1], bhi.y);
  r1.z = fmaf(di, b0[2] + b1[2], bhi.z); r1.w = fmaf(di, b0[3] + b1[3], bhi.w);
  *(float4*)(g2 + (size_t)i * 112 + c * 8) = r0;
  *(float4*)(g2 + (size_t)i * 112 + c * 8 + 4) = r1;
}

// ---------------- BN column stats (standalone, for g2) ----------------
template <int C>
__global__ void k_colstats(const float* __restrict__ X, float* __restrict__ sums,
                           float* __restrict__ sqs) {
  int c = threadIdx.x;
  if (c >= C) return;
  int chunk = (N_NODES + gridDim.x - 1) / gridDim.x;
  int i0 = blockIdx.x * chunk;
  int i1 = min(N_NODES, i0 + chunk);
  float s = 0.f, q = 0.f;
  for (int i = i0; i < i1; ++i) {
    float v = X[(size_t)i * C + c];
    s += v;
    q = fmaf(v, v, q);
  }
  int rep = (blockIdx.x & (NREP - 1));
  atomicAdd(&sums[rep * C + c], s);
  atomicAdd(&sqs[rep * C + c], q);
}

template <int C>
__global__ void k_bnfinal(const float* __restrict__ sums, const float* __restrict__ sqs,
                          const float* __restrict__ gamma, const float* __restrict__ beta,
                          float* __restrict__ bn_a, float* __restrict__ bn_c) {
  int c = threadIdx.x;
  if (c >= C) return;
  float s = 0.f, q = 0.f;
#pragma unroll
  for (int r = 0; r < NREP; ++r) {
    s += sums[r * C + c];
    q += sqs[r * C + c];
  }
  const float inv_n = 1.0f / (float)N_NODES;
  float mean = s * inv_n;
  float var = fmaxf(q * inv_n - mean * mean, 0.f);
  float rstd = 1.0f / sqrtf(var + 1e-5f);
  float a = gamma[c] * rstd;
  bn_a[c] = a;
  bn_c[c] = beta[c] - mean * a;
}

// ---------------- final: out = relu(bn3(h4)) @ lin4_w + lin4_b ----------------
__global__ void k_final(const float* __restrict__ h4, const float* __restrict__ bn_a,
                        const float* __restrict__ bn_c, const float* __restrict__ w4,
                        const float* __restrict__ b4, float* __restrict__ out) {
  int lane = threadIdx.x & 63;
  int i = blockIdx.x * 4 + (threadIdx.x >> 6);   // 25000*4 == 100000 exactly
  float acc = fmaxf(fmaf(h4[(size_t)i * 100 + lane], bn_a[lane], bn_c[lane]), 0.f) * w4[lane];
  if (lane < 36) {
    int k = lane + 64;
    acc += fmaxf(fmaf(h4[(size_t)i * 100 + k], bn_a[k], bn_c[k]), 0.f) * w4[k];
  }
#pragma unroll
  for (int off = 32; off >= 1; off >>= 1) acc += __shfl_down(acc, off);
  if (lane == 0) out[i] = acc + b4[0];
}

extern "C" void kernel_launch(void* const* d_in, const int* in_sizes, int n_in,
                              void* d_out, int out_size, void* d_ws, size_t ws_size,
                              hipStream_t stream) {
  const float* x   = (const float*)d_in[0];
  const int*   ei  = (const int*)d_in[1];
  const float* W1  = (const float*)d_in[2];
  const float* b1  = (const float*)d_in[3];
  const float* W2  = (const float*)d_in[4];
  const float* b2  = (const float*)d_in[5];
  const float* l2w = (const float*)d_in[6];
  const float* l2b = (const float*)d_in[7];
  const float* l3w = (const float*)d_in[8];
  const float* l3b = (const float*)d_in[9];
  const float* l4w = (const float*)d_in[10];
  const float* l4b = (const float*)d_in[11];
  const float* g1  = (const float*)d_in[12];
  const float* be1 = (const float*)d_in[13];
  const float* g2w = (const float*)d_in[14];
  const float* be2 = (const float*)d_in[15];
  const float* g3  = (const float*)d_in[16];
  const float* be3 = (const float*)d_in[17];
  float* out = (float*)d_out;

  // ---- workspace carve-up (~203 MB) ----
  char* base = (char*)d_ws;
  size_t off = 0;
  auto alloc = [&](size_t bytes) -> char* {
    char* p = base + off;
    off = (off + bytes + 255) & ~(size_t)255;
    return p;
  };
  int*   cnt    = (int*)alloc((size_t)N_NODES * 4);
  int*   rowoff = (int*)alloc((size_t)N_NODES * 4);
  int*   cursor = (int*)alloc((size_t)N_NODES * 4);
  int*   bsum   = (int*)alloc(512 * 4);
  float* dinv   = (float*)alloc((size_t)N_NODES * 4);
  int*   csr    = (int*)alloc((size_t)N_EDGES * 4);
  float* stats  = (float*)alloc((size_t)NREP * 960 * 4);
  float* bnco   = (float*)alloc(960 * 4);
  float* xs     = (float*)alloc((size_t)N_NODES * 24 * 4);   // padded dinv-scaled x
  float* aggx   = (float*)alloc((size_t)N_NODES * 24 * 4);   // padded conv1 agg
  float* h1     = (float*)alloc((size_t)N_NODES * 256 * 4);  // reused as h3
  _Float16* t2s = (_Float16*)alloc((size_t)N_NODES * 112 * 2); // f16 dinv-scaled h1W2
  float* g2buf  = (float*)alloc((size_t)N_NODES * 112 * 4);  // reused as h4
  _Float16* wt2h = (_Float16*)alloc(112 * 256 * 2);
  _Float16* wt2l = (_Float16*)alloc(112 * 256 * 2);
  _Float16* wt3h = (_Float16*)alloc(256 * 128 * 2);
  _Float16* wt3l = (_Float16*)alloc(256 * 128 * 2);
  _Float16* wt4h = (_Float16*)alloc(112 * 256 * 2);
  _Float16* wt4l = (_Float16*)alloc(112 * 256 * 2);
  float* h4 = g2buf;   // g2buf dead after h3-mgemm; h4 [N,100] fits in [N,112]

  // replicated stats layout: [NREP x C] per array
  float* sums1 = stats;                     // NREP*112
  float* sqs1  = sums1 + NREP * 112;
  float* sums2 = sqs1 + NREP * 112;         // NREP*256
  float* sqs2  = sums2 + NREP * 256;
  float* sums3 = sqs2 + NREP * 256;         // NREP*100 used
  float* sqs3  = sums3 + NREP * 112;
  float* bn_a1 = bnco + 0,   *bn_c1 = bnco + 112;
  float* bn_a2 = bnco + 224, *bn_c2 = bnco + 480;
  float* bn_a3 = bnco + 736, *bn_c3 = bnco + 848;

  hipMemsetAsync(cnt, 0, (size_t)N_NODES * 4, stream);
  hipMemsetAsync(stats, 0, (size_t)NREP * 960 * 4, stream);

  const int EB = (N_EDGES + 255) / 256;   // 6250
  const int NB = (N_NODES + 255) / 256;   // 391
  k_hist<<<EB, 256, 0, stream>>>(ei, cnt);
  k_dinv<<<NB, 256, 0, stream>>>(cnt, dinv);
  k_scan_block<<<NB, 256, 0, stream>>>(cnt, rowoff, bsum);
  k_scan_top<<<1, 512, 0, stream>>>(bsum, NB);
  k_scan_add<<<NB, 256, 0, stream>>>(rowoff, cursor, bsum);
  k_fill<<<EB, 256, 0, stream>>>(ei, cursor, csr);

  // W splits (independent, tiny)
  k_wsplit<256, 256, 112, 112><<<112, 256, 0, stream>>>(W2, wt2h, wt2l);
  k_wsplit<112, 128, 256, 256><<<128, 256, 0, stream>>>(l2w, wt3h, wt3l);
  k_wsplit<256, 256, 100, 112><<<112, 256, 0, stream>>>(l3w, wt4h, wt4l);

  k_xpad<<<(N_NODES * 24 + 255) / 256, 256, 0, stream>>>(x, dinv, xs);
  k_aggx<<<2500, 256, 0, stream>>>((const float4*)xs, dinv, rowoff, cnt, csr,
                                   (float4*)aggx);
  k_gemm1<<<3125, 256, 0, stream>>>((const float4*)aggx, W1, b1, h1);

  // t2s = dinv * (h1 @ W2), f16 out: K=256, NOUT=112; waves 4x1, MT=2,NT=7
  k_mgemm<256, 256, 7, 2, 4, 1, false, false, true><<<782, 256, 0, stream>>>(
      h1, wt2h, wt2l, nullptr, nullptr, nullptr, dinv, t2s, 112, nullptr, nullptr);
  k_agg2<<<6250, 256, 0, stream>>>((const f16x8*)t2s, dinv, rowoff, cnt, csr, b2,
                                   g2buf);

  k_colstats<112><<<1600, 128, 0, stream>>>(g2buf, sums1, sqs1);
  k_bnfinal<112><<<1, 128, 0, stream>>>(sums1, sqs1, g1, be1, bn_a1, bn_c1);

  // h3 = relu(bn1(g2)) @ lin2_w: K=112, NOUT=256; waves 2x2, MT=2,NT=8
  k_mgemm<112, 128, 8, 2, 2, 2, true, true, false><<<1563, 256, 0, stream>>>(
      g2buf, wt3h, wt3l, l2b, bn_a1, bn_c1, nullptr, h1, 256, sums2, sqs2);
  k_bnfinal<256><<<1, 256, 0, stream>>>(sums2, sqs2, g2w, be2, bn_a2, bn_c2);

  // h4 = relu(bn2(h3)) @ lin3_w: K=256, NOUT=100; waves 4x1, MT=2,NT=7
  k_mgemm<256, 256, 7, 2, 4, 1, true, true, false><<<782, 256, 0, stream>>>(
      h1, wt4h, wt4l, l3b, bn_a2, bn_c2, nullptr, h4, 100, sums3, sqs3);
  k_bnfinal<100><<<1, 128, 0, stream>>>(sums3, sqs3, g3, be3, bn_a3, bn_c3);

  k_final<<<25000, 256, 0, stream>>>(h4, bn_a3, bn_c3, l4w, l4b, out);
}

// Round 6
// 503.366 us; speedup vs baseline: 2.8881x; 1.2820x over previous
//
#include <hip/hip_runtime.h>

#define N_NODES 100000
#define N_EDGES 1600000

typedef _Float16 f16x8 __attribute__((ext_vector_type(8)));
typedef _Float16 f16x4 __attribute__((ext_vector_type(4)));
typedef float fx4 __attribute__((ext_vector_type(4)));

#define NREP 16     // stats-accumulator replication to de-contend atomics
#define NBUCK 196   // ceil(100000/512) buckets of 512 nodes
#define CHUNK 8192  // edges per k_bin block (196*8192 >= 1.6M)
#define BCAP 12288  // per-bucket slot capacity (mean 8192, sd ~90 -> safe)

// ---------------- CSR build, pass 1: LDS counting-sort chunks by bucket --------
// Packed pair = (src<<9) | (dst & 511); bucket = dst >> 9. Flushes contiguous
// bucket runs to fixed per-bucket regions -> dense writes (no 64B/4B scatter
// write-allocate amplification like old k_fill: 105.8 MB HBM for 6.4 MB data).
__global__ __launch_bounds__(256) void k_bin(const int* __restrict__ ei,
                                             unsigned* __restrict__ binned,
                                             int* __restrict__ gcount) {
  __shared__ unsigned pr[CHUNK];          // 32 KB packed pairs
  __shared__ unsigned srt[CHUNK];         // 32 KB sorted copy
  __shared__ unsigned char bk[CHUNK];     // 8 KB bucket ids
  __shared__ int hist[256], scanb[256], offs[256], bs[256], gb[256];
  const int t = threadIdx.x;
  const int e0 = blockIdx.x * CHUNK;
  const int n = min(CHUNK, N_EDGES - e0);
  hist[t] = 0;
  __syncthreads();
  for (int i = t; i < n; i += 256) {
    int src = ei[e0 + i], dst = ei[N_EDGES + e0 + i];
    int b = dst >> 9;
    pr[i] = ((unsigned)src << 9) | (unsigned)(dst & 511);
    bk[i] = (unsigned char)b;
    atomicAdd(&hist[b], 1);
  }
  __syncthreads();
  int v = hist[t];
  scanb[t] = v;
  __syncthreads();
  for (int off = 1; off < 256; off <<= 1) {
    int a = (t >= off) ? scanb[t - off] : 0;
    __syncthreads();
    scanb[t] += a;
    __syncthreads();
  }
  offs[t] = scanb[t] - v;   // exclusive: bump cursor for scatter
  bs[t] = scanb[t] - v;     // stable copy: bucket local start for flush
  __syncthreads();
  for (int i = t; i < n; i += 256) {
    int b = bk[i];
    int p = atomicAdd(&offs[b], 1);
    srt[p] = pr[i];
  }
  // reserve global space per bucket
  if (t < NBUCK && v > 0) gb[t] = atomicAdd(&gcount[t], v);
  __syncthreads();
  // cooperative flush: one wave per bucket (round-robin), coalesced runs
  int wave = t >> 6, lane = t & 63;
  for (int b = wave; b < NBUCK; b += 4) {
    int c = hist[b];
    if (c == 0) continue;
    int ls = bs[b], base = gb[b];
    unsigned* dstp = binned + (size_t)b * BCAP + base;
    for (int i = lane; i < c; i += 64) dstp[i] = srt[ls + i];
  }
}

// ---------------- CSR build, pass 2: scan bucket counts -> csr bases ----------
__global__ void k_bscan(const int* __restrict__ gcount, int* __restrict__ gbase) {
  __shared__ int s[256];
  int t = threadIdx.x;
  int v = (t < NBUCK) ? gcount[t] : 0;
  s[t] = v;
  __syncthreads();
  for (int off = 1; off < 256; off <<= 1) {
    int a = (t >= off) ? s[t - off] : 0;
    __syncthreads();
    s[t] += a;
    __syncthreads();
  }
  if (t < NBUCK) gbase[t] = s[t] - v;
}

// ---------------- CSR build, pass 3: per-bucket sort by node; fused cnt/dinv/rowoff
__global__ __launch_bounds__(256) void k_csr(const unsigned* __restrict__ binned,
                                             const int* __restrict__ gcount,
                                             const int* __restrict__ gbase,
                                             int* __restrict__ rowoff,
                                             int* __restrict__ cnt,
                                             float* __restrict__ dinv,
                                             int* __restrict__ csr) {
  __shared__ int hist[512], offs[512], ps[256];
  __shared__ unsigned srt[BCAP];          // 48 KB
  const int b = blockIdx.x, t = threadIdx.x;
  const int n = min(gcount[b], BCAP);
  const int gb0 = gbase[b];
  const unsigned* bp = binned + (size_t)b * BCAP;
  hist[t] = 0;
  hist[t + 256] = 0;
  __syncthreads();
  for (int i = t; i < n; i += 256) atomicAdd(&hist[bp[i] & 511], 1);
  __syncthreads();
  // exclusive scan of 512 with 256 threads (pair trick)
  int e0v = hist[2 * t], e1v = hist[2 * t + 1];
  ps[t] = e0v + e1v;
  __syncthreads();
  for (int off = 1; off < 256; off <<= 1) {
    int a = (t >= off) ? ps[t - off] : 0;
    __syncthreads();
    ps[t] += a;
    __syncthreads();
  }
  int excl = ps[t] - (e0v + e1v);
  offs[2 * t] = excl;
  offs[2 * t + 1] = excl + e0v;
  __syncthreads();
  // fused per-node outputs (replaces k_hist/k_dinv/k_scan_*)
#pragma unroll
  for (int u = 0; u < 2; ++u) {
    int j = 2 * t + u;
    int nd = (b << 9) + j;
    if (nd < N_NODES) {
      int c = hist[j];
      cnt[nd] = c;
      dinv[nd] = rsqrtf((float)(c + 1));
      rowoff[nd] = gb0 + offs[j];
    }
  }
  __syncthreads();
  for (int i = t; i < n; i += 256) {
    unsigned p = bp[i];
    int d = p & 511;
    int pos = atomicAdd(&offs[d], 1);
    srt[pos] = p >> 9;
  }
  __syncthreads();
  for (int i = t; i < n; i += 256) csr[gb0 + i] = (int)srt[i];
}

// ---------------- xs = dinv[i] * x[i], padded [N,24] ----------------
__global__ void k_xpad(const float* __restrict__ x, const float* __restrict__ dinv,
                       float* __restrict__ xs) {
  int idx = blockIdx.x * 256 + threadIdx.x;
  if (idx >= N_NODES * 24) return;
  int r = idx / 24, c = idx - r * 24;
  xs[idx] = (c < 21) ? x[r * 21 + c] * dinv[r] : 0.f;
}

// ---------------- conv1 aggregation: aggx = A_norm @ x   [N,24 padded] ----------
__global__ __launch_bounds__(256) void k_aggx(
    const float4* __restrict__ xs4, const float* __restrict__ dinv,
    const int* __restrict__ rowoff, const int* __restrict__ cnt,
    const int* __restrict__ csr, float4* __restrict__ aggx4) {
  int lane = threadIdx.x & 63, wave = threadIdx.x >> 6;
  int j = lane / 6, c4 = lane - j * 6;
  if (j >= 10) return;
  int i = blockIdx.x * 40 + wave * 10 + j;     // 2500*40 == 100000 exactly
  float di = dinv[i];
  int start = rowoff[i], len = cnt[i];
  float4 a0 = xs4[i * 6 + c4];                 // self-loop term (pre-scaled)
  float4 a1 = make_float4(0.f, 0.f, 0.f, 0.f);
  int e = 0;
  for (; e + 1 < len; e += 2) {
    int s0 = csr[start + e], s1 = csr[start + e + 1];
    float4 u0 = xs4[s0 * 6 + c4];
    float4 u1 = xs4[s1 * 6 + c4];
    a0.x += u0.x; a0.y += u0.y; a0.z += u0.z; a0.w += u0.w;
    a1.x += u1.x; a1.y += u1.y; a1.z += u1.z; a1.w += u1.w;
  }
  if (e < len) {
    int s0 = csr[start + e];
    float4 u0 = xs4[s0 * 6 + c4];
    a0.x += u0.x; a0.y += u0.y; a0.z += u0.z; a0.w += u0.w;
  }
  float4 r;
  r.x = di * (a0.x + a1.x); r.y = di * (a0.y + a1.y);
  r.z = di * (a0.z + a1.z); r.w = di * (a0.w + a1.w);
  aggx4[i * 6 + c4] = r;
}

// ---------------- gemm1: h1 = relu(aggx @ W1 + b1)   [N,256], K=21 (stride 24) ---
__global__ __launch_bounds__(256) void k_gemm1(const float4* __restrict__ aggx4,
                                               const float* __restrict__ W1,
                                               const float* __restrict__ b1,
                                               float* __restrict__ h1) {
  __shared__ float As[32][24];
  int t = threadIdx.x;
  int base = blockIdx.x * 32;           // 3125 * 32 == 100000 exactly
  for (int idx = t; idx < 32 * 6; idx += 256) {
    int m = idx / 6, q = idx - m * 6;
    *(float4*)(&As[m][q * 4]) = aggx4[(base + m) * 6 + q];
  }
  float w[21];
#pragma unroll
  for (int k = 0; k < 21; ++k) w[k] = W1[k * 256 + t];
  float bias = b1[t];
  __syncthreads();
  for (int m = 0; m < 32; ++m) {
    float acc = bias;
#pragma unroll
    for (int k = 0; k < 21; ++k) acc = fmaf(As[m][k], w[k], acc);
    h1[(size_t)(base + m) * 256 + t] = fmaxf(acc, 0.f);
  }
}

// ---------------- W prep: split fp32 W[k][n] -> transposed f16 hi/lo Wt[n][kpad] ---
template <int K, int KPAD, int NOUT, int NR>
__global__ void k_wsplit(const float* __restrict__ W, _Float16* __restrict__ Wh,
                         _Float16* __restrict__ Wl) {
  int idx = blockIdx.x * 256 + threadIdx.x;
  if (idx >= NR * KPAD) return;
  int n = idx / KPAD, k = idx % KPAD;
  float v = (n < NOUT && k < K) ? W[k * NOUT + n] : 0.f;
  _Float16 h = (_Float16)v;              // RNE
  Wh[idx] = h;
  Wl[idx] = (_Float16)(v - (float)h);
}

// ---------------- MFMA GEMM: C = f(A)[N,K] @ W[K,NOUT] (+bias), split-f16 -------
template <int K, int KPAD, int NT, int MT, int WR, int WC, bool BN, bool STATS, bool F16OUT>
__global__ __launch_bounds__(256, 3) void k_mgemm(
    const float* __restrict__ A, const _Float16* __restrict__ Wth,
    const _Float16* __restrict__ Wtl, const float* __restrict__ bias,
    const float* __restrict__ bn_a, const float* __restrict__ bn_c,
    const float* __restrict__ rowscale, void* __restrict__ Cv, int NOUTr,
    float* __restrict__ sums, float* __restrict__ sqs) {
  constexpr int BM = WR * MT * 16;
  constexpr int NR = WC * NT * 16;
  constexpr int BKP = 40;                // 32 + 8 pad (80 B rows)
  constexpr int ABYTES = BM * BKP * 2;
  constexpr int BBYTES = NR * BKP * 2;
  __shared__ __align__(16) char smem[2 * ABYTES + 2 * BBYTES];
  _Float16* Ah = (_Float16*)smem;
  _Float16* Al = (_Float16*)(smem + ABYTES);
  _Float16* Bh = (_Float16*)(smem + 2 * ABYTES);
  _Float16* Bl = (_Float16*)(smem + 2 * ABYTES + BBYTES);
  float* C = (float*)Cv;
  _Float16* C16 = (_Float16*)Cv;

  const int tid = threadIdx.x;
  const int lane = tid & 63, wave = tid >> 6;
  const int wr = wave % WR, wc = wave / WR;
  const int quad = lane >> 4, ln = lane & 15;
  const int rowbase = blockIdx.x * BM;

  fx4 acc[MT][NT];
#pragma unroll
  for (int mt = 0; mt < MT; ++mt)
#pragma unroll
    for (int j = 0; j < NT; ++j) acc[mt][j] = (fx4){0.f, 0.f, 0.f, 0.f};

  for (int kc = 0; kc < KPAD / 32; ++kc) {
    __syncthreads();
    // stage A chunk: fp32 -> (BN+ReLU) -> f16 hi/lo
    for (int idx = tid; idx < BM * 8; idx += 256) {
      int m = idx >> 3, q = idx & 7;
      int gi = rowbase + m;
      int k = kc * 32 + q * 4;
      float vv[4] = {0.f, 0.f, 0.f, 0.f};
      if (gi < N_NODES && k < K) {
        float4 v = *(const float4*)(A + (size_t)gi * K + k);
        if constexpr (BN) {
          float4 a4 = *(const float4*)(bn_a + k);
          float4 c4 = *(const float4*)(bn_c + k);
          v.x = fmaxf(fmaf(v.x, a4.x, c4.x), 0.f);
          v.y = fmaxf(fmaf(v.y, a4.y, c4.y), 0.f);
          v.z = fmaxf(fmaf(v.z, a4.z, c4.z), 0.f);
          v.w = fmaxf(fmaf(v.w, a4.w, c4.w), 0.f);
        }
        vv[0] = v.x; vv[1] = v.y; vv[2] = v.z; vv[3] = v.w;
      }
      f16x4 hi, lo;
#pragma unroll
      for (int t = 0; t < 4; ++t) {
        _Float16 h = (_Float16)vv[t];
        hi[t] = h;
        lo[t] = (_Float16)(vv[t] - (float)h);
      }
      *(f16x4*)(Ah + m * BKP + q * 4) = hi;
      *(f16x4*)(Al + m * BKP + q * 4) = lo;
    }
    // stage W tiles (pre-split, pre-transposed, zero-padded)
    for (int idx = tid; idx < NR * 4; idx += 256) {
      int n = idx >> 2, p = idx & 3;
      int src = n * KPAD + kc * 32 + p * 8;
      *(f16x8*)(Bh + n * BKP + p * 8) = *(const f16x8*)(Wth + src);
      *(f16x8*)(Bl + n * BKP + p * 8) = *(const f16x8*)(Wtl + src);
    }
    __syncthreads();
    f16x8 ah[MT], al[MT];
#pragma unroll
    for (int mt = 0; mt < MT; ++mt) {
      int r = (wr * MT + mt) * 16 + ln;
      ah[mt] = *(const f16x8*)(Ah + r * BKP + quad * 8);
      al[mt] = *(const f16x8*)(Al + r * BKP + quad * 8);
    }
#pragma unroll
    for (int j = 0; j < NT; ++j) {
      int n = (wc * NT + j) * 16 + ln;
      f16x8 bh = *(const f16x8*)(Bh + n * BKP + quad * 8);
      f16x8 bl = *(const f16x8*)(Bl + n * BKP + quad * 8);
#pragma unroll
      for (int mt = 0; mt < MT; ++mt)
        acc[mt][j] = __builtin_amdgcn_mfma_f32_16x16x32_f16(ah[mt], bh, acc[mt][j], 0, 0, 0);
#pragma unroll
      for (int mt = 0; mt < MT; ++mt)
        acc[mt][j] = __builtin_amdgcn_mfma_f32_16x16x32_f16(al[mt], bh, acc[mt][j], 0, 0, 0);
#pragma unroll
      for (int mt = 0; mt < MT; ++mt)
        acc[mt][j] = __builtin_amdgcn_mfma_f32_16x16x32_f16(ah[mt], bl, acc[mt][j], 0, 0, 0);
    }
  }

  float rsv[MT][4];
#pragma unroll
  for (int mt = 0; mt < MT; ++mt)
#pragma unroll
    for (int r = 0; r < 4; ++r) {
      int gi = rowbase + (wr * MT + mt) * 16 + quad * 4 + r;
      rsv[mt][r] = (rowscale != nullptr && gi < N_NODES) ? rowscale[gi] : 1.f;
    }

  float scA[NT], sqA[NT];
#pragma unroll
  for (int j = 0; j < NT; ++j) {
    int col = (wc * NT + j) * 16 + ln;
    float bs = (bias != nullptr && col < NOUTr) ? bias[col] : 0.f;
    float sc = 0.f, sq = 0.f;
#pragma unroll
    for (int mt = 0; mt < MT; ++mt) {
      int rb = rowbase + (wr * MT + mt) * 16 + quad * 4;
#pragma unroll
      for (int r = 0; r < 4; ++r) {
        int gi = rb + r;
        if (gi < N_NODES && col < NOUTr) {
          float v = (acc[mt][j][r] + bs) * rsv[mt][r];
          if constexpr (F16OUT)
            C16[(size_t)gi * NOUTr + col] = (_Float16)v;
          else
            C[(size_t)gi * NOUTr + col] = v;
          sc += v;
          sq = fmaf(v, v, sq);
        }
      }
    }
    scA[j] = sc;
    sqA[j] = sq;
  }
  if constexpr (STATS) {
    float* s_s = (float*)smem;           // reuse A region (safe after barrier)
    float* s_q = s_s + NR;
    __syncthreads();
    for (int c = tid; c < 2 * NR; c += 256) s_s[c] = 0.f;
    __syncthreads();
#pragma unroll
    for (int j = 0; j < NT; ++j) {
      float sc = scA[j], sq = sqA[j];
      sc += __shfl_xor(sc, 16); sq += __shfl_xor(sq, 16);
      sc += __shfl_xor(sc, 32); sq += __shfl_xor(sq, 32);
      if (quad == 0) {
        int c = (wc * NT + j) * 16 + ln;
        atomicAdd(&s_s[c], sc);
        atomicAdd(&s_q[c], sq);
      }
    }
    __syncthreads();
    int rep = (blockIdx.x & (NREP - 1));
    for (int c = tid; c < NR; c += 256) {
      if (c < NOUTr) {
        atomicAdd(&sums[rep * NOUTr + c], s_s[c]);   // stride NOUTr = consumer stride
        atomicAdd(&sqs[rep * NOUTr + c], s_q[c]);
      }
    }
  }
}

// ---------------- conv2 aggregation: g2 = A_norm @ t2 + b2   [N,112] -------------
__global__ __launch_bounds__(256) void k_agg2(
    const f16x8* __restrict__ t2s8, const float* __restrict__ dinv,
    const int* __restrict__ rowoff, const int* __restrict__ cnt,
    const int* __restrict__ csr, const float* __restrict__ b2,
    float* __restrict__ g2) {
  int lane = threadIdx.x & 63, wave = threadIdx.x >> 6;
  int j = lane / 14, c = lane - j * 14;
  if (j >= 4) return;
  int i = blockIdx.x * 16 + wave * 4 + j;      // 6250*16 == 100000 exactly
  float di = dinv[i];
  int start = rowoff[i], len = cnt[i];
  f16x8 u = t2s8[i * 14 + c];                  // self-loop term
  fx4 a0, a1, b0, b1;
#pragma unroll
  for (int t = 0; t < 4; ++t) { a0[t] = (float)u[t]; b0[t] = (float)u[t + 4]; }
  a1 = (fx4){0.f, 0.f, 0.f, 0.f};
  b1 = (fx4){0.f, 0.f, 0.f, 0.f};
  int e = 0;
  for (; e + 1 < len; e += 2) {
    int s0 = csr[start + e], s1 = csr[start + e + 1];
    f16x8 u0 = t2s8[s0 * 14 + c];
    f16x8 u1 = t2s8[s1 * 14 + c];
#pragma unroll
    for (int t = 0; t < 4; ++t) {
      a0[t] += (float)u0[t]; b0[t] += (float)u0[t + 4];
      a1[t] += (float)u1[t]; b1[t] += (float)u1[t + 4];
    }
  }
  if (e < len) {
    int s0 = csr[start + e];
    f16x8 u0 = t2s8[s0 * 14 + c];
#pragma unroll
    for (int t = 0; t < 4; ++t) { a0[t] += (float)u0[t]; b0[t] += (float)u0[t + 4]; }
  }
  float4 blo = *(const float4*)(b2 + c * 8);
  float4 bhi = *(const float4*)(b2 + c * 8 + 4);
  float4 r0, r1;
  r0.x = fmaf(di, a0[0] + a1[0], blo.x); r0.y = fmaf(di, a0[1] + a1[1], blo.y);
  r0.z = fmaf(di, a0[2] + a1[2], blo.z); r0.w = fmaf(di, a0[3] + a1[3], blo.w);
  r1.x = fmaf(di, b0[0] + b1[0], bhi.x); r1.y = fmaf(di, b0[1] + b1[1], bhi.y);
  r1.z = fmaf(di, b0[2] + b1[2], bhi.z); r1.w = fmaf(di, b0[3] + b1[3], bhi.w);
  *(float4*)(g2 + (size_t)i * 112 + c * 8) = r0;
  *(float4*)(g2 + (size_t)i * 112 + c * 8 + 4) = r1;
}

// ---------------- BN column stats (standalone, for g2) ----------------
template <int C>
__global__ void k_colstats(const float* __restrict__ X, float* __restrict__ sums,
                           float* __restrict__ sqs) {
  int c = threadIdx.x;
  if (c >= C) return;
  int chunk = (N_NODES + gridDim.x - 1) / gridDim.x;
  int i0 = blockIdx.x * chunk;
  int i1 = min(N_NODES, i0 + chunk);
  float s = 0.f, q = 0.f;
  for (int i = i0; i < i1; ++i) {
    float v = X[(size_t)i * C + c];
    s += v;
    q = fmaf(v, v, q);
  }
  int rep = (blockIdx.x & (NREP - 1));
  atomicAdd(&sums[rep * C + c], s);
  atomicAdd(&sqs[rep * C + c], q);
}

template <int C>
__global__ void k_bnfinal(const float* __restrict__ sums, const float* __restrict__ sqs,
                          const float* __restrict__ gamma, const float* __restrict__ beta,
                          float* __restrict__ bn_a, float* __restrict__ bn_c) {
  int c = threadIdx.x;
  if (c >= C) return;
  float s = 0.f, q = 0.f;
#pragma unroll
  for (int r = 0; r < NREP; ++r) {
    s += sums[r * C + c];
    q += sqs[r * C + c];
  }
  const float inv_n = 1.0f / (float)N_NODES;
  float mean = s * inv_n;
  float var = fmaxf(q * inv_n - mean * mean, 0.f);
  float rstd = 1.0f / sqrtf(var + 1e-5f);
  float a = gamma[c] * rstd;
  bn_a[c] = a;
  bn_c[c] = beta[c] - mean * a;
}

// ---------------- final: out = relu(bn3(h4)) @ lin4_w + lin4_b ----------------
__global__ void k_final(const float* __restrict__ h4, const float* __restrict__ bn_a,
                        const float* __restrict__ bn_c, const float* __restrict__ w4,
                        const float* __restrict__ b4, float* __restrict__ out) {
  int lane = threadIdx.x & 63;
  int i = blockIdx.x * 4 + (threadIdx.x >> 6);   // 25000*4 == 100000 exactly
  float acc = fmaxf(fmaf(h4[(size_t)i * 100 + lane], bn_a[lane], bn_c[lane]), 0.f) * w4[lane];
  if (lane < 36) {
    int k = lane + 64;
    acc += fmaxf(fmaf(h4[(size_t)i * 100 + k], bn_a[k], bn_c[k]), 0.f) * w4[k];
  }
#pragma unroll
  for (int off = 32; off >= 1; off >>= 1) acc += __shfl_down(acc, off);
  if (lane == 0) out[i] = acc + b4[0];
}

extern "C" void kernel_launch(void* const* d_in, const int* in_sizes, int n_in,
                              void* d_out, int out_size, void* d_ws, size_t ws_size,
                              hipStream_t stream) {
  const float* x   = (const float*)d_in[0];
  const int*   ei  = (const int*)d_in[1];
  const float* W1  = (const float*)d_in[2];
  const float* b1  = (const float*)d_in[3];
  const float* W2  = (const float*)d_in[4];
  const float* b2  = (const float*)d_in[5];
  const float* l2w = (const float*)d_in[6];
  const float* l2b = (const float*)d_in[7];
  const float* l3w = (const float*)d_in[8];
  const float* l3b = (const float*)d_in[9];
  const float* l4w = (const float*)d_in[10];
  const float* l4b = (const float*)d_in[11];
  const float* g1  = (const float*)d_in[12];
  const float* be1 = (const float*)d_in[13];
  const float* g2w = (const float*)d_in[14];
  const float* be2 = (const float*)d_in[15];
  const float* g3  = (const float*)d_in[16];
  const float* be3 = (const float*)d_in[17];
  float* out = (float*)d_out;

  // ---- workspace carve-up (~206 MB) ----
  char* base = (char*)d_ws;
  size_t off = 0;
  auto alloc = [&](size_t bytes) -> char* {
    char* p = base + off;
    off = (off + bytes + 255) & ~(size_t)255;
    return p;
  };
  int*   cnt    = (int*)alloc((size_t)N_NODES * 4);
  int*   rowoff = (int*)alloc((size_t)N_NODES * 4);
  float* dinv   = (float*)alloc((size_t)N_NODES * 4);
  int*   csr    = (int*)alloc((size_t)N_EDGES * 4);
  unsigned* binned = (unsigned*)alloc((size_t)NBUCK * BCAP * 4);  // 9.6 MB
  int*   gcount = (int*)alloc(NBUCK * 4);
  int*   gbase  = (int*)alloc(NBUCK * 4);
  float* stats  = (float*)alloc((size_t)NREP * 960 * 4);
  float* bnco   = (float*)alloc(960 * 4);
  float* xs     = (float*)alloc((size_t)N_NODES * 24 * 4);   // padded dinv-scaled x
  float* aggx   = (float*)alloc((size_t)N_NODES * 24 * 4);   // padded conv1 agg
  float* h1     = (float*)alloc((size_t)N_NODES * 256 * 4);  // reused as h3
  _Float16* t2s = (_Float16*)alloc((size_t)N_NODES * 112 * 2); // f16 dinv-scaled h1W2
  float* g2buf  = (float*)alloc((size_t)N_NODES * 112 * 4);  // reused as h4
  _Float16* wt2h = (_Float16*)alloc(112 * 256 * 2);
  _Float16* wt2l = (_Float16*)alloc(112 * 256 * 2);
  _Float16* wt3h = (_Float16*)alloc(256 * 128 * 2);
  _Float16* wt3l = (_Float16*)alloc(256 * 128 * 2);
  _Float16* wt4h = (_Float16*)alloc(112 * 256 * 2);
  _Float16* wt4l = (_Float16*)alloc(112 * 256 * 2);
  float* h4 = g2buf;   // g2buf dead after h3-mgemm; h4 [N,100] fits in [N,112]

  float* sums1 = stats;                     // NREP*112
  float* sqs1  = sums1 + NREP * 112;
  float* sums2 = sqs1 + NREP * 112;         // NREP*256
  float* sqs2  = sums2 + NREP * 256;
  float* sums3 = sqs2 + NREP * 256;         // NREP*100 used
  float* sqs3  = sums3 + NREP * 112;
  float* bn_a1 = bnco + 0,   *bn_c1 = bnco + 112;
  float* bn_a2 = bnco + 224, *bn_c2 = bnco + 480;
  float* bn_a3 = bnco + 736, *bn_c3 = bnco + 848;

  hipMemsetAsync(gcount, 0, NBUCK * 4, stream);
  hipMemsetAsync(stats, 0, (size_t)NREP * 960 * 4, stream);

  // CSR build: LDS counting sort (dense writes; replaces hist/dinv/scans/fill)
  k_bin<<<NBUCK, 256, 0, stream>>>(ei, binned, gcount);
  k_bscan<<<1, 256, 0, stream>>>(gcount, gbase);
  k_csr<<<NBUCK, 256, 0, stream>>>(binned, gcount, gbase, rowoff, cnt, dinv, csr);

  // W splits (independent, tiny)
  k_wsplit<256, 256, 112, 112><<<112, 256, 0, stream>>>(W2, wt2h, wt2l);
  k_wsplit<112, 128, 256, 256><<<128, 256, 0, stream>>>(l2w, wt3h, wt3l);
  k_wsplit<256, 256, 100, 112><<<112, 256, 0, stream>>>(l3w, wt4h, wt4l);

  k_xpad<<<(N_NODES * 24 + 255) / 256, 256, 0, stream>>>(x, dinv, xs);
  k_aggx<<<2500, 256, 0, stream>>>((const float4*)xs, dinv, rowoff, cnt, csr,
                                   (float4*)aggx);
  k_gemm1<<<3125, 256, 0, stream>>>((const float4*)aggx, W1, b1, h1);

  // t2s = dinv * (h1 @ W2), f16 out: K=256, NOUT=112; waves 4x1, MT=2,NT=7
  k_mgemm<256, 256, 7, 2, 4, 1, false, false, true><<<782, 256, 0, stream>>>(
      h1, wt2h, wt2l, nullptr, nullptr, nullptr, dinv, t2s, 112, nullptr, nullptr);
  k_agg2<<<6250, 256, 0, stream>>>((const f16x8*)t2s, dinv, rowoff, cnt, csr, b2,
                                   g2buf);

  k_colstats<112><<<1600, 128, 0, stream>>>(g2buf, sums1, sqs1);
  k_bnfinal<112><<<1, 128, 0, stream>>>(sums1, sqs1, g1, be1, bn_a1, bn_c1);

  // h3 = relu(bn1(g2)) @ lin2_w: K=112, NOUT=256; waves 2x2, MT=2,NT=8
  k_mgemm<112, 128, 8, 2, 2, 2, true, true, false><<<1563, 256, 0, stream>>>(
      g2buf, wt3h, wt3l, l2b, bn_a1, bn_c1, nullptr, h1, 256, sums2, sqs2);
  k_bnfinal<256><<<1, 256, 0, stream>>>(sums2, sqs2, g2w, be2, bn_a2, bn_c2);

  // h4 = relu(bn2(h3)) @ lin3_w: K=256, NOUT=100; waves 4x1, MT=2,NT=7
  k_mgemm<256, 256, 7, 2, 4, 1, true, true, false><<<782, 256, 0, stream>>>(
      h1, wt4h, wt4l, l3b, bn_a2, bn_c2, nullptr, h4, 100, sums3, sqs3);
  k_bnfinal<100><<<1, 128, 0, stream>>>(sums3, sqs3, g3, be3, bn_a3, bn_c3);

  k_final<<<25000, 256, 0, stream>>>(h4, bn_a3, bn_c3, l4w, l4b, out);
}

// Round 7
// 467.752 us; speedup vs baseline: 3.1080x; 1.0761x over previous
//
#include <hip/hip_runtime.h>

#define N_NODES 100000
#define N_EDGES 1600000

typedef _Float16 f16x8 __attribute__((ext_vector_type(8)));
typedef _Float16 f16x4 __attribute__((ext_vector_type(4)));
typedef _Float16 f16x2 __attribute__((ext_vector_type(2)));
typedef float fx4 __attribute__((ext_vector_type(4)));

#define NREP 16     // stats-accumulator replication to de-contend atomics
#define NBUCK 196   // ceil(100000/512) buckets of 512 nodes
#define CHUNK 8192  // edges per k_bin block
#define BCAP 12288  // per-bucket slot capacity

// ---------------- CSR build, pass 1: LDS counting-sort chunks by bucket --------
__global__ __launch_bounds__(256) void k_bin(const int* __restrict__ ei,
                                             unsigned* __restrict__ binned,
                                             int* __restrict__ gcount) {
  __shared__ unsigned pr[CHUNK];
  __shared__ unsigned srt[CHUNK];
  __shared__ unsigned char bk[CHUNK];
  __shared__ int hist[256], scanb[256], offs[256], bs[256], gb[256];
  const int t = threadIdx.x;
  const int e0 = blockIdx.x * CHUNK;
  const int n = min(CHUNK, N_EDGES - e0);
  hist[t] = 0;
  __syncthreads();
  for (int i = t; i < n; i += 256) {
    int src = ei[e0 + i], dst = ei[N_EDGES + e0 + i];
    int b = dst >> 9;
    pr[i] = ((unsigned)src << 9) | (unsigned)(dst & 511);
    bk[i] = (unsigned char)b;
    atomicAdd(&hist[b], 1);
  }
  __syncthreads();
  int v = hist[t];
  scanb[t] = v;
  __syncthreads();
  for (int off = 1; off < 256; off <<= 1) {
    int a = (t >= off) ? scanb[t - off] : 0;
    __syncthreads();
    scanb[t] += a;
    __syncthreads();
  }
  offs[t] = scanb[t] - v;
  bs[t] = scanb[t] - v;
  __syncthreads();
  for (int i = t; i < n; i += 256) {
    int b = bk[i];
    int p = atomicAdd(&offs[b], 1);
    srt[p] = pr[i];
  }
  if (t < NBUCK && v > 0) gb[t] = atomicAdd(&gcount[t], v);
  __syncthreads();
  int wave = t >> 6, lane = t & 63;
  for (int b = wave; b < NBUCK; b += 4) {
    int c = hist[b];
    if (c == 0) continue;
    int ls = bs[b], base = gb[b];
    unsigned* dstp = binned + (size_t)b * BCAP + base;
    for (int i = lane; i < c; i += 64) dstp[i] = srt[ls + i];
  }
}

__global__ void k_bscan(const int* __restrict__ gcount, int* __restrict__ gbase) {
  __shared__ int s[256];
  int t = threadIdx.x;
  int v = (t < NBUCK) ? gcount[t] : 0;
  s[t] = v;
  __syncthreads();
  for (int off = 1; off < 256; off <<= 1) {
    int a = (t >= off) ? s[t - off] : 0;
    __syncthreads();
    s[t] += a;
    __syncthreads();
  }
  if (t < NBUCK) gbase[t] = s[t] - v;
}

__global__ __launch_bounds__(256) void k_csr(const unsigned* __restrict__ binned,
                                             const int* __restrict__ gcount,
                                             const int* __restrict__ gbase,
                                             int* __restrict__ rowoff,
                                             int* __restrict__ cnt,
                                             float* __restrict__ dinv,
                                             int* __restrict__ csr) {
  __shared__ int hist[512], offs[512], ps[256];
  __shared__ unsigned srt[BCAP];
  const int b = blockIdx.x, t = threadIdx.x;
  const int n = min(gcount[b], BCAP);
  const int gb0 = gbase[b];
  const unsigned* bp = binned + (size_t)b * BCAP;
  hist[t] = 0;
  hist[t + 256] = 0;
  __syncthreads();
  for (int i = t; i < n; i += 256) atomicAdd(&hist[bp[i] & 511], 1);
  __syncthreads();
  int e0v = hist[2 * t], e1v = hist[2 * t + 1];
  ps[t] = e0v + e1v;
  __syncthreads();
  for (int off = 1; off < 256; off <<= 1) {
    int a = (t >= off) ? ps[t - off] : 0;
    __syncthreads();
    ps[t] += a;
    __syncthreads();
  }
  int excl = ps[t] - (e0v + e1v);
  offs[2 * t] = excl;
  offs[2 * t + 1] = excl + e0v;
  __syncthreads();
#pragma unroll
  for (int u = 0; u < 2; ++u) {
    int j = 2 * t + u;
    int nd = (b << 9) + j;
    if (nd < N_NODES) {
      int c = hist[j];
      cnt[nd] = c;
      dinv[nd] = rsqrtf((float)(c + 1));
      rowoff[nd] = gb0 + offs[j];
    }
  }
  __syncthreads();
  for (int i = t; i < n; i += 256) {
    unsigned p = bp[i];
    int d = p & 511;
    int pos = atomicAdd(&offs[d], 1);
    srt[pos] = p >> 9;
  }
  __syncthreads();
  for (int i = t; i < n; i += 256) csr[gb0 + i] = (int)srt[i];
}

// ---------------- xs = dinv[i] * x[i], padded [N,24] ----------------
__global__ void k_xpad(const float* __restrict__ x, const float* __restrict__ dinv,
                       float* __restrict__ xs) {
  int idx = blockIdx.x * 256 + threadIdx.x;
  if (idx >= N_NODES * 24) return;
  int r = idx / 24, c = idx - r * 24;
  xs[idx] = (c < 21) ? x[r * 21 + c] * dinv[r] : 0.f;
}

// ---------------- conv1 aggregation ----------------
__global__ __launch_bounds__(256) void k_aggx(
    const float4* __restrict__ xs4, const float* __restrict__ dinv,
    const int* __restrict__ rowoff, const int* __restrict__ cnt,
    const int* __restrict__ csr, float4* __restrict__ aggx4) {
  int lane = threadIdx.x & 63, wave = threadIdx.x >> 6;
  int j = lane / 6, c4 = lane - j * 6;
  if (j >= 10) return;
  int i = blockIdx.x * 40 + wave * 10 + j;
  float di = dinv[i];
  int start = rowoff[i], len = cnt[i];
  float4 a0 = xs4[i * 6 + c4];
  float4 a1 = make_float4(0.f, 0.f, 0.f, 0.f);
  int e = 0;
  for (; e + 1 < len; e += 2) {
    int s0 = csr[start + e], s1 = csr[start + e + 1];
    float4 u0 = xs4[s0 * 6 + c4];
    float4 u1 = xs4[s1 * 6 + c4];
    a0.x += u0.x; a0.y += u0.y; a0.z += u0.z; a0.w += u0.w;
    a1.x += u1.x; a1.y += u1.y; a1.z += u1.z; a1.w += u1.w;
  }
  if (e < len) {
    int s0 = csr[start + e];
    float4 u0 = xs4[s0 * 6 + c4];
    a0.x += u0.x; a0.y += u0.y; a0.z += u0.z; a0.w += u0.w;
  }
  float4 r;
  r.x = di * (a0.x + a1.x); r.y = di * (a0.y + a1.y);
  r.z = di * (a0.z + a1.z); r.w = di * (a0.w + a1.w);
  aggx4[i * 6 + c4] = r;
}

// ---------------- gemm1: h1 = relu(aggx @ W1 + b1), f16 out ----------------
__global__ __launch_bounds__(256) void k_gemm1(const float4* __restrict__ aggx4,
                                               const float* __restrict__ W1,
                                               const float* __restrict__ b1,
                                               _Float16* __restrict__ h1) {
  __shared__ float As[32][24];
  int t = threadIdx.x;
  int base = blockIdx.x * 32;
  for (int idx = t; idx < 32 * 6; idx += 256) {
    int m = idx / 6, q = idx - m * 6;
    *(float4*)(&As[m][q * 4]) = aggx4[(base + m) * 6 + q];
  }
  float w[21];
#pragma unroll
  for (int k = 0; k < 21; ++k) w[k] = W1[k * 256 + t];
  float bias = b1[t];
  __syncthreads();
  for (int m = 0; m < 32; ++m) {
    float acc = bias;
#pragma unroll
    for (int k = 0; k < 21; ++k) acc = fmaf(As[m][k], w[k], acc);
    h1[(size_t)(base + m) * 256 + t] = (_Float16)fmaxf(acc, 0.f);
  }
}

// ---------------- W prep ----------------
template <int K, int KPAD, int NOUT, int NR>
__global__ void k_wsplit(const float* __restrict__ W, _Float16* __restrict__ Wh,
                         _Float16* __restrict__ Wl) {
  int idx = blockIdx.x * 256 + threadIdx.x;
  if (idx >= NR * KPAD) return;
  int n = idx / KPAD, k = idx % KPAD;
  float v = (n < NOUT && k < K) ? W[k * NOUT + n] : 0.f;
  _Float16 h = (_Float16)v;
  Wh[idx] = h;
  Wl[idx] = (_Float16)(v - (float)h);
}

// ---------------- MFMA GEMM, operand-swapped (D rows=channels, cols=nodes) ------
// A-operand = W (hi/lo split), B-operand = nodes (f16, hi only). Per lane the
// D fragment holds 4 CONSECUTIVE CHANNELS of ONE node -> packed vector stores.
template <int K, int KPAD, int NT, int MT, int WR, int WC, int MINW,
          bool BN, bool STATS, bool F16IN, bool F16OUT>
__global__ __launch_bounds__(256, MINW) void k_mgemm(
    const void* __restrict__ Av, const _Float16* __restrict__ Wth,
    const _Float16* __restrict__ Wtl, const float* __restrict__ bias,
    const float* __restrict__ bn_a, const float* __restrict__ bn_c,
    const float* __restrict__ rowscale, void* __restrict__ Cv, int NOUTr,
    float* __restrict__ sums, float* __restrict__ sqs) {
  constexpr int BM = WR * MT * 16;       // nodes per block
  constexpr int NR = WC * NT * 16;       // padded channels
  constexpr int BKP = 40;                // 32 + 8 pad (80 B rows)
  constexpr int ABYTES = BM * BKP * 2;   // node tile (hi only)
  constexpr int BBYTES = NR * BKP * 2;
  __shared__ __align__(16) char smem[ABYTES + 2 * BBYTES];
  _Float16* Ah = (_Float16*)smem;
  _Float16* Bh = (_Float16*)(smem + ABYTES);
  _Float16* Bl = (_Float16*)(smem + ABYTES + BBYTES);
  const float* A32 = (const float*)Av;
  const _Float16* A16 = (const _Float16*)Av;
  float* C = (float*)Cv;
  _Float16* C16 = (_Float16*)Cv;

  const int tid = threadIdx.x;
  const int lane = tid & 63, wave = tid >> 6;
  const int wr = wave % WR, wc = wave / WR;
  const int quad = lane >> 4, ln = lane & 15;
  const int rowbase = blockIdx.x * BM;

  fx4 acc[MT][NT];
#pragma unroll
  for (int mt = 0; mt < MT; ++mt)
#pragma unroll
    for (int j = 0; j < NT; ++j) acc[mt][j] = (fx4){0.f, 0.f, 0.f, 0.f};

  for (int kc = 0; kc < KPAD / 32; ++kc) {
    __syncthreads();
    // stage node chunk: 16-B f16x8 per thread (even bank spread)
    for (int idx = tid; idx < BM * 4; idx += 256) {
      int m = idx >> 2, q = idx & 3;
      int gi = rowbase + m;
      int k = kc * 32 + q * 8;
      f16x8 hv;
#pragma unroll
      for (int t = 0; t < 8; ++t) hv[t] = (_Float16)0;
      if (gi < N_NODES && k < K) {
        if constexpr (F16IN) {
          hv = *(const f16x8*)(A16 + (size_t)gi * K + k);
          if constexpr (BN) {
            float4 a0 = *(const float4*)(bn_a + k);
            float4 a1 = *(const float4*)(bn_a + k + 4);
            float4 c0 = *(const float4*)(bn_c + k);
            float4 c1 = *(const float4*)(bn_c + k + 4);
            float av[8] = {a0.x, a0.y, a0.z, a0.w, a1.x, a1.y, a1.z, a1.w};
            float cv[8] = {c0.x, c0.y, c0.z, c0.w, c1.x, c1.y, c1.z, c1.w};
#pragma unroll
            for (int t = 0; t < 8; ++t)
              hv[t] = (_Float16)fmaxf(fmaf((float)hv[t], av[t], cv[t]), 0.f);
          }
        } else {
          float4 v0 = *(const float4*)(A32 + (size_t)gi * K + k);
          float4 v1 = *(const float4*)(A32 + (size_t)gi * K + k + 4);
          float vv[8] = {v0.x, v0.y, v0.z, v0.w, v1.x, v1.y, v1.z, v1.w};
          if constexpr (BN) {
            float4 a0 = *(const float4*)(bn_a + k);
            float4 a1 = *(const float4*)(bn_a + k + 4);
            float4 c0 = *(const float4*)(bn_c + k);
            float4 c1 = *(const float4*)(bn_c + k + 4);
            float av[8] = {a0.x, a0.y, a0.z, a0.w, a1.x, a1.y, a1.z, a1.w};
            float cv[8] = {c0.x, c0.y, c0.z, c0.w, c1.x, c1.y, c1.z, c1.w};
#pragma unroll
            for (int t = 0; t < 8; ++t)
              vv[t] = fmaxf(fmaf(vv[t], av[t], cv[t]), 0.f);
          }
#pragma unroll
          for (int t = 0; t < 8; ++t) hv[t] = (_Float16)vv[t];
        }
      }
      *(f16x8*)(Ah + m * BKP + q * 8) = hv;
    }
    // stage W tiles (pre-split hi/lo, pre-transposed, zero-padded)
    for (int idx = tid; idx < NR * 4; idx += 256) {
      int n = idx >> 2, p = idx & 3;
      int src = n * KPAD + kc * 32 + p * 8;
      *(f16x8*)(Bh + n * BKP + p * 8) = *(const f16x8*)(Wth + src);
      *(f16x8*)(Bl + n * BKP + p * 8) = *(const f16x8*)(Wtl + src);
    }
    __syncthreads();
    f16x8 nf[MT];
#pragma unroll
    for (int mt = 0; mt < MT; ++mt) {
      int r = (wr * MT + mt) * 16 + ln;
      nf[mt] = *(const f16x8*)(Ah + r * BKP + quad * 8);
    }
#pragma unroll
    for (int j = 0; j < NT; ++j) {
      int n = (wc * NT + j) * 16 + ln;
      f16x8 wh = *(const f16x8*)(Bh + n * BKP + quad * 8);
      f16x8 wl = *(const f16x8*)(Bl + n * BKP + quad * 8);
#pragma unroll
      for (int mt = 0; mt < MT; ++mt)   // W-hi x A
        acc[mt][j] = __builtin_amdgcn_mfma_f32_16x16x32_f16(wh, nf[mt], acc[mt][j], 0, 0, 0);
#pragma unroll
      for (int mt = 0; mt < MT; ++mt)   // W-lo x A
        acc[mt][j] = __builtin_amdgcn_mfma_f32_16x16x32_f16(wl, nf[mt], acc[mt][j], 0, 0, 0);
    }
  }

  // epilogue: lane = node ln, rows = channels quad*4+r (+16*tile) -> packed stores
  float* s_s = (float*)smem;             // stats partials (reuse A region)
  float* s_q = s_s + NR;
  __syncthreads();
  if constexpr (STATS) {
    for (int c = tid; c < 2 * NR; c += 256) s_s[c] = 0.f;
    __syncthreads();
  }
  float rs[MT];
#pragma unroll
  for (int mt = 0; mt < MT; ++mt) {
    int nd = rowbase + (wr * MT + mt) * 16 + ln;
    rs[mt] = (rowscale != nullptr && nd < N_NODES) ? rowscale[nd] : 1.f;
  }
#pragma unroll
  for (int j = 0; j < NT; ++j) {
    int ch0 = (wc * NT + j) * 16 + quad * 4;
    bool cv = ch0 < NOUTr;               // NOUTr % 4 == 0 -> all-or-nothing per quad
    float4 b4 = make_float4(0.f, 0.f, 0.f, 0.f);
    if (cv && bias != nullptr) b4 = *(const float4*)(bias + ch0);
    float sc[4] = {0.f, 0.f, 0.f, 0.f}, sq[4] = {0.f, 0.f, 0.f, 0.f};
#pragma unroll
    for (int mt = 0; mt < MT; ++mt) {
      int nd = rowbase + (wr * MT + mt) * 16 + ln;
      if (nd < N_NODES && cv) {
        float v0 = (acc[mt][j][0] + b4.x) * rs[mt];
        float v1 = (acc[mt][j][1] + b4.y) * rs[mt];
        float v2 = (acc[mt][j][2] + b4.z) * rs[mt];
        float v3 = (acc[mt][j][3] + b4.w) * rs[mt];
        if constexpr (F16OUT) {
          f16x4 o = {(_Float16)v0, (_Float16)v1, (_Float16)v2, (_Float16)v3};
          *(f16x4*)(C16 + (size_t)nd * NOUTr + ch0) = o;
        } else {
          float4 o = make_float4(v0, v1, v2, v3);
          *(float4*)(C + (size_t)nd * NOUTr + ch0) = o;
        }
        if constexpr (STATS) {
          sc[0] += v0; sq[0] = fmaf(v0, v0, sq[0]);
          sc[1] += v1; sq[1] = fmaf(v1, v1, sq[1]);
          sc[2] += v2; sq[2] = fmaf(v2, v2, sq[2]);
          sc[3] += v3; sq[3] = fmaf(v3, v3, sq[3]);
        }
      }
    }
    if constexpr (STATS) {
      if (cv) {
#pragma unroll
        for (int r = 0; r < 4; ++r) {
          float s = sc[r], q = sq[r];
          s += __shfl_xor(s, 1); q += __shfl_xor(q, 1);
          s += __shfl_xor(s, 2); q += __shfl_xor(q, 2);
          s += __shfl_xor(s, 4); q += __shfl_xor(q, 4);
          s += __shfl_xor(s, 8); q += __shfl_xor(q, 8);
          if (ln == 0) {
            atomicAdd(&s_s[ch0 + r], s);
            atomicAdd(&s_q[ch0 + r], q);
          }
        }
      }
    }
  }
  if constexpr (STATS) {
    __syncthreads();
    int rep = (blockIdx.x & (NREP - 1));
    for (int c = tid; c < NR; c += 256) {
      if (c < NOUTr) {
        atomicAdd(&sums[rep * NOUTr + c], s_s[c]);
        atomicAdd(&sqs[rep * NOUTr + c], s_q[c]);
      }
    }
  }
}

// ---------------- conv2 aggregation ----------------
__global__ __launch_bounds__(256) void k_agg2(
    const f16x8* __restrict__ t2s8, const float* __restrict__ dinv,
    const int* __restrict__ rowoff, const int* __restrict__ cnt,
    const int* __restrict__ csr, const float* __restrict__ b2,
    float* __restrict__ g2) {
  int lane = threadIdx.x & 63, wave = threadIdx.x >> 6;
  int j = lane / 14, c = lane - j * 14;
  if (j >= 4) return;
  int i = blockIdx.x * 16 + wave * 4 + j;
  float di = dinv[i];
  int start = rowoff[i], len = cnt[i];
  f16x8 u = t2s8[i * 14 + c];
  fx4 a0, a1, b0, b1;
#pragma unroll
  for (int t = 0; t < 4; ++t) { a0[t] = (float)u[t]; b0[t] = (float)u[t + 4]; }
  a1 = (fx4){0.f, 0.f, 0.f, 0.f};
  b1 = (fx4){0.f, 0.f, 0.f, 0.f};
  int e = 0;
  for (; e + 1 < len; e += 2) {
    int s0 = csr[start + e], s1 = csr[start + e + 1];
    f16x8 u0 = t2s8[s0 * 14 + c];
    f16x8 u1 = t2s8[s1 * 14 + c];
#pragma unroll
    for (int t = 0; t < 4; ++t) {
      a0[t] += (float)u0[t]; b0[t] += (float)u0[t + 4];
      a1[t] += (float)u1[t]; b1[t] += (float)u1[t + 4];
    }
  }
  if (e < len) {
    int s0 = csr[start + e];
    f16x8 u0 = t2s8[s0 * 14 + c];
#pragma unroll
    for (int t = 0; t < 4; ++t) { a0[t] += (float)u0[t]; b0[t] += (float)u0[t + 4]; }
  }
  float4 blo = *(const float4*)(b2 + c * 8);
  float4 bhi = *(const float4*)(b2 + c * 8 + 4);
  float4 r0, r1;
  r0.x = fmaf(di, a0[0] + a1[0], blo.x); r0.y = fmaf(di, a0[1] + a1[1], blo.y);
  r0.z = fmaf(di, a0[2] + a1[2], blo.z); r0.w = fmaf(di, a0[3] + a1[3], blo.w);
  r1.x = fmaf(di, b0[0] + b1[0], bhi.x); r1.y = fmaf(di, b0[1] + b1[1], bhi.y);
  r1.z = fmaf(di, b0[2] + b1[2], bhi.z); r1.w = fmaf(di, b0[3] + b1[3], bhi.w);
  *(float4*)(g2 + (size_t)i * 112 + c * 8) = r0;
  *(float4*)(g2 + (size_t)i * 112 + c * 8 + 4) = r1;
}

// ---------------- BN column stats (standalone, for g2) ----------------
template <int C>
__global__ void k_colstats(const float* __restrict__ X, float* __restrict__ sums,
                           float* __restrict__ sqs) {
  int c = threadIdx.x;
  if (c >= C) return;
  int chunk = (N_NODES + gridDim.x - 1) / gridDim.x;
  int i0 = blockIdx.x * chunk;
  int i1 = min(N_NODES, i0 + chunk);
  float s = 0.f, q = 0.f;
  for (int i = i0; i < i1; ++i) {
    float v = X[(size_t)i * C + c];
    s += v;
    q = fmaf(v, v, q);
  }
  int rep = (blockIdx.x & (NREP - 1));
  atomicAdd(&sums[rep * C + c], s);
  atomicAdd(&sqs[rep * C + c], q);
}

template <int C>
__global__ void k_bnfinal(const float* __restrict__ sums, const float* __restrict__ sqs,
                          const float* __restrict__ gamma, const float* __restrict__ beta,
                          float* __restrict__ bn_a, float* __restrict__ bn_c) {
  int c = threadIdx.x;
  if (c >= C) return;
  float s = 0.f, q = 0.f;
#pragma unroll
  for (int r = 0; r < NREP; ++r) {
    s += sums[r * C + c];
    q += sqs[r * C + c];
  }
  const float inv_n = 1.0f / (float)N_NODES;
  float mean = s * inv_n;
  float var = fmaxf(q * inv_n - mean * mean, 0.f);
  float rstd = 1.0f / sqrtf(var + 1e-5f);
  float a = gamma[c] * rstd;
  bn_a[c] = a;
  bn_c[c] = beta[c] - mean * a;
}

// ---------------- final ----------------
__global__ void k_final(const float* __restrict__ h4, const float* __restrict__ bn_a,
                        const float* __restrict__ bn_c, const float* __restrict__ w4,
                        const float* __restrict__ b4, float* __restrict__ out) {
  int lane = threadIdx.x & 63;
  int i = blockIdx.x * 4 + (threadIdx.x >> 6);
  float acc = fmaxf(fmaf(h4[(size_t)i * 100 + lane], bn_a[lane], bn_c[lane]), 0.f) * w4[lane];
  if (lane < 36) {
    int k = lane + 64;
    acc += fmaxf(fmaf(h4[(size_t)i * 100 + k], bn_a[k], bn_c[k]), 0.f) * w4[k];
  }
#pragma unroll
  for (int off = 32; off >= 1; off >>= 1) acc += __shfl_down(acc, off);
  if (lane == 0) out[i] = acc + b4[0];
}

extern "C" void kernel_launch(void* const* d_in, const int* in_sizes, int n_in,
                              void* d_out, int out_size, void* d_ws, size_t ws_size,
                              hipStream_t stream) {
  const float* x   = (const float*)d_in[0];
  const int*   ei  = (const int*)d_in[1];
  const float* W1  = (const float*)d_in[2];
  const float* b1  = (const float*)d_in[3];
  const float* W2  = (const float*)d_in[4];
  const float* b2  = (const float*)d_in[5];
  const float* l2w = (const float*)d_in[6];
  const float* l2b = (const float*)d_in[7];
  const float* l3w = (const float*)d_in[8];
  const float* l3b = (const float*)d_in[9];
  const float* l4w = (const float*)d_in[10];
  const float* l4b = (const float*)d_in[11];
  const float* g1  = (const float*)d_in[12];
  const float* be1 = (const float*)d_in[13];
  const float* g2w = (const float*)d_in[14];
  const float* be2 = (const float*)d_in[15];
  const float* g3  = (const float*)d_in[16];
  const float* be3 = (const float*)d_in[17];
  float* out = (float*)d_out;

  char* base = (char*)d_ws;
  size_t off = 0;
  auto alloc = [&](size_t bytes) -> char* {
    char* p = base + off;
    off = (off + bytes + 255) & ~(size_t)255;
    return p;
  };
  int*   cnt    = (int*)alloc((size_t)N_NODES * 4);
  int*   rowoff = (int*)alloc((size_t)N_NODES * 4);
  float* dinv   = (float*)alloc((size_t)N_NODES * 4);
  int*   csr    = (int*)alloc((size_t)N_EDGES * 4);
  unsigned* binned = (unsigned*)alloc((size_t)NBUCK * BCAP * 4);
  int*   gcount = (int*)alloc(NBUCK * 4);
  int*   gbase  = (int*)alloc(NBUCK * 4);
  float* stats  = (float*)alloc((size_t)NREP * 960 * 4);
  float* bnco   = (float*)alloc(960 * 4);
  float* xs     = (float*)alloc((size_t)N_NODES * 24 * 4);
  float* aggx   = (float*)alloc((size_t)N_NODES * 24 * 4);
  _Float16* h1  = (_Float16*)alloc((size_t)N_NODES * 256 * 2);  // f16; reused as h3
  _Float16* t2s = (_Float16*)alloc((size_t)N_NODES * 112 * 2);  // f16 dinv-scaled h1W2
  float* g2buf  = (float*)alloc((size_t)N_NODES * 112 * 4);     // reused as h4
  _Float16* wt2h = (_Float16*)alloc(112 * 256 * 2);
  _Float16* wt2l = (_Float16*)alloc(112 * 256 * 2);
  _Float16* wt3h = (_Float16*)alloc(256 * 128 * 2);
  _Float16* wt3l = (_Float16*)alloc(256 * 128 * 2);
  _Float16* wt4h = (_Float16*)alloc(112 * 256 * 2);
  _Float16* wt4l = (_Float16*)alloc(112 * 256 * 2);
  float* h4 = g2buf;   // g2buf dead after h3-mgemm staging; h4 [N,100] fits

  float* sums1 = stats;
  float* sqs1  = sums1 + NREP * 112;
  float* sums2 = sqs1 + NREP * 112;
  float* sqs2  = sums2 + NREP * 256;
  float* sums3 = sqs2 + NREP * 256;
  float* sqs3  = sums3 + NREP * 112;
  float* bn_a1 = bnco + 0,   *bn_c1 = bnco + 112;
  float* bn_a2 = bnco + 224, *bn_c2 = bnco + 480;
  float* bn_a3 = bnco + 736, *bn_c3 = bnco + 848;

  hipMemsetAsync(gcount, 0, NBUCK * 4, stream);
  hipMemsetAsync(stats, 0, (size_t)NREP * 960 * 4, stream);

  k_bin<<<NBUCK, 256, 0, stream>>>(ei, binned, gcount);
  k_bscan<<<1, 256, 0, stream>>>(gcount, gbase);
  k_csr<<<NBUCK, 256, 0, stream>>>(binned, gcount, gbase, rowoff, cnt, dinv, csr);

  k_wsplit<256, 256, 112, 112><<<112, 256, 0, stream>>>(W2, wt2h, wt2l);
  k_wsplit<112, 128, 256, 256><<<128, 256, 0, stream>>>(l2w, wt3h, wt3l);
  k_wsplit<256, 256, 100, 112><<<112, 256, 0, stream>>>(l3w, wt4h, wt4l);

  k_xpad<<<(N_NODES * 24 + 255) / 256, 256, 0, stream>>>(x, dinv, xs);
  k_aggx<<<2500, 256, 0, stream>>>((const float4*)xs, dinv, rowoff, cnt, csr,
                                   (float4*)aggx);
  k_gemm1<<<3125, 256, 0, stream>>>((const float4*)aggx, W1, b1, h1);

  // t2s = dinv*(h1@W2) f16: K=256, f16-in, no BN/stats, f16-out, MINW=4
  k_mgemm<256, 256, 7, 2, 4, 1, 4, false, false, true, true><<<782, 256, 0, stream>>>(
      h1, wt2h, wt2l, nullptr, nullptr, nullptr, dinv, t2s, 112, nullptr, nullptr);
  k_agg2<<<6250, 256, 0, stream>>>((const f16x8*)t2s, dinv, rowoff, cnt, csr, b2,
                                   g2buf);

  k_colstats<112><<<1600, 128, 0, stream>>>(g2buf, sums1, sqs1);
  k_bnfinal<112><<<1, 128, 0, stream>>>(sums1, sqs1, g1, be1, bn_a1, bn_c1);

  // h3 = relu(bn1(g2))@lin2_w + b: K=112, fp32-in+BN, stats, f16-out -> h1 buffer
  k_mgemm<112, 128, 8, 2, 2, 2, 3, true, true, false, true><<<1563, 256, 0, stream>>>(
      g2buf, wt3h, wt3l, l2b, bn_a1, bn_c1, nullptr, h1, 256, sums2, sqs2);
  k_bnfinal<256><<<1, 256, 0, stream>>>(sums2, sqs2, g2w, be2, bn_a2, bn_c2);

  // h4 = relu(bn2(h3))@lin3_w + b: K=256, f16-in+BN, stats, fp32-out
  k_mgemm<256, 256, 7, 2, 4, 1, 4, true, true, true, false><<<782, 256, 0, stream>>>(
      h1, wt4h, wt4l, l3b, bn_a2, bn_c2, nullptr, h4, 100, sums3, sqs3);
  k_bnfinal<100><<<1, 128, 0, stream>>>(sums3, sqs3, g3, be3, bn_a3, bn_c3);

  k_final<<<25000, 256, 0, stream>>>(h4, bn_a3, bn_c3, l4w, l4b, out);
}

// Round 8
// 435.139 us; speedup vs baseline: 3.3410x; 1.0749x over previous
//
#include <hip/hip_runtime.h>

#define N_NODES 100000
#define N_EDGES 1600000

typedef _Float16 f16x8 __attribute__((ext_vector_type(8)));
typedef _Float16 f16x4 __attribute__((ext_vector_type(4)));
typedef float fx4 __attribute__((ext_vector_type(4)));

#define NREP 16     // stats-accumulator replication to de-contend atomics
#define NBUCK 196   // ceil(100000/512) buckets of 512 nodes
#define CHUNK 8192  // edges per k_bin block
#define BCAP 12288  // per-bucket slot capacity

// ---------------- CSR build, pass 1: LDS counting-sort chunks by bucket --------
__global__ __launch_bounds__(256) void k_bin(const int* __restrict__ ei,
                                             unsigned* __restrict__ binned,
                                             int* __restrict__ gcount) {
  __shared__ unsigned pr[CHUNK];
  __shared__ unsigned srt[CHUNK];
  __shared__ unsigned char bk[CHUNK];
  __shared__ int hist[256], scanb[256], offs[256], bs[256], gb[256];
  const int t = threadIdx.x;
  const int e0 = blockIdx.x * CHUNK;
  const int n = min(CHUNK, N_EDGES - e0);
  hist[t] = 0;
  __syncthreads();
  for (int i = t; i < n; i += 256) {
    int src = ei[e0 + i], dst = ei[N_EDGES + e0 + i];
    int b = dst >> 9;
    pr[i] = ((unsigned)src << 9) | (unsigned)(dst & 511);
    bk[i] = (unsigned char)b;
    atomicAdd(&hist[b], 1);
  }
  __syncthreads();
  int v = hist[t];
  scanb[t] = v;
  __syncthreads();
  for (int off = 1; off < 256; off <<= 1) {
    int a = (t >= off) ? scanb[t - off] : 0;
    __syncthreads();
    scanb[t] += a;
    __syncthreads();
  }
  offs[t] = scanb[t] - v;
  bs[t] = scanb[t] - v;
  __syncthreads();
  for (int i = t; i < n; i += 256) {
    int b = bk[i];
    int p = atomicAdd(&offs[b], 1);
    srt[p] = pr[i];
  }
  if (t < NBUCK && v > 0) gb[t] = atomicAdd(&gcount[t], v);
  __syncthreads();
  int wave = t >> 6, lane = t & 63;
  for (int b = wave; b < NBUCK; b += 4) {
    int c = hist[b];
    if (c == 0) continue;
    int ls = bs[b], base = gb[b];
    unsigned* dstp = binned + (size_t)b * BCAP + base;
    for (int i = lane; i < c; i += 64) dstp[i] = srt[ls + i];
  }
}

__global__ void k_bscan(const int* __restrict__ gcount, int* __restrict__ gbase) {
  __shared__ int s[256];
  int t = threadIdx.x;
  int v = (t < NBUCK) ? gcount[t] : 0;
  s[t] = v;
  __syncthreads();
  for (int off = 1; off < 256; off <<= 1) {
    int a = (t >= off) ? s[t - off] : 0;
    __syncthreads();
    s[t] += a;
    __syncthreads();
  }
  if (t < NBUCK) gbase[t] = s[t] - v;
}

__global__ __launch_bounds__(256) void k_csr(const unsigned* __restrict__ binned,
                                             const int* __restrict__ gcount,
                                             const int* __restrict__ gbase,
                                             int* __restrict__ rowoff,
                                             int* __restrict__ cnt,
                                             float* __restrict__ dinv,
                                             int* __restrict__ csr) {
  __shared__ int hist[512], offs[512], ps[256];
  __shared__ unsigned srt[BCAP];
  const int b = blockIdx.x, t = threadIdx.x;
  const int n = min(gcount[b], BCAP);
  const int gb0 = gbase[b];
  const unsigned* bp = binned + (size_t)b * BCAP;
  hist[t] = 0;
  hist[t + 256] = 0;
  __syncthreads();
  for (int i = t; i < n; i += 256) atomicAdd(&hist[bp[i] & 511], 1);
  __syncthreads();
  int e0v = hist[2 * t], e1v = hist[2 * t + 1];
  ps[t] = e0v + e1v;
  __syncthreads();
  for (int off = 1; off < 256; off <<= 1) {
    int a = (t >= off) ? ps[t - off] : 0;
    __syncthreads();
    ps[t] += a;
    __syncthreads();
  }
  int excl = ps[t] - (e0v + e1v);
  offs[2 * t] = excl;
  offs[2 * t + 1] = excl + e0v;
  __syncthreads();
#pragma unroll
  for (int u = 0; u < 2; ++u) {
    int j = 2 * t + u;
    int nd = (b << 9) + j;
    if (nd < N_NODES) {
      int c = hist[j];
      cnt[nd] = c;
      dinv[nd] = rsqrtf((float)(c + 1));
      rowoff[nd] = gb0 + offs[j];
    }
  }
  __syncthreads();
  for (int i = t; i < n; i += 256) {
    unsigned p = bp[i];
    int d = p & 511;
    int pos = atomicAdd(&offs[d], 1);
    srt[pos] = p >> 9;
  }
  __syncthreads();
  for (int i = t; i < n; i += 256) csr[gb0 + i] = (int)srt[i];
}

// ---------------- xs = dinv[i] * x[i], padded [N,24] ----------------
__global__ void k_xpad(const float* __restrict__ x, const float* __restrict__ dinv,
                       float* __restrict__ xs) {
  int idx = blockIdx.x * 256 + threadIdx.x;
  if (idx >= N_NODES * 24) return;
  int r = idx / 24, c = idx - r * 24;
  xs[idx] = (c < 21) ? x[r * 21 + c] * dinv[r] : 0.f;
}

// ---------------- conv1 aggregation ----------------
__global__ __launch_bounds__(256) void k_aggx(
    const float4* __restrict__ xs4, const float* __restrict__ dinv,
    const int* __restrict__ rowoff, const int* __restrict__ cnt,
    const int* __restrict__ csr, float4* __restrict__ aggx4) {
  int lane = threadIdx.x & 63, wave = threadIdx.x >> 6;
  int j = lane / 6, c4 = lane - j * 6;
  if (j >= 10) return;
  int i = blockIdx.x * 40 + wave * 10 + j;
  float di = dinv[i];
  int start = rowoff[i], len = cnt[i];
  float4 a0 = xs4[i * 6 + c4];
  float4 a1 = make_float4(0.f, 0.f, 0.f, 0.f);
  int e = 0;
  for (; e + 1 < len; e += 2) {
    int s0 = csr[start + e], s1 = csr[start + e + 1];
    float4 u0 = xs4[s0 * 6 + c4];
    float4 u1 = xs4[s1 * 6 + c4];
    a0.x += u0.x; a0.y += u0.y; a0.z += u0.z; a0.w += u0.w;
    a1.x += u1.x; a1.y += u1.y; a1.z += u1.z; a1.w += u1.w;
  }
  if (e < len) {
    int s0 = csr[start + e];
    float4 u0 = xs4[s0 * 6 + c4];
    a0.x += u0.x; a0.y += u0.y; a0.z += u0.z; a0.w += u0.w;
  }
  float4 r;
  r.x = di * (a0.x + a1.x); r.y = di * (a0.y + a1.y);
  r.z = di * (a0.z + a1.z); r.w = di * (a0.w + a1.w);
  aggx4[i * 6 + c4] = r;
}

// ---------------- gemm1: h1 = relu(aggx @ W1 + b1), f16 out ----------------
__global__ __launch_bounds__(256) void k_gemm1(const float4* __restrict__ aggx4,
                                               const float* __restrict__ W1,
                                               const float* __restrict__ b1,
                                               _Float16* __restrict__ h1) {
  __shared__ float As[32][24];
  int t = threadIdx.x;
  int base = blockIdx.x * 32;
  for (int idx = t; idx < 32 * 6; idx += 256) {
    int m = idx / 6, q = idx - m * 6;
    *(float4*)(&As[m][q * 4]) = aggx4[(base + m) * 6 + q];
  }
  float w[21];
#pragma unroll
  for (int k = 0; k < 21; ++k) w[k] = W1[k * 256 + t];
  float bias = b1[t];
  __syncthreads();
  for (int m = 0; m < 32; ++m) {
    float acc = bias;
#pragma unroll
    for (int k = 0; k < 21; ++k) acc = fmaf(As[m][k], w[k], acc);
    h1[(size_t)(base + m) * 256 + t] = (_Float16)fmaxf(acc, 0.f);
  }
}

// ---------------- W prep: transpose + f16 (single precision, no split) ---------
template <int K, int KPAD, int NOUT, int NR>
__global__ void k_wcvt(const float* __restrict__ W, _Float16* __restrict__ Wh) {
  int idx = blockIdx.x * 256 + threadIdx.x;
  if (idx >= NR * KPAD) return;
  int n = idx / KPAD, k = idx % KPAD;
  float v = (n < NOUT && k < K) ? W[k * NOUT + n] : 0.f;
  Wh[idx] = (_Float16)v;
}

// ---------------- MFMA GEMM, operand-swapped, f16 single, A-prefetch pipeline ---
// A-operand = W (f16), B-operand = nodes (f16). Lane's D frag = 4 consecutive
// channels of one node -> packed stores. Chunk k+1's A is prefetched to regs
// right after the barrier so global latency overlaps chunk k's MFMA phase.
template <int K, int KPAD, int NT, int MT, int WR, int WC, int MINW,
          bool BN, bool STATS, bool F16IN, bool F16OUT>
__global__ __launch_bounds__(256, MINW) void k_mgemm(
    const void* __restrict__ Av, const _Float16* __restrict__ Wt,
    const float* __restrict__ bias, const float* __restrict__ bn_a,
    const float* __restrict__ bn_c, const float* __restrict__ rowscale,
    void* __restrict__ Cv, int NOUTr, float* __restrict__ sums,
    float* __restrict__ sqs) {
  constexpr int BM = WR * MT * 16;       // nodes per block
  constexpr int NR = WC * NT * 16;       // padded channels
  constexpr int BKP = 40;                // 32 + 8 pad (80 B rows)
  constexpr int NC = KPAD / 32;
  constexpr int AIT = BM * 4 / 256;      // A-staging iters per thread
  constexpr int ABYTES = BM * BKP * 2;
  constexpr int BBYTES = NR * BKP * 2;
  __shared__ __align__(16) char smem[ABYTES + BBYTES];
  _Float16* Ah = (_Float16*)smem;
  _Float16* Bh = (_Float16*)(smem + ABYTES);
  const float* A32 = (const float*)Av;
  const _Float16* A16 = (const _Float16*)Av;
  float* C = (float*)Cv;
  _Float16* C16 = (_Float16*)Cv;

  const int tid = threadIdx.x;
  const int lane = tid & 63, wave = tid >> 6;
  const int wr = wave % WR, wc = wave / WR;
  const int quad = lane >> 4, ln = lane & 15;
  const int rowbase = blockIdx.x * BM;

  fx4 acc[MT][NT];
#pragma unroll
  for (int mt = 0; mt < MT; ++mt)
#pragma unroll
    for (int j = 0; j < NT; ++j) acc[mt][j] = (fx4){0.f, 0.f, 0.f, 0.f};

  f16x8 pf16[AIT];
  fx4 pf32a[AIT], pf32b[AIT];

  auto loadA = [&](int kc) {
#pragma unroll
    for (int it = 0; it < AIT; ++it) {
      int idx = tid + it * 256;
      int m = idx >> 2, q = idx & 3;
      int gi = rowbase + m;
      int k = kc * 32 + q * 8;
      bool ok = (gi < N_NODES) && (k < K);
      if constexpr (F16IN) {
        f16x8 z;
#pragma unroll
        for (int t = 0; t < 8; ++t) z[t] = (_Float16)0;
        pf16[it] = ok ? *(const f16x8*)(A16 + (size_t)gi * K + k) : z;
      } else {
        if (ok) {
          pf32a[it] = *(const fx4*)(A32 + (size_t)gi * K + k);
          pf32b[it] = *(const fx4*)(A32 + (size_t)gi * K + k + 4);
        } else {
          pf32a[it] = (fx4){0.f, 0.f, 0.f, 0.f};
          pf32b[it] = (fx4){0.f, 0.f, 0.f, 0.f};
        }
      }
    }
  };

  auto writeA = [&](int kc) {
#pragma unroll
    for (int it = 0; it < AIT; ++it) {
      int idx = tid + it * 256;
      int m = idx >> 2, q = idx & 3;
      int k = kc * 32 + q * 8;
      float vv[8];
      if constexpr (F16IN) {
#pragma unroll
        for (int t = 0; t < 8; ++t) vv[t] = (float)pf16[it][t];
      } else {
#pragma unroll
        for (int t = 0; t < 4; ++t) { vv[t] = pf32a[it][t]; vv[t + 4] = pf32b[it][t]; }
      }
      if constexpr (BN) {
        if (k < K) {   // keep zero-padding exact (bn arrays also end at K)
          float4 a0 = *(const float4*)(bn_a + k);
          float4 a1 = *(const float4*)(bn_a + k + 4);
          float4 c0 = *(const float4*)(bn_c + k);
          float4 c1 = *(const float4*)(bn_c + k + 4);
          float av[8] = {a0.x, a0.y, a0.z, a0.w, a1.x, a1.y, a1.z, a1.w};
          float cv[8] = {c0.x, c0.y, c0.z, c0.w, c1.x, c1.y, c1.z, c1.w};
#pragma unroll
          for (int t = 0; t < 8; ++t) vv[t] = fmaxf(fmaf(vv[t], av[t], cv[t]), 0.f);
        }
      }
      f16x8 hv;
#pragma unroll
      for (int t = 0; t < 8; ++t) hv[t] = (_Float16)vv[t];
      *(f16x8*)(Ah + m * BKP + q * 8) = hv;
    }
  };

  loadA(0);
  for (int kc = 0; kc < NC; ++kc) {
    __syncthreads();                     // prev chunk's LDS reads complete
    writeA(kc);
    for (int idx = tid; idx < NR * 4; idx += 256) {
      int n = idx >> 2, p = idx & 3;
      *(f16x8*)(Bh + n * BKP + p * 8) =
          *(const f16x8*)(Wt + n * KPAD + kc * 32 + p * 8);
    }
    __syncthreads();
    if (kc + 1 < NC) loadA(kc + 1);      // prefetch overlaps MFMA below
    f16x8 nf[MT];
#pragma unroll
    for (int mt = 0; mt < MT; ++mt) {
      int r = (wr * MT + mt) * 16 + ln;
      nf[mt] = *(const f16x8*)(Ah + r * BKP + quad * 8);
    }
#pragma unroll
    for (int j = 0; j < NT; ++j) {
      int n = (wc * NT + j) * 16 + ln;
      f16x8 wh = *(const f16x8*)(Bh + n * BKP + quad * 8);
#pragma unroll
      for (int mt = 0; mt < MT; ++mt)
        acc[mt][j] = __builtin_amdgcn_mfma_f32_16x16x32_f16(wh, nf[mt], acc[mt][j], 0, 0, 0);
    }
  }

  // epilogue: lane = node ln, rows = channels quad*4+r -> packed stores
  float* s_s = (float*)smem;
  float* s_q = s_s + NR;
  __syncthreads();
  if constexpr (STATS) {
    for (int c = tid; c < 2 * NR; c += 256) s_s[c] = 0.f;
    __syncthreads();
  }
  float rs[MT];
#pragma unroll
  for (int mt = 0; mt < MT; ++mt) {
    int nd = rowbase + (wr * MT + mt) * 16 + ln;
    rs[mt] = (rowscale != nullptr && nd < N_NODES) ? rowscale[nd] : 1.f;
  }
#pragma unroll
  for (int j = 0; j < NT; ++j) {
    int ch0 = (wc * NT + j) * 16 + quad * 4;
    bool cv = ch0 < NOUTr;               // NOUTr % 4 == 0 -> all-or-nothing per quad
    float4 b4 = make_float4(0.f, 0.f, 0.f, 0.f);
    if (cv && bias != nullptr) b4 = *(const float4*)(bias + ch0);
    float sc[4] = {0.f, 0.f, 0.f, 0.f}, sq[4] = {0.f, 0.f, 0.f, 0.f};
#pragma unroll
    for (int mt = 0; mt < MT; ++mt) {
      int nd = rowbase + (wr * MT + mt) * 16 + ln;
      if (nd < N_NODES && cv) {
        float v0 = (acc[mt][j][0] + b4.x) * rs[mt];
        float v1 = (acc[mt][j][1] + b4.y) * rs[mt];
        float v2 = (acc[mt][j][2] + b4.z) * rs[mt];
        float v3 = (acc[mt][j][3] + b4.w) * rs[mt];
        if constexpr (F16OUT) {
          f16x4 o = {(_Float16)v0, (_Float16)v1, (_Float16)v2, (_Float16)v3};
          *(f16x4*)(C16 + (size_t)nd * NOUTr + ch0) = o;
        } else {
          float4 o = make_float4(v0, v1, v2, v3);
          *(float4*)(C + (size_t)nd * NOUTr + ch0) = o;
        }
        if constexpr (STATS) {
          sc[0] += v0; sq[0] = fmaf(v0, v0, sq[0]);
          sc[1] += v1; sq[1] = fmaf(v1, v1, sq[1]);
          sc[2] += v2; sq[2] = fmaf(v2, v2, sq[2]);
          sc[3] += v3; sq[3] = fmaf(v3, v3, sq[3]);
        }
      }
    }
    if constexpr (STATS) {
      if (cv) {
#pragma unroll
        for (int r = 0; r < 4; ++r) {
          float s = sc[r], q = sq[r];
          s += __shfl_xor(s, 1); q += __shfl_xor(q, 1);
          s += __shfl_xor(s, 2); q += __shfl_xor(q, 2);
          s += __shfl_xor(s, 4); q += __shfl_xor(q, 4);
          s += __shfl_xor(s, 8); q += __shfl_xor(q, 8);
          if (ln == 0) {
            atomicAdd(&s_s[ch0 + r], s);
            atomicAdd(&s_q[ch0 + r], q);
          }
        }
      }
    }
  }
  if constexpr (STATS) {
    __syncthreads();
    int rep = (blockIdx.x & (NREP - 1));
    for (int c = tid; c < NR; c += 256) {
      if (c < NOUTr) {
        atomicAdd(&sums[rep * NOUTr + c], s_s[c]);
        atomicAdd(&sqs[rep * NOUTr + c], s_q[c]);
      }
    }
  }
}

// ---------------- conv2 aggregation: g2 (f16) = A_norm @ t2 + b2 ----------------
__global__ __launch_bounds__(256) void k_agg2(
    const f16x8* __restrict__ t2s8, const float* __restrict__ dinv,
    const int* __restrict__ rowoff, const int* __restrict__ cnt,
    const int* __restrict__ csr, const float* __restrict__ b2,
    _Float16* __restrict__ g2) {
  int lane = threadIdx.x & 63, wave = threadIdx.x >> 6;
  int j = lane / 14, c = lane - j * 14;
  if (j >= 4) return;
  int i = blockIdx.x * 16 + wave * 4 + j;
  float di = dinv[i];
  int start = rowoff[i], len = cnt[i];
  f16x8 u = t2s8[i * 14 + c];
  fx4 a0, a1, b0, b1;
#pragma unroll
  for (int t = 0; t < 4; ++t) { a0[t] = (float)u[t]; b0[t] = (float)u[t + 4]; }
  a1 = (fx4){0.f, 0.f, 0.f, 0.f};
  b1 = (fx4){0.f, 0.f, 0.f, 0.f};
  int e = 0;
  for (; e + 1 < len; e += 2) {
    int s0 = csr[start + e], s1 = csr[start + e + 1];
    f16x8 u0 = t2s8[s0 * 14 + c];
    f16x8 u1 = t2s8[s1 * 14 + c];
#pragma unroll
    for (int t = 0; t < 4; ++t) {
      a0[t] += (float)u0[t]; b0[t] += (float)u0[t + 4];
      a1[t] += (float)u1[t]; b1[t] += (float)u1[t + 4];
    }
  }
  if (e < len) {
    int s0 = csr[start + e];
    f16x8 u0 = t2s8[s0 * 14 + c];
#pragma unroll
    for (int t = 0; t < 4; ++t) { a0[t] += (float)u0[t]; b0[t] += (float)u0[t + 4]; }
  }
  float4 blo = *(const float4*)(b2 + c * 8);
  float4 bhi = *(const float4*)(b2 + c * 8 + 4);
  f16x8 o;
  o[0] = (_Float16)fmaf(di, a0[0] + a1[0], blo.x);
  o[1] = (_Float16)fmaf(di, a0[1] + a1[1], blo.y);
  o[2] = (_Float16)fmaf(di, a0[2] + a1[2], blo.z);
  o[3] = (_Float16)fmaf(di, a0[3] + a1[3], blo.w);
  o[4] = (_Float16)fmaf(di, b0[0] + b1[0], bhi.x);
  o[5] = (_Float16)fmaf(di, b0[1] + b1[1], bhi.y);
  o[6] = (_Float16)fmaf(di, b0[2] + b1[2], bhi.z);
  o[7] = (_Float16)fmaf(di, b0[3] + b1[3], bhi.w);
  *(f16x8*)(g2 + (size_t)i * 112 + c * 8) = o;
}

// ---------------- BN column stats (f16 input, for g2) ----------------
template <int C>
__global__ void k_colstats16(const _Float16* __restrict__ X, float* __restrict__ sums,
                             float* __restrict__ sqs) {
  int c = threadIdx.x;
  if (c >= C) return;
  int chunk = (N_NODES + gridDim.x - 1) / gridDim.x;
  int i0 = blockIdx.x * chunk;
  int i1 = min(N_NODES, i0 + chunk);
  float s = 0.f, q = 0.f;
  for (int i = i0; i < i1; ++i) {
    float v = (float)X[(size_t)i * C + c];
    s += v;
    q = fmaf(v, v, q);
  }
  int rep = (blockIdx.x & (NREP - 1));
  atomicAdd(&sums[rep * C + c], s);
  atomicAdd(&sqs[rep * C + c], q);
}

template <int C>
__global__ void k_bnfinal(const float* __restrict__ sums, const float* __restrict__ sqs,
                          const float* __restrict__ gamma, const float* __restrict__ beta,
                          float* __restrict__ bn_a, float* __restrict__ bn_c) {
  int c = threadIdx.x;
  if (c >= C) return;
  float s = 0.f, q = 0.f;
#pragma unroll
  for (int r = 0; r < NREP; ++r) {
    s += sums[r * C + c];
    q += sqs[r * C + c];
  }
  const float inv_n = 1.0f / (float)N_NODES;
  float mean = s * inv_n;
  float var = fmaxf(q * inv_n - mean * mean, 0.f);
  float rstd = 1.0f / sqrtf(var + 1e-5f);
  float a = gamma[c] * rstd;
  bn_a[c] = a;
  bn_c[c] = beta[c] - mean * a;
}

// ---------------- final ----------------
__global__ void k_final(const float* __restrict__ h4, const float* __restrict__ bn_a,
                        const float* __restrict__ bn_c, const float* __restrict__ w4,
                        const float* __restrict__ b4, float* __restrict__ out) {
  int lane = threadIdx.x & 63;
  int i = blockIdx.x * 4 + (threadIdx.x >> 6);
  float acc = fmaxf(fmaf(h4[(size_t)i * 100 + lane], bn_a[lane], bn_c[lane]), 0.f) * w4[lane];
  if (lane < 36) {
    int k = lane + 64;
    acc += fmaxf(fmaf(h4[(size_t)i * 100 + k], bn_a[k], bn_c[k]), 0.f) * w4[k];
  }
#pragma unroll
  for (int off = 32; off >= 1; off >>= 1) acc += __shfl_down(acc, off);
  if (lane == 0) out[i] = acc + b4[0];
}

extern "C" void kernel_launch(void* const* d_in, const int* in_sizes, int n_in,
                              void* d_out, int out_size, void* d_ws, size_t ws_size,
                              hipStream_t stream) {
  const float* x   = (const float*)d_in[0];
  const int*   ei  = (const int*)d_in[1];
  const float* W1  = (const float*)d_in[2];
  const float* b1  = (const float*)d_in[3];
  const float* W2  = (const float*)d_in[4];
  const float* b2  = (const float*)d_in[5];
  const float* l2w = (const float*)d_in[6];
  const float* l2b = (const float*)d_in[7];
  const float* l3w = (const float*)d_in[8];
  const float* l3b = (const float*)d_in[9];
  const float* l4w = (const float*)d_in[10];
  const float* l4b = (const float*)d_in[11];
  const float* g1  = (const float*)d_in[12];
  const float* be1 = (const float*)d_in[13];
  const float* g2w = (const float*)d_in[14];
  const float* be2 = (const float*)d_in[15];
  const float* g3  = (const float*)d_in[16];
  const float* be3 = (const float*)d_in[17];
  float* out = (float*)d_out;

  char* base = (char*)d_ws;
  size_t off = 0;
  auto alloc = [&](size_t bytes) -> char* {
    char* p = base + off;
    off = (off + bytes + 255) & ~(size_t)255;
    return p;
  };
  int*   cnt    = (int*)alloc((size_t)N_NODES * 4);
  int*   rowoff = (int*)alloc((size_t)N_NODES * 4);
  float* dinv   = (float*)alloc((size_t)N_NODES * 4);
  int*   csr    = (int*)alloc((size_t)N_EDGES * 4);
  unsigned* binned = (unsigned*)alloc((size_t)NBUCK * BCAP * 4);
  int*   gcount = (int*)alloc(NBUCK * 4);
  int*   gbase  = (int*)alloc(NBUCK * 4);
  float* stats  = (float*)alloc((size_t)NREP * 960 * 4);
  float* bnco   = (float*)alloc(960 * 4);
  float* xs     = (float*)alloc((size_t)N_NODES * 24 * 4);
  float* aggx   = (float*)alloc((size_t)N_NODES * 24 * 4);
  _Float16* h1  = (_Float16*)alloc((size_t)N_NODES * 256 * 2);  // f16; reused as h3
  _Float16* t2s = (_Float16*)alloc((size_t)N_NODES * 112 * 2);  // f16 dinv-scaled h1W2
  _Float16* g2h = (_Float16*)alloc((size_t)N_NODES * 112 * 2);  // f16 conv2 output
  float* h4     = (float*)alloc((size_t)N_NODES * 112 * 4);
  _Float16* wt2 = (_Float16*)alloc(112 * 256 * 2);
  _Float16* wt3 = (_Float16*)alloc(256 * 128 * 2);
  _Float16* wt4 = (_Float16*)alloc(112 * 256 * 2);

  float* sums1 = stats;
  float* sqs1  = sums1 + NREP * 112;
  float* sums2 = sqs1 + NREP * 112;
  float* sqs2  = sums2 + NREP * 256;
  float* sums3 = sqs2 + NREP * 256;
  float* sqs3  = sums3 + NREP * 112;
  float* bn_a1 = bnco + 0,   *bn_c1 = bnco + 112;
  float* bn_a2 = bnco + 224, *bn_c2 = bnco + 480;
  float* bn_a3 = bnco + 736, *bn_c3 = bnco + 848;

  hipMemsetAsync(gcount, 0, NBUCK * 4, stream);
  hipMemsetAsync(stats, 0, (size_t)NREP * 960 * 4, stream);

  k_bin<<<NBUCK, 256, 0, stream>>>(ei, binned, gcount);
  k_bscan<<<1, 256, 0, stream>>>(gcount, gbase);
  k_csr<<<NBUCK, 256, 0, stream>>>(binned, gcount, gbase, rowoff, cnt, dinv, csr);

  k_wcvt<256, 256, 112, 112><<<112, 256, 0, stream>>>(W2, wt2);
  k_wcvt<112, 128, 256, 256><<<128, 256, 0, stream>>>(l2w, wt3);
  k_wcvt<256, 256, 100, 112><<<112, 256, 0, stream>>>(l3w, wt4);

  k_xpad<<<(N_NODES * 24 + 255) / 256, 256, 0, stream>>>(x, dinv, xs);
  k_aggx<<<2500, 256, 0, stream>>>((const float4*)xs, dinv, rowoff, cnt, csr,
                                   (float4*)aggx);
  k_gemm1<<<3125, 256, 0, stream>>>((const float4*)aggx, W1, b1, h1);

  // t2s = dinv*(h1@W2) f16: K=256, f16-in, f16-out, BM=128
  k_mgemm<256, 256, 7, 2, 4, 1, 4, false, false, true, true><<<782, 256, 0, stream>>>(
      h1, wt2, nullptr, nullptr, nullptr, dinv, t2s, 112, nullptr, nullptr);
  k_agg2<<<6250, 256, 0, stream>>>((const f16x8*)t2s, dinv, rowoff, cnt, csr, b2,
                                   g2h);

  k_colstats16<112><<<1600, 128, 0, stream>>>(g2h, sums1, sqs1);
  k_bnfinal<112><<<1, 128, 0, stream>>>(sums1, sqs1, g1, be1, bn_a1, bn_c1);

  // h3 = relu(bn1(g2))@lin2_w + b: K=112, f16-in+BN, stats, f16-out -> h1 buffer
  k_mgemm<112, 128, 8, 2, 2, 2, 4, true, true, true, true><<<1563, 256, 0, stream>>>(
      g2h, wt3, l2b, bn_a1, bn_c1, nullptr, h1, 256, sums2, sqs2);
  k_bnfinal<256><<<1, 256, 0, stream>>>(sums2, sqs2, g2w, be2, bn_a2, bn_c2);

  // h4 = relu(bn2(h3))@lin3_w + b: K=256, f16-in+BN, stats, fp32-out, BM=128
  k_mgemm<256, 256, 7, 2, 4, 1, 4, true, true, true, false><<<782, 256, 0, stream>>>(
      h1, wt4, l3b, bn_a2, bn_c2, nullptr, h4, 100, sums3, sqs3);
  k_bnfinal<100><<<1, 128, 0, stream>>>(sums3, sqs3, g3, be3, bn_a3, bn_c3);

  k_final<<<25000, 256, 0, stream>>>(h4, bn_a3, bn_c3, l4w, l4b, out);
}

// Round 9
// 414.800 us; speedup vs baseline: 3.5048x; 1.0490x over previous
//
#include <hip/hip_runtime.h>

#define N_NODES 100000
#define N_EDGES 1600000

typedef _Float16 f16x8 __attribute__((ext_vector_type(8)));
typedef _Float16 f16x4 __attribute__((ext_vector_type(4)));
typedef float fx4 __attribute__((ext_vector_type(4)));

#define NREP 16     // stats-accumulator replication to de-contend atomics
#define NBUCK 196   // ceil(100000/512) buckets of 512 nodes
#define CHUNK 8192  // edges per k_bin block
#define BCAP 12288  // per-bucket slot capacity

// ---------------- CSR build, pass 1: LDS counting-sort chunks by bucket --------
__global__ __launch_bounds__(256) void k_bin(const int* __restrict__ ei,
                                             unsigned* __restrict__ binned,
                                             int* __restrict__ gcount) {
  __shared__ unsigned pr[CHUNK];
  __shared__ unsigned srt[CHUNK];
  __shared__ unsigned char bk[CHUNK];
  __shared__ int hist[256], scanb[256], offs[256], bs[256], gb[256];
  const int t = threadIdx.x;
  const int e0 = blockIdx.x * CHUNK;
  const int n = min(CHUNK, N_EDGES - e0);
  hist[t] = 0;
  __syncthreads();
  for (int i = t; i < n; i += 256) {
    int src = ei[e0 + i], dst = ei[N_EDGES + e0 + i];
    int b = dst >> 9;
    pr[i] = ((unsigned)src << 9) | (unsigned)(dst & 511);
    bk[i] = (unsigned char)b;
    atomicAdd(&hist[b], 1);
  }
  __syncthreads();
  int v = hist[t];
  scanb[t] = v;
  __syncthreads();
  for (int off = 1; off < 256; off <<= 1) {
    int a = (t >= off) ? scanb[t - off] : 0;
    __syncthreads();
    scanb[t] += a;
    __syncthreads();
  }
  offs[t] = scanb[t] - v;
  bs[t] = scanb[t] - v;
  __syncthreads();
  for (int i = t; i < n; i += 256) {
    int b = bk[i];
    int p = atomicAdd(&offs[b], 1);
    srt[p] = pr[i];
  }
  if (t < NBUCK && v > 0) gb[t] = atomicAdd(&gcount[t], v);
  __syncthreads();
  int wave = t >> 6, lane = t & 63;
  for (int b = wave; b < NBUCK; b += 4) {
    int c = hist[b];
    if (c == 0) continue;
    int ls = bs[b], base = gb[b];
    unsigned* dstp = binned + (size_t)b * BCAP + base;
    for (int i = lane; i < c; i += 64) dstp[i] = srt[ls + i];
  }
}

__global__ void k_bscan(const int* __restrict__ gcount, int* __restrict__ gbase) {
  __shared__ int s[256];
  int t = threadIdx.x;
  int v = (t < NBUCK) ? gcount[t] : 0;
  s[t] = v;
  __syncthreads();
  for (int off = 1; off < 256; off <<= 1) {
    int a = (t >= off) ? s[t - off] : 0;
    __syncthreads();
    s[t] += a;
    __syncthreads();
  }
  if (t < NBUCK) gbase[t] = s[t] - v;
}

__global__ __launch_bounds__(256) void k_csr(const unsigned* __restrict__ binned,
                                             const int* __restrict__ gcount,
                                             const int* __restrict__ gbase,
                                             int* __restrict__ rowoff,
                                             int* __restrict__ cnt,
                                             float* __restrict__ dinv,
                                             int* __restrict__ csr) {
  __shared__ int hist[512], offs[512], ps[256];
  __shared__ unsigned srt[BCAP];
  const int b = blockIdx.x, t = threadIdx.x;
  const int n = min(gcount[b], BCAP);
  const int gb0 = gbase[b];
  const unsigned* bp = binned + (size_t)b * BCAP;
  hist[t] = 0;
  hist[t + 256] = 0;
  __syncthreads();
  for (int i = t; i < n; i += 256) atomicAdd(&hist[bp[i] & 511], 1);
  __syncthreads();
  int e0v = hist[2 * t], e1v = hist[2 * t + 1];
  ps[t] = e0v + e1v;
  __syncthreads();
  for (int off = 1; off < 256; off <<= 1) {
    int a = (t >= off) ? ps[t - off] : 0;
    __syncthreads();
    ps[t] += a;
    __syncthreads();
  }
  int excl = ps[t] - (e0v + e1v);
  offs[2 * t] = excl;
  offs[2 * t + 1] = excl + e0v;
  __syncthreads();
#pragma unroll
  for (int u = 0; u < 2; ++u) {
    int j = 2 * t + u;
    int nd = (b << 9) + j;
    if (nd < N_NODES) {
      int c = hist[j];
      cnt[nd] = c;
      dinv[nd] = rsqrtf((float)(c + 1));
      rowoff[nd] = gb0 + offs[j];
    }
  }
  __syncthreads();
  for (int i = t; i < n; i += 256) {
    unsigned p = bp[i];
    int d = p & 511;
    int pos = atomicAdd(&offs[d], 1);
    srt[pos] = p >> 9;
  }
  __syncthreads();
  for (int i = t; i < n; i += 256) csr[gb0 + i] = (int)srt[i];
}

// ---------------- xs = dinv[i] * x[i], f16, padded [N,24] ----------------
__global__ void k_xpad(const float* __restrict__ x, const float* __restrict__ dinv,
                       _Float16* __restrict__ xs) {
  int idx = blockIdx.x * 256 + threadIdx.x;
  if (idx >= N_NODES * 24) return;
  int r = idx / 24, c = idx - r * 24;
  xs[idx] = (_Float16)((c < 21) ? x[r * 21 + c] * dinv[r] : 0.f);
}

// ---------------- conv1 aggregation: 3 lanes x f16x8 per row, 21 rows/wave ------
// f16 rows = 48 B -> 4.8 MB working set (~per-XCD L2). 4 accumulator chains.
__global__ __launch_bounds__(256) void k_aggx(
    const f16x8* __restrict__ xs3, const float* __restrict__ dinv,
    const int* __restrict__ rowoff, const int* __restrict__ cnt,
    const int* __restrict__ csr, float* __restrict__ aggx) {
  int lane = threadIdx.x & 63, wave = threadIdx.x >> 6;
  int j = lane / 3, c = lane - j * 3;
  if (j >= 21) return;
  int i = blockIdx.x * 84 + wave * 21 + j;
  if (i >= N_NODES) return;
  float di = dinv[i];
  int start = rowoff[i], len = cnt[i];
  f16x8 u = xs3[i * 3 + c];                    // self-loop (pre-scaled)
  float a0[8], a1[8], a2[8], a3[8];
#pragma unroll
  for (int t = 0; t < 8; ++t) { a0[t] = (float)u[t]; a1[t] = a2[t] = a3[t] = 0.f; }
  int e = 0;
  for (; e + 3 < len; e += 4) {
    int s0 = csr[start + e], s1 = csr[start + e + 1];
    int s2 = csr[start + e + 2], s3 = csr[start + e + 3];
    f16x8 u0 = xs3[s0 * 3 + c];
    f16x8 u1 = xs3[s1 * 3 + c];
    f16x8 u2 = xs3[s2 * 3 + c];
    f16x8 u3 = xs3[s3 * 3 + c];
#pragma unroll
    for (int t = 0; t < 8; ++t) {
      a0[t] += (float)u0[t]; a1[t] += (float)u1[t];
      a2[t] += (float)u2[t]; a3[t] += (float)u3[t];
    }
  }
  for (; e < len; ++e) {
    int s0 = csr[start + e];
    f16x8 u0 = xs3[s0 * 3 + c];
#pragma unroll
    for (int t = 0; t < 8; ++t) a0[t] += (float)u0[t];
  }
  float4 r0, r1;
  r0.x = di * (a0[0] + a1[0] + a2[0] + a3[0]);
  r0.y = di * (a0[1] + a1[1] + a2[1] + a3[1]);
  r0.z = di * (a0[2] + a1[2] + a2[2] + a3[2]);
  r0.w = di * (a0[3] + a1[3] + a2[3] + a3[3]);
  r1.x = di * (a0[4] + a1[4] + a2[4] + a3[4]);
  r1.y = di * (a0[5] + a1[5] + a2[5] + a3[5]);
  r1.z = di * (a0[6] + a1[6] + a2[6] + a3[6]);
  r1.w = di * (a0[7] + a1[7] + a2[7] + a3[7]);
  *(float4*)(aggx + (size_t)i * 24 + c * 8) = r0;
  *(float4*)(aggx + (size_t)i * 24 + c * 8 + 4) = r1;
}

// ---------------- gemm1: h1 = relu(aggx @ W1 + b1), f16 out ----------------
__global__ __launch_bounds__(256) void k_gemm1(const float4* __restrict__ aggx4,
                                               const float* __restrict__ W1,
                                               const float* __restrict__ b1,
                                               _Float16* __restrict__ h1) {
  __shared__ float As[32][24];
  int t = threadIdx.x;
  int base = blockIdx.x * 32;
  for (int idx = t; idx < 32 * 6; idx += 256) {
    int m = idx / 6, q = idx - m * 6;
    *(float4*)(&As[m][q * 4]) = aggx4[(base + m) * 6 + q];
  }
  float w[21];
#pragma unroll
  for (int k = 0; k < 21; ++k) w[k] = W1[k * 256 + t];
  float bias = b1[t];
  __syncthreads();
  for (int m = 0; m < 32; ++m) {
    float acc = bias;
#pragma unroll
    for (int k = 0; k < 21; ++k) acc = fmaf(As[m][k], w[k], acc);
    h1[(size_t)(base + m) * 256 + t] = (_Float16)fmaxf(acc, 0.f);
  }
}

// ---------------- W prep: transpose + f16 ----------------
template <int K, int KPAD, int NOUT, int NR>
__global__ void k_wcvt(const float* __restrict__ W, _Float16* __restrict__ Wh) {
  int idx = blockIdx.x * 256 + threadIdx.x;
  if (idx >= NR * KPAD) return;
  int n = idx / KPAD, k = idx % KPAD;
  float v = (n < NOUT && k < K) ? W[k * NOUT + n] : 0.f;
  Wh[idx] = (_Float16)v;
}

// ---------------- MFMA GEMM, operand-swapped, f16, A-prefetch pipeline ----------
template <int K, int KPAD, int NT, int MT, int WR, int WC, int MINW,
          bool BN, bool STATS, bool F16IN, bool F16OUT>
__global__ __launch_bounds__(256, MINW) void k_mgemm(
    const void* __restrict__ Av, const _Float16* __restrict__ Wt,
    const float* __restrict__ bias, const float* __restrict__ bn_a,
    const float* __restrict__ bn_c, const float* __restrict__ rowscale,
    void* __restrict__ Cv, int NOUTr, float* __restrict__ sums,
    float* __restrict__ sqs) {
  constexpr int BM = WR * MT * 16;
  constexpr int NR = WC * NT * 16;
  constexpr int BKP = 40;
  constexpr int NC = KPAD / 32;
  constexpr int AIT = BM * 4 / 256;
  constexpr int ABYTES = BM * BKP * 2;
  constexpr int BBYTES = NR * BKP * 2;
  __shared__ __align__(16) char smem[ABYTES + BBYTES];
  _Float16* Ah = (_Float16*)smem;
  _Float16* Bh = (_Float16*)(smem + ABYTES);
  const float* A32 = (const float*)Av;
  const _Float16* A16 = (const _Float16*)Av;
  float* C = (float*)Cv;
  _Float16* C16 = (_Float16*)Cv;

  const int tid = threadIdx.x;
  const int lane = tid & 63, wave = tid >> 6;
  const int wr = wave % WR, wc = wave / WR;
  const int quad = lane >> 4, ln = lane & 15;
  const int rowbase = blockIdx.x * BM;

  fx4 acc[MT][NT];
#pragma unroll
  for (int mt = 0; mt < MT; ++mt)
#pragma unroll
    for (int j = 0; j < NT; ++j) acc[mt][j] = (fx4){0.f, 0.f, 0.f, 0.f};

  f16x8 pf16[AIT];
  fx4 pf32a[AIT], pf32b[AIT];

  auto loadA = [&](int kc) {
#pragma unroll
    for (int it = 0; it < AIT; ++it) {
      int idx = tid + it * 256;
      int m = idx >> 2, q = idx & 3;
      int gi = rowbase + m;
      int k = kc * 32 + q * 8;
      bool ok = (gi < N_NODES) && (k < K);
      if constexpr (F16IN) {
        f16x8 z;
#pragma unroll
        for (int t = 0; t < 8; ++t) z[t] = (_Float16)0;
        pf16[it] = ok ? *(const f16x8*)(A16 + (size_t)gi * K + k) : z;
      } else {
        if (ok) {
          pf32a[it] = *(const fx4*)(A32 + (size_t)gi * K + k);
          pf32b[it] = *(const fx4*)(A32 + (size_t)gi * K + k + 4);
        } else {
          pf32a[it] = (fx4){0.f, 0.f, 0.f, 0.f};
          pf32b[it] = (fx4){0.f, 0.f, 0.f, 0.f};
        }
      }
    }
  };

  auto writeA = [&](int kc) {
#pragma unroll
    for (int it = 0; it < AIT; ++it) {
      int idx = tid + it * 256;
      int m = idx >> 2, q = idx & 3;
      int k = kc * 32 + q * 8;
      float vv[8];
      if constexpr (F16IN) {
#pragma unroll
        for (int t = 0; t < 8; ++t) vv[t] = (float)pf16[it][t];
      } else {
#pragma unroll
        for (int t = 0; t < 4; ++t) { vv[t] = pf32a[it][t]; vv[t + 4] = pf32b[it][t]; }
      }
      if constexpr (BN) {
        if (k < K) {
          float4 a0 = *(const float4*)(bn_a + k);
          float4 a1 = *(const float4*)(bn_a + k + 4);
          float4 c0 = *(const float4*)(bn_c + k);
          float4 c1 = *(const float4*)(bn_c + k + 4);
          float av[8] = {a0.x, a0.y, a0.z, a0.w, a1.x, a1.y, a1.z, a1.w};
          float cv[8] = {c0.x, c0.y, c0.z, c0.w, c1.x, c1.y, c1.z, c1.w};
#pragma unroll
          for (int t = 0; t < 8; ++t) vv[t] = fmaxf(fmaf(vv[t], av[t], cv[t]), 0.f);
        }
      }
      f16x8 hv;
#pragma unroll
      for (int t = 0; t < 8; ++t) hv[t] = (_Float16)vv[t];
      *(f16x8*)(Ah + m * BKP + q * 8) = hv;
    }
  };

  loadA(0);
  for (int kc = 0; kc < NC; ++kc) {
    __syncthreads();
    writeA(kc);
    for (int idx = tid; idx < NR * 4; idx += 256) {
      int n = idx >> 2, p = idx & 3;
      *(f16x8*)(Bh + n * BKP + p * 8) =
          *(const f16x8*)(Wt + n * KPAD + kc * 32 + p * 8);
    }
    __syncthreads();
    if (kc + 1 < NC) loadA(kc + 1);
    f16x8 nf[MT];
#pragma unroll
    for (int mt = 0; mt < MT; ++mt) {
      int r = (wr * MT + mt) * 16 + ln;
      nf[mt] = *(const f16x8*)(Ah + r * BKP + quad * 8);
    }
#pragma unroll
    for (int j = 0; j < NT; ++j) {
      int n = (wc * NT + j) * 16 + ln;
      f16x8 wh = *(const f16x8*)(Bh + n * BKP + quad * 8);
#pragma unroll
      for (int mt = 0; mt < MT; ++mt)
        acc[mt][j] = __builtin_amdgcn_mfma_f32_16x16x32_f16(wh, nf[mt], acc[mt][j], 0, 0, 0);
    }
  }

  float* s_s = (float*)smem;
  float* s_q = s_s + NR;
  __syncthreads();
  if constexpr (STATS) {
    for (int c = tid; c < 2 * NR; c += 256) s_s[c] = 0.f;
    __syncthreads();
  }
  float rs[MT];
#pragma unroll
  for (int mt = 0; mt < MT; ++mt) {
    int nd = rowbase + (wr * MT + mt) * 16 + ln;
    rs[mt] = (rowscale != nullptr && nd < N_NODES) ? rowscale[nd] : 1.f;
  }
#pragma unroll
  for (int j = 0; j < NT; ++j) {
    int ch0 = (wc * NT + j) * 16 + quad * 4;
    bool cv = ch0 < NOUTr;
    float4 b4 = make_float4(0.f, 0.f, 0.f, 0.f);
    if (cv && bias != nullptr) b4 = *(const float4*)(bias + ch0);
    float sc[4] = {0.f, 0.f, 0.f, 0.f}, sq[4] = {0.f, 0.f, 0.f, 0.f};
#pragma unroll
    for (int mt = 0; mt < MT; ++mt) {
      int nd = rowbase + (wr * MT + mt) * 16 + ln;
      if (nd < N_NODES && cv) {
        float v0 = (acc[mt][j][0] + b4.x) * rs[mt];
        float v1 = (acc[mt][j][1] + b4.y) * rs[mt];
        float v2 = (acc[mt][j][2] + b4.z) * rs[mt];
        float v3 = (acc[mt][j][3] + b4.w) * rs[mt];
        if constexpr (F16OUT) {
          f16x4 o = {(_Float16)v0, (_Float16)v1, (_Float16)v2, (_Float16)v3};
          *(f16x4*)(C16 + (size_t)nd * NOUTr + ch0) = o;
        } else {
          float4 o = make_float4(v0, v1, v2, v3);
          *(float4*)(C + (size_t)nd * NOUTr + ch0) = o;
        }
        if constexpr (STATS) {
          sc[0] += v0; sq[0] = fmaf(v0, v0, sq[0]);
          sc[1] += v1; sq[1] = fmaf(v1, v1, sq[1]);
          sc[2] += v2; sq[2] = fmaf(v2, v2, sq[2]);
          sc[3] += v3; sq[3] = fmaf(v3, v3, sq[3]);
        }
      }
    }
    if constexpr (STATS) {
      if (cv) {
#pragma unroll
        for (int r = 0; r < 4; ++r) {
          float s = sc[r], q = sq[r];
          s += __shfl_xor(s, 1); q += __shfl_xor(q, 1);
          s += __shfl_xor(s, 2); q += __shfl_xor(q, 2);
          s += __shfl_xor(s, 4); q += __shfl_xor(q, 4);
          s += __shfl_xor(s, 8); q += __shfl_xor(q, 8);
          if (ln == 0) {
            atomicAdd(&s_s[ch0 + r], s);
            atomicAdd(&s_q[ch0 + r], q);
          }
        }
      }
    }
  }
  if constexpr (STATS) {
    __syncthreads();
    int rep = (blockIdx.x & (NREP - 1));
    for (int c = tid; c < NR; c += 256) {
      if (c < NOUTr) {
        atomicAdd(&sums[rep * NOUTr + c], s_s[c]);
        atomicAdd(&sqs[rep * NOUTr + c], s_q[c]);
      }
    }
  }
}

// ---------------- conv2 aggregation: g2 (f16) = A_norm @ t2 + b2, 4 chains ------
__global__ __launch_bounds__(256) void k_agg2(
    const f16x8* __restrict__ t2s8, const float* __restrict__ dinv,
    const int* __restrict__ rowoff, const int* __restrict__ cnt,
    const int* __restrict__ csr, const float* __restrict__ b2,
    _Float16* __restrict__ g2) {
  int lane = threadIdx.x & 63, wave = threadIdx.x >> 6;
  int j = lane / 14, c = lane - j * 14;
  if (j >= 4) return;
  int i = blockIdx.x * 16 + wave * 4 + j;
  float di = dinv[i];
  int start = rowoff[i], len = cnt[i];
  f16x8 u = t2s8[i * 14 + c];
  float a0[8], a1[8], a2[8], a3[8];
#pragma unroll
  for (int t = 0; t < 8; ++t) { a0[t] = (float)u[t]; a1[t] = a2[t] = a3[t] = 0.f; }
  int e = 0;
  for (; e + 3 < len; e += 4) {
    int s0 = csr[start + e], s1 = csr[start + e + 1];
    int s2 = csr[start + e + 2], s3 = csr[start + e + 3];
    f16x8 u0 = t2s8[s0 * 14 + c];
    f16x8 u1 = t2s8[s1 * 14 + c];
    f16x8 u2 = t2s8[s2 * 14 + c];
    f16x8 u3 = t2s8[s3 * 14 + c];
#pragma unroll
    for (int t = 0; t < 8; ++t) {
      a0[t] += (float)u0[t]; a1[t] += (float)u1[t];
      a2[t] += (float)u2[t]; a3[t] += (float)u3[t];
    }
  }
  for (; e < len; ++e) {
    int s0 = csr[start + e];
    f16x8 u0 = t2s8[s0 * 14 + c];
#pragma unroll
    for (int t = 0; t < 8; ++t) a0[t] += (float)u0[t];
  }
  float4 blo = *(const float4*)(b2 + c * 8);
  float4 bhi = *(const float4*)(b2 + c * 8 + 4);
  float bb[8] = {blo.x, blo.y, blo.z, blo.w, bhi.x, bhi.y, bhi.z, bhi.w};
  f16x8 o;
#pragma unroll
  for (int t = 0; t < 8; ++t)
    o[t] = (_Float16)fmaf(di, a0[t] + a1[t] + a2[t] + a3[t], bb[t]);
  *(f16x8*)(g2 + (size_t)i * 112 + c * 8) = o;
}

// ---------------- BN column stats (f16 input, for g2) ----------------
template <int C>
__global__ void k_colstats16(const _Float16* __restrict__ X, float* __restrict__ sums,
                             float* __restrict__ sqs) {
  int c = threadIdx.x;
  if (c >= C) return;
  int chunk = (N_NODES + gridDim.x - 1) / gridDim.x;
  int i0 = blockIdx.x * chunk;
  int i1 = min(N_NODES, i0 + chunk);
  float s = 0.f, q = 0.f;
  for (int i = i0; i < i1; ++i) {
    float v = (float)X[(size_t)i * C + c];
    s += v;
    q = fmaf(v, v, q);
  }
  int rep = (blockIdx.x & (NREP - 1));
  atomicAdd(&sums[rep * C + c], s);
  atomicAdd(&sqs[rep * C + c], q);
}

template <int C>
__global__ void k_bnfinal(const float* __restrict__ sums, const float* __restrict__ sqs,
                          const float* __restrict__ gamma, const float* __restrict__ beta,
                          float* __restrict__ bn_a, float* __restrict__ bn_c) {
  int c = threadIdx.x;
  if (c >= C) return;
  float s = 0.f, q = 0.f;
#pragma unroll
  for (int r = 0; r < NREP; ++r) {
    s += sums[r * C + c];
    q += sqs[r * C + c];
  }
  const float inv_n = 1.0f / (float)N_NODES;
  float mean = s * inv_n;
  float var = fmaxf(q * inv_n - mean * mean, 0.f);
  float rstd = 1.0f / sqrtf(var + 1e-5f);
  float a = gamma[c] * rstd;
  bn_a[c] = a;
  bn_c[c] = beta[c] - mean * a;
}

// ---------------- final ----------------
__global__ void k_final(const float* __restrict__ h4, const float* __restrict__ bn_a,
                        const float* __restrict__ bn_c, const float* __restrict__ w4,
                        const float* __restrict__ b4, float* __restrict__ out) {
  int lane = threadIdx.x & 63;
  int i = blockIdx.x * 4 + (threadIdx.x >> 6);
  float acc = fmaxf(fmaf(h4[(size_t)i * 100 + lane], bn_a[lane], bn_c[lane]), 0.f) * w4[lane];
  if (lane < 36) {
    int k = lane + 64;
    acc += fmaxf(fmaf(h4[(size_t)i * 100 + k], bn_a[k], bn_c[k]), 0.f) * w4[k];
  }
#pragma unroll
  for (int off = 32; off >= 1; off >>= 1) acc += __shfl_down(acc, off);
  if (lane == 0) out[i] = acc + b4[0];
}

extern "C" void kernel_launch(void* const* d_in, const int* in_sizes, int n_in,
                              void* d_out, int out_size, void* d_ws, size_t ws_size,
                              hipStream_t stream) {
  const float* x   = (const float*)d_in[0];
  const int*   ei  = (const int*)d_in[1];
  const float* W1  = (const float*)d_in[2];
  const float* b1  = (const float*)d_in[3];
  const float* W2  = (const float*)d_in[4];
  const float* b2  = (const float*)d_in[5];
  const float* l2w = (const float*)d_in[6];
  const float* l2b = (const float*)d_in[7];
  const float* l3w = (const float*)d_in[8];
  const float* l3b = (const float*)d_in[9];
  const float* l4w = (const float*)d_in[10];
  const float* l4b = (const float*)d_in[11];
  const float* g1  = (const float*)d_in[12];
  const float* be1 = (const float*)d_in[13];
  const float* g2w = (const float*)d_in[14];
  const float* be2 = (const float*)d_in[15];
  const float* g3  = (const float*)d_in[16];
  const float* be3 = (const float*)d_in[17];
  float* out = (float*)d_out;

  char* base = (char*)d_ws;
  size_t off = 0;
  auto alloc = [&](size_t bytes) -> char* {
    char* p = base + off;
    off = (off + bytes + 255) & ~(size_t)255;
    return p;
  };
  int*   cnt    = (int*)alloc((size_t)N_NODES * 4);
  int*   rowoff = (int*)alloc((size_t)N_NODES * 4);
  float* dinv   = (float*)alloc((size_t)N_NODES * 4);
  int*   csr    = (int*)alloc((size_t)N_EDGES * 4);
  unsigned* binned = (unsigned*)alloc((size_t)NBUCK * BCAP * 4);
  int*   gcount = (int*)alloc(NBUCK * 4);
  int*   gbase  = (int*)alloc(NBUCK * 4);
  float* stats  = (float*)alloc((size_t)NREP * 960 * 4);
  float* bnco   = (float*)alloc(960 * 4);
  _Float16* xs  = (_Float16*)alloc((size_t)N_NODES * 24 * 2);  // f16 dinv-scaled x
  float* aggx   = (float*)alloc((size_t)N_NODES * 24 * 4);
  _Float16* h1  = (_Float16*)alloc((size_t)N_NODES * 256 * 2);  // f16; reused as h3
  _Float16* t2s = (_Float16*)alloc((size_t)N_NODES * 112 * 2);  // f16 dinv-scaled h1W2
  _Float16* g2h = (_Float16*)alloc((size_t)N_NODES * 112 * 2);  // f16 conv2 output
  float* h4     = (float*)alloc((size_t)N_NODES * 112 * 4);
  _Float16* wt2 = (_Float16*)alloc(112 * 256 * 2);
  _Float16* wt3 = (_Float16*)alloc(256 * 128 * 2);
  _Float16* wt4 = (_Float16*)alloc(112 * 256 * 2);

  float* sums1 = stats;
  float* sqs1  = sums1 + NREP * 112;
  float* sums2 = sqs1 + NREP * 112;
  float* sqs2  = sums2 + NREP * 256;
  float* sums3 = sqs2 + NREP * 256;
  float* sqs3  = sums3 + NREP * 112;
  float* bn_a1 = bnco + 0,   *bn_c1 = bnco + 112;
  float* bn_a2 = bnco + 224, *bn_c2 = bnco + 480;
  float* bn_a3 = bnco + 736, *bn_c3 = bnco + 848;

  hipMemsetAsync(gcount, 0, NBUCK * 4, stream);
  hipMemsetAsync(stats, 0, (size_t)NREP * 960 * 4, stream);

  k_bin<<<NBUCK, 256, 0, stream>>>(ei, binned, gcount);
  k_bscan<<<1, 256, 0, stream>>>(gcount, gbase);
  k_csr<<<NBUCK, 256, 0, stream>>>(binned, gcount, gbase, rowoff, cnt, dinv, csr);

  k_wcvt<256, 256, 112, 112><<<112, 256, 0, stream>>>(W2, wt2);
  k_wcvt<112, 128, 256, 256><<<128, 256, 0, stream>>>(l2w, wt3);
  k_wcvt<256, 256, 100, 112><<<112, 256, 0, stream>>>(l3w, wt4);

  k_xpad<<<(N_NODES * 24 + 255) / 256, 256, 0, stream>>>(x, dinv, xs);
  k_aggx<<<(N_NODES + 83) / 84, 256, 0, stream>>>((const f16x8*)xs, dinv, rowoff,
                                                  cnt, csr, aggx);
  k_gemm1<<<3125, 256, 0, stream>>>((const float4*)aggx, W1, b1, h1);

  // t2s = dinv*(h1@W2) f16: K=256, f16-in, f16-out, BM=128
  k_mgemm<256, 256, 7, 2, 4, 1, 4, false, false, true, true><<<782, 256, 0, stream>>>(
      h1, wt2, nullptr, nullptr, nullptr, dinv, t2s, 112, nullptr, nullptr);
  k_agg2<<<6250, 256, 0, stream>>>((const f16x8*)t2s, dinv, rowoff, cnt, csr, b2,
                                   g2h);

  k_colstats16<112><<<1600, 128, 0, stream>>>(g2h, sums1, sqs1);
  k_bnfinal<112><<<1, 128, 0, stream>>>(sums1, sqs1, g1, be1, bn_a1, bn_c1);

  // h3 = relu(bn1(g2))@lin2_w + b: K=112, f16-in+BN, stats, f16-out -> h1 buffer
  k_mgemm<112, 128, 8, 2, 2, 2, 4, true, true, true, true><<<1563, 256, 0, stream>>>(
      g2h, wt3, l2b, bn_a1, bn_c1, nullptr, h1, 256, sums2, sqs2);
  k_bnfinal<256><<<1, 256, 0, stream>>>(sums2, sqs2, g2w, be2, bn_a2, bn_c2);

  // h4 = relu(bn2(h3))@lin3_w + b: K=256, f16-in+BN, stats, fp32-out, BM=128
  k_mgemm<256, 256, 7, 2, 4, 1, 4, true, true, true, false><<<782, 256, 0, stream>>>(
      h1, wt4, l3b, bn_a2, bn_c2, nullptr, h4, 100, sums3, sqs3);
  k_bnfinal<100><<<1, 128, 0, stream>>>(sums3, sqs3, g3, be3, bn_a3, bn_c3);

  k_final<<<25000, 256, 0, stream>>>(h4, bn_a3, bn_c3, l4w, l4b, out);
}

// Round 10
// 411.398 us; speedup vs baseline: 3.5338x; 1.0083x over previous
//
#include <hip/hip_runtime.h>

#define N_NODES 100000
#define N_EDGES 1600000

typedef _Float16 f16x8 __attribute__((ext_vector_type(8)));
typedef _Float16 f16x4 __attribute__((ext_vector_type(4)));
typedef float fx4 __attribute__((ext_vector_type(4)));

#define NREP 16     // stats-accumulator replication to de-contend atomics
#define NBUCK 196   // ceil(100000/512) buckets of 512 nodes
#define CHUNK 8192  // edges per k_bin block
#define BCAP 12288  // per-bucket slot capacity

// ---------------- CSR build, pass 1: LDS counting-sort chunks by bucket --------
__global__ __launch_bounds__(256) void k_bin(const int* __restrict__ ei,
                                             unsigned* __restrict__ binned,
                                             int* __restrict__ gcount) {
  __shared__ unsigned pr[CHUNK];
  __shared__ unsigned srt[CHUNK];
  __shared__ unsigned char bk[CHUNK];
  __shared__ int hist[256], scanb[256], offs[256], bs[256], gb[256];
  const int t = threadIdx.x;
  const int e0 = blockIdx.x * CHUNK;
  const int n = min(CHUNK, N_EDGES - e0);
  hist[t] = 0;
  __syncthreads();
  for (int i = t; i < n; i += 256) {
    int src = ei[e0 + i], dst = ei[N_EDGES + e0 + i];
    int b = dst >> 9;
    pr[i] = ((unsigned)src << 9) | (unsigned)(dst & 511);
    bk[i] = (unsigned char)b;
    atomicAdd(&hist[b], 1);
  }
  __syncthreads();
  int v = hist[t];
  scanb[t] = v;
  __syncthreads();
  for (int off = 1; off < 256; off <<= 1) {
    int a = (t >= off) ? scanb[t - off] : 0;
    __syncthreads();
    scanb[t] += a;
    __syncthreads();
  }
  offs[t] = scanb[t] - v;
  bs[t] = scanb[t] - v;
  __syncthreads();
  for (int i = t; i < n; i += 256) {
    int b = bk[i];
    int p = atomicAdd(&offs[b], 1);
    srt[p] = pr[i];
  }
  if (t < NBUCK && v > 0) gb[t] = atomicAdd(&gcount[t], v);
  __syncthreads();
  int wave = t >> 6, lane = t & 63;
  for (int b = wave; b < NBUCK; b += 4) {
    int c = hist[b];
    if (c == 0) continue;
    int ls = bs[b], base = gb[b];
    unsigned* dstp = binned + (size_t)b * BCAP + base;
    for (int i = lane; i < c; i += 64) dstp[i] = srt[ls + i];
  }
}

__global__ void k_bscan(const int* __restrict__ gcount, int* __restrict__ gbase) {
  __shared__ int s[256];
  int t = threadIdx.x;
  int v = (t < NBUCK) ? gcount[t] : 0;
  s[t] = v;
  __syncthreads();
  for (int off = 1; off < 256; off <<= 1) {
    int a = (t >= off) ? s[t - off] : 0;
    __syncthreads();
    s[t] += a;
    __syncthreads();
  }
  if (t < NBUCK) gbase[t] = s[t] - v;
}

__global__ __launch_bounds__(256) void k_csr(const unsigned* __restrict__ binned,
                                             const int* __restrict__ gcount,
                                             const int* __restrict__ gbase,
                                             int* __restrict__ rowoff,
                                             int* __restrict__ cnt,
                                             float* __restrict__ dinv,
                                             int* __restrict__ csr) {
  __shared__ int hist[512], offs[512], ps[256];
  __shared__ unsigned srt[BCAP];
  const int b = blockIdx.x, t = threadIdx.x;
  const int n = min(gcount[b], BCAP);
  const int gb0 = gbase[b];
  const unsigned* bp = binned + (size_t)b * BCAP;
  hist[t] = 0;
  hist[t + 256] = 0;
  __syncthreads();
  for (int i = t; i < n; i += 256) atomicAdd(&hist[bp[i] & 511], 1);
  __syncthreads();
  int e0v = hist[2 * t], e1v = hist[2 * t + 1];
  ps[t] = e0v + e1v;
  __syncthreads();
  for (int off = 1; off < 256; off <<= 1) {
    int a = (t >= off) ? ps[t - off] : 0;
    __syncthreads();
    ps[t] += a;
    __syncthreads();
  }
  int excl = ps[t] - (e0v + e1v);
  offs[2 * t] = excl;
  offs[2 * t + 1] = excl + e0v;
  __syncthreads();
#pragma unroll
  for (int u = 0; u < 2; ++u) {
    int j = 2 * t + u;
    int nd = (b << 9) + j;
    if (nd < N_NODES) {
      int c = hist[j];
      cnt[nd] = c;
      dinv[nd] = rsqrtf((float)(c + 1));
      rowoff[nd] = gb0 + offs[j];
    }
  }
  __syncthreads();
  for (int i = t; i < n; i += 256) {
    unsigned p = bp[i];
    int d = p & 511;
    int pos = atomicAdd(&offs[d], 1);
    srt[pos] = p >> 9;
  }
  __syncthreads();
  for (int i = t; i < n; i += 256) csr[gb0 + i] = (int)srt[i];
}

// ---------------- xs = dinv[i] * x[i], f16, padded [N,24] ----------------
__global__ void k_xpad(const float* __restrict__ x, const float* __restrict__ dinv,
                       _Float16* __restrict__ xs) {
  int idx = blockIdx.x * 256 + threadIdx.x;
  if (idx >= N_NODES * 24) return;
  int r = idx / 24, c = idx - r * 24;
  xs[idx] = (_Float16)((c < 21) ? x[r * 21 + c] * dinv[r] : 0.f);
}

// ---------------- conv1 aggregation: 3 lanes x f16x8 per row, 21 rows/wave ------
__global__ __launch_bounds__(256) void k_aggx(
    const f16x8* __restrict__ xs3, const float* __restrict__ dinv,
    const int* __restrict__ rowoff, const int* __restrict__ cnt,
    const int* __restrict__ csr, float* __restrict__ aggx) {
  int lane = threadIdx.x & 63, wave = threadIdx.x >> 6;
  int j = lane / 3, c = lane - j * 3;
  if (j >= 21) return;
  int i = blockIdx.x * 84 + wave * 21 + j;
  if (i >= N_NODES) return;
  float di = dinv[i];
  int start = rowoff[i], len = cnt[i];
  f16x8 u = xs3[i * 3 + c];
  float a0[8], a1[8], a2[8], a3[8];
#pragma unroll
  for (int t = 0; t < 8; ++t) { a0[t] = (float)u[t]; a1[t] = a2[t] = a3[t] = 0.f; }
  int e = 0;
  for (; e + 3 < len; e += 4) {
    int s0 = csr[start + e], s1 = csr[start + e + 1];
    int s2 = csr[start + e + 2], s3 = csr[start + e + 3];
    f16x8 u0 = xs3[s0 * 3 + c];
    f16x8 u1 = xs3[s1 * 3 + c];
    f16x8 u2 = xs3[s2 * 3 + c];
    f16x8 u3 = xs3[s3 * 3 + c];
#pragma unroll
    for (int t = 0; t < 8; ++t) {
      a0[t] += (float)u0[t]; a1[t] += (float)u1[t];
      a2[t] += (float)u2[t]; a3[t] += (float)u3[t];
    }
  }
  for (; e < len; ++e) {
    int s0 = csr[start + e];
    f16x8 u0 = xs3[s0 * 3 + c];
#pragma unroll
    for (int t = 0; t < 8; ++t) a0[t] += (float)u0[t];
  }
  float4 r0, r1;
  r0.x = di * (a0[0] + a1[0] + a2[0] + a3[0]);
  r0.y = di * (a0[1] + a1[1] + a2[1] + a3[1]);
  r0.z = di * (a0[2] + a1[2] + a2[2] + a3[2]);
  r0.w = di * (a0[3] + a1[3] + a2[3] + a3[3]);
  r1.x = di * (a0[4] + a1[4] + a2[4] + a3[4]);
  r1.y = di * (a0[5] + a1[5] + a2[5] + a3[5]);
  r1.z = di * (a0[6] + a1[6] + a2[6] + a3[6]);
  r1.w = di * (a0[7] + a1[7] + a2[7] + a3[7]);
  *(float4*)(aggx + (size_t)i * 24 + c * 8) = r0;
  *(float4*)(aggx + (size_t)i * 24 + c * 8 + 4) = r1;
}

// ---------------- gemm1: h1 = relu(aggx @ W1 + b1), f16 out ----------------
__global__ __launch_bounds__(256) void k_gemm1(const float4* __restrict__ aggx4,
                                               const float* __restrict__ W1,
                                               const float* __restrict__ b1,
                                               _Float16* __restrict__ h1) {
  __shared__ float As[32][24];
  int t = threadIdx.x;
  int base = blockIdx.x * 32;
  for (int idx = t; idx < 32 * 6; idx += 256) {
    int m = idx / 6, q = idx - m * 6;
    *(float4*)(&As[m][q * 4]) = aggx4[(base + m) * 6 + q];
  }
  float w[21];
#pragma unroll
  for (int k = 0; k < 21; ++k) w[k] = W1[k * 256 + t];
  float bias = b1[t];
  __syncthreads();
  for (int m = 0; m < 32; ++m) {
    float acc = bias;
#pragma unroll
    for (int k = 0; k < 21; ++k) acc = fmaf(As[m][k], w[k], acc);
    h1[(size_t)(base + m) * 256 + t] = (_Float16)fmaxf(acc, 0.f);
  }
}

// ---------------- W prep: transpose + f16 ----------------
template <int K, int KPAD, int NOUT, int NR>
__global__ void k_wcvt(const float* __restrict__ W, _Float16* __restrict__ Wh) {
  int idx = blockIdx.x * 256 + threadIdx.x;
  if (idx >= NR * KPAD) return;
  int n = idx / KPAD, k = idx % KPAD;
  float v = (n < NOUT && k < K) ? W[k * NOUT + n] : 0.f;
  Wh[idx] = (_Float16)v;
}

// ---------------- MFMA GEMM, operand-swapped, f16, A-prefetch pipeline ----------
// SPLIT: f16 output routed to two [N,64] arrays (ch 0-55 -> Cv, 56-111 -> Cv2),
// rows 128 B line-aligned for the conv2 gather.
template <int K, int KPAD, int NT, int MT, int WR, int WC, int MINW,
          bool BN, bool STATS, bool F16IN, bool F16OUT, bool SPLIT>
__global__ __launch_bounds__(256, MINW) void k_mgemm(
    const void* __restrict__ Av, const _Float16* __restrict__ Wt,
    const float* __restrict__ bias, const float* __restrict__ bn_a,
    const float* __restrict__ bn_c, const float* __restrict__ rowscale,
    void* __restrict__ Cv, void* __restrict__ Cv2, int NOUTr,
    float* __restrict__ sums, float* __restrict__ sqs) {
  constexpr int BM = WR * MT * 16;
  constexpr int NR = WC * NT * 16;
  constexpr int BKP = 40;
  constexpr int NC = KPAD / 32;
  constexpr int AIT = BM * 4 / 256;
  constexpr int ABYTES = BM * BKP * 2;
  constexpr int BBYTES = NR * BKP * 2;
  __shared__ __align__(16) char smem[ABYTES + BBYTES];
  _Float16* Ah = (_Float16*)smem;
  _Float16* Bh = (_Float16*)(smem + ABYTES);
  const float* A32 = (const float*)Av;
  const _Float16* A16 = (const _Float16*)Av;
  float* C = (float*)Cv;
  _Float16* C16 = (_Float16*)Cv;
  _Float16* C16b = (_Float16*)Cv2;

  const int tid = threadIdx.x;
  const int lane = tid & 63, wave = tid >> 6;
  const int wr = wave % WR, wc = wave / WR;
  const int quad = lane >> 4, ln = lane & 15;
  const int rowbase = blockIdx.x * BM;

  fx4 acc[MT][NT];
#pragma unroll
  for (int mt = 0; mt < MT; ++mt)
#pragma unroll
    for (int j = 0; j < NT; ++j) acc[mt][j] = (fx4){0.f, 0.f, 0.f, 0.f};

  f16x8 pf16[AIT];
  fx4 pf32a[AIT], pf32b[AIT];

  auto loadA = [&](int kc) {
#pragma unroll
    for (int it = 0; it < AIT; ++it) {
      int idx = tid + it * 256;
      int m = idx >> 2, q = idx & 3;
      int gi = rowbase + m;
      int k = kc * 32 + q * 8;
      bool ok = (gi < N_NODES) && (k < K);
      if constexpr (F16IN) {
        f16x8 z;
#pragma unroll
        for (int t = 0; t < 8; ++t) z[t] = (_Float16)0;
        pf16[it] = ok ? *(const f16x8*)(A16 + (size_t)gi * K + k) : z;
      } else {
        if (ok) {
          pf32a[it] = *(const fx4*)(A32 + (size_t)gi * K + k);
          pf32b[it] = *(const fx4*)(A32 + (size_t)gi * K + k + 4);
        } else {
          pf32a[it] = (fx4){0.f, 0.f, 0.f, 0.f};
          pf32b[it] = (fx4){0.f, 0.f, 0.f, 0.f};
        }
      }
    }
  };

  auto writeA = [&](int kc) {
#pragma unroll
    for (int it = 0; it < AIT; ++it) {
      int idx = tid + it * 256;
      int m = idx >> 2, q = idx & 3;
      int k = kc * 32 + q * 8;
      float vv[8];
      if constexpr (F16IN) {
#pragma unroll
        for (int t = 0; t < 8; ++t) vv[t] = (float)pf16[it][t];
      } else {
#pragma unroll
        for (int t = 0; t < 4; ++t) { vv[t] = pf32a[it][t]; vv[t + 4] = pf32b[it][t]; }
      }
      if constexpr (BN) {
        if (k < K) {
          float4 a0 = *(const float4*)(bn_a + k);
          float4 a1 = *(const float4*)(bn_a + k + 4);
          float4 c0 = *(const float4*)(bn_c + k);
          float4 c1 = *(const float4*)(bn_c + k + 4);
          float av[8] = {a0.x, a0.y, a0.z, a0.w, a1.x, a1.y, a1.z, a1.w};
          float cv[8] = {c0.x, c0.y, c0.z, c0.w, c1.x, c1.y, c1.z, c1.w};
#pragma unroll
          for (int t = 0; t < 8; ++t) vv[t] = fmaxf(fmaf(vv[t], av[t], cv[t]), 0.f);
        }
      }
      f16x8 hv;
#pragma unroll
      for (int t = 0; t < 8; ++t) hv[t] = (_Float16)vv[t];
      *(f16x8*)(Ah + m * BKP + q * 8) = hv;
    }
  };

  loadA(0);
  for (int kc = 0; kc < NC; ++kc) {
    __syncthreads();
    writeA(kc);
    for (int idx = tid; idx < NR * 4; idx += 256) {
      int n = idx >> 2, p = idx & 3;
      *(f16x8*)(Bh + n * BKP + p * 8) =
          *(const f16x8*)(Wt + n * KPAD + kc * 32 + p * 8);
    }
    __syncthreads();
    if (kc + 1 < NC) loadA(kc + 1);
    f16x8 nf[MT];
#pragma unroll
    for (int mt = 0; mt < MT; ++mt) {
      int r = (wr * MT + mt) * 16 + ln;
      nf[mt] = *(const f16x8*)(Ah + r * BKP + quad * 8);
    }
#pragma unroll
    for (int j = 0; j < NT; ++j) {
      int n = (wc * NT + j) * 16 + ln;
      f16x8 wh = *(const f16x8*)(Bh + n * BKP + quad * 8);
#pragma unroll
      for (int mt = 0; mt < MT; ++mt)
        acc[mt][j] = __builtin_amdgcn_mfma_f32_16x16x32_f16(wh, nf[mt], acc[mt][j], 0, 0, 0);
    }
  }

  float* s_s = (float*)smem;
  float* s_q = s_s + NR;
  __syncthreads();
  if constexpr (STATS) {
    for (int c = tid; c < 2 * NR; c += 256) s_s[c] = 0.f;
    __syncthreads();
  }
  float rs[MT];
#pragma unroll
  for (int mt = 0; mt < MT; ++mt) {
    int nd = rowbase + (wr * MT + mt) * 16 + ln;
    rs[mt] = (rowscale != nullptr && nd < N_NODES) ? rowscale[nd] : 1.f;
  }
#pragma unroll
  for (int j = 0; j < NT; ++j) {
    int ch0 = (wc * NT + j) * 16 + quad * 4;
    bool cv = ch0 < NOUTr;
    float4 b4 = make_float4(0.f, 0.f, 0.f, 0.f);
    if (cv && bias != nullptr) b4 = *(const float4*)(bias + ch0);
    float sc[4] = {0.f, 0.f, 0.f, 0.f}, sq[4] = {0.f, 0.f, 0.f, 0.f};
#pragma unroll
    for (int mt = 0; mt < MT; ++mt) {
      int nd = rowbase + (wr * MT + mt) * 16 + ln;
      if (nd < N_NODES && cv) {
        float v0 = (acc[mt][j][0] + b4.x) * rs[mt];
        float v1 = (acc[mt][j][1] + b4.y) * rs[mt];
        float v2 = (acc[mt][j][2] + b4.z) * rs[mt];
        float v3 = (acc[mt][j][3] + b4.w) * rs[mt];
        if constexpr (F16OUT) {
          f16x4 o = {(_Float16)v0, (_Float16)v1, (_Float16)v2, (_Float16)v3};
          if constexpr (SPLIT) {
            _Float16* dp = (ch0 < 56)
                ? C16 + (size_t)nd * 64 + ch0
                : C16b + (size_t)nd * 64 + (ch0 - 56);
            *(f16x4*)dp = o;
          } else {
            *(f16x4*)(C16 + (size_t)nd * NOUTr + ch0) = o;
          }
        } else {
          float4 o = make_float4(v0, v1, v2, v3);
          *(float4*)(C + (size_t)nd * NOUTr + ch0) = o;
        }
        if constexpr (STATS) {
          sc[0] += v0; sq[0] = fmaf(v0, v0, sq[0]);
          sc[1] += v1; sq[1] = fmaf(v1, v1, sq[1]);
          sc[2] += v2; sq[2] = fmaf(v2, v2, sq[2]);
          sc[3] += v3; sq[3] = fmaf(v3, v3, sq[3]);
        }
      }
    }
    if constexpr (STATS) {
      if (cv) {
#pragma unroll
        for (int r = 0; r < 4; ++r) {
          float s = sc[r], q = sq[r];
          s += __shfl_xor(s, 1); q += __shfl_xor(q, 1);
          s += __shfl_xor(s, 2); q += __shfl_xor(q, 2);
          s += __shfl_xor(s, 4); q += __shfl_xor(q, 4);
          s += __shfl_xor(s, 8); q += __shfl_xor(q, 8);
          if (ln == 0) {
            atomicAdd(&s_s[ch0 + r], s);
            atomicAdd(&s_q[ch0 + r], q);
          }
        }
      }
    }
  }
  if constexpr (STATS) {
    __syncthreads();
    int rep = (blockIdx.x & (NREP - 1));
    for (int c = tid; c < NR; c += 256) {
      if (c < NOUTr) {
        atomicAdd(&sums[rep * NOUTr + c], s_s[c]);
        atomicAdd(&sqs[rep * NOUTr + c], s_q[c]);
      }
    }
  }
}

// ---------------- conv2 aggregation, half-channel pass ----------------
// Source = one split array [N,64] f16 (128 B aligned rows -> 1 L2 line/gather).
// 8 lanes x f16x8 per row, 8 rows/wave (full 64 lanes). Lane c==7 reads pad
// (same cache line, no extra traffic) and skips the store.
__global__ __launch_bounds__(256) void k_agg2(
    const f16x8* __restrict__ t2x8, const float* __restrict__ dinv,
    const int* __restrict__ rowoff, const int* __restrict__ cnt,
    const int* __restrict__ csr, const float* __restrict__ b2,
    _Float16* __restrict__ g2, int off) {
  int lane = threadIdx.x & 63, wave = threadIdx.x >> 6;
  int j = lane >> 3, c = lane & 7;
  int i = blockIdx.x * 32 + wave * 8 + j;      // 3125*32 == 100000 exactly
  float di = dinv[i];
  int start = rowoff[i], len = cnt[i];
  f16x8 u = t2x8[i * 8 + c];                   // self-loop term
  float a0[8], a1[8], a2[8], a3[8];
#pragma unroll
  for (int t = 0; t < 8; ++t) { a0[t] = (float)u[t]; a1[t] = a2[t] = a3[t] = 0.f; }
  int e = 0;
  for (; e + 3 < len; e += 4) {
    int s0 = csr[start + e], s1 = csr[start + e + 1];
    int s2 = csr[start + e + 2], s3 = csr[start + e + 3];
    f16x8 u0 = t2x8[s0 * 8 + c];
    f16x8 u1 = t2x8[s1 * 8 + c];
    f16x8 u2 = t2x8[s2 * 8 + c];
    f16x8 u3 = t2x8[s3 * 8 + c];
#pragma unroll
    for (int t = 0; t < 8; ++t) {
      a0[t] += (float)u0[t]; a1[t] += (float)u1[t];
      a2[t] += (float)u2[t]; a3[t] += (float)u3[t];
    }
  }
  for (; e < len; ++e) {
    int s0 = csr[start + e];
    f16x8 u0 = t2x8[s0 * 8 + c];
#pragma unroll
    for (int t = 0; t < 8; ++t) a0[t] += (float)u0[t];
  }
  if (c < 7) {
    float4 blo = *(const float4*)(b2 + off + c * 8);
    float4 bhi = *(const float4*)(b2 + off + c * 8 + 4);
    float bb[8] = {blo.x, blo.y, blo.z, blo.w, bhi.x, bhi.y, bhi.z, bhi.w};
    f16x8 o;
#pragma unroll
    for (int t = 0; t < 8; ++t)
      o[t] = (_Float16)fmaf(di, a0[t] + a1[t] + a2[t] + a3[t], bb[t]);
    *(f16x8*)(g2 + (size_t)i * 112 + off + c * 8) = o;
  }
}

// ---------------- BN column stats (f16 input, for g2) ----------------
template <int C>
__global__ void k_colstats16(const _Float16* __restrict__ X, float* __restrict__ sums,
                             float* __restrict__ sqs) {
  int c = threadIdx.x;
  if (c >= C) return;
  int chunk = (N_NODES + gridDim.x - 1) / gridDim.x;
  int i0 = blockIdx.x * chunk;
  int i1 = min(N_NODES, i0 + chunk);
  float s = 0.f, q = 0.f;
  for (int i = i0; i < i1; ++i) {
    float v = (float)X[(size_t)i * C + c];
    s += v;
    q = fmaf(v, v, q);
  }
  int rep = (blockIdx.x & (NREP - 1));
  atomicAdd(&sums[rep * C + c], s);
  atomicAdd(&sqs[rep * C + c], q);
}

template <int C>
__global__ void k_bnfinal(const float* __restrict__ sums, const float* __restrict__ sqs,
                          const float* __restrict__ gamma, const float* __restrict__ beta,
                          float* __restrict__ bn_a, float* __restrict__ bn_c) {
  int c = threadIdx.x;
  if (c >= C) return;
  float s = 0.f, q = 0.f;
#pragma unroll
  for (int r = 0; r < NREP; ++r) {
    s += sums[r * C + c];
    q += sqs[r * C + c];
  }
  const float inv_n = 1.0f / (float)N_NODES;
  float mean = s * inv_n;
  float var = fmaxf(q * inv_n - mean * mean, 0.f);
  float rstd = 1.0f / sqrtf(var + 1e-5f);
  float a = gamma[c] * rstd;
  bn_a[c] = a;
  bn_c[c] = beta[c] - mean * a;
}

// ---------------- final ----------------
__global__ void k_final(const float* __restrict__ h4, const float* __restrict__ bn_a,
                        const float* __restrict__ bn_c, const float* __restrict__ w4,
                        const float* __restrict__ b4, float* __restrict__ out) {
  int lane = threadIdx.x & 63;
  int i = blockIdx.x * 4 + (threadIdx.x >> 6);
  float acc = fmaxf(fmaf(h4[(size_t)i * 100 + lane], bn_a[lane], bn_c[lane]), 0.f) * w4[lane];
  if (lane < 36) {
    int k = lane + 64;
    acc += fmaxf(fmaf(h4[(size_t)i * 100 + k], bn_a[k], bn_c[k]), 0.f) * w4[k];
  }
#pragma unroll
  for (int off = 32; off >= 1; off >>= 1) acc += __shfl_down(acc, off);
  if (lane == 0) out[i] = acc + b4[0];
}

extern "C" void kernel_launch(void* const* d_in, const int* in_sizes, int n_in,
                              void* d_out, int out_size, void* d_ws, size_t ws_size,
                              hipStream_t stream) {
  const float* x   = (const float*)d_in[0];
  const int*   ei  = (const int*)d_in[1];
  const float* W1  = (const float*)d_in[2];
  const float* b1  = (const float*)d_in[3];
  const float* W2  = (const float*)d_in[4];
  const float* b2  = (const float*)d_in[5];
  const float* l2w = (const float*)d_in[6];
  const float* l2b = (const float*)d_in[7];
  const float* l3w = (const float*)d_in[8];
  const float* l3b = (const float*)d_in[9];
  const float* l4w = (const float*)d_in[10];
  const float* l4b = (const float*)d_in[11];
  const float* g1  = (const float*)d_in[12];
  const float* be1 = (const float*)d_in[13];
  const float* g2w = (const float*)d_in[14];
  const float* be2 = (const float*)d_in[15];
  const float* g3  = (const float*)d_in[16];
  const float* be3 = (const float*)d_in[17];
  float* out = (float*)d_out;

  char* base = (char*)d_ws;
  size_t off = 0;
  auto alloc = [&](size_t bytes) -> char* {
    char* p = base + off;
    off = (off + bytes + 255) & ~(size_t)255;
    return p;
  };
  int*   cnt    = (int*)alloc((size_t)N_NODES * 4);
  int*   rowoff = (int*)alloc((size_t)N_NODES * 4);
  float* dinv   = (float*)alloc((size_t)N_NODES * 4);
  int*   csr    = (int*)alloc((size_t)N_EDGES * 4);
  unsigned* binned = (unsigned*)alloc((size_t)NBUCK * BCAP * 4);
  int*   gcount = (int*)alloc(NBUCK * 4);
  int*   gbase  = (int*)alloc(NBUCK * 4);
  float* stats  = (float*)alloc((size_t)NREP * 960 * 4);
  float* bnco   = (float*)alloc(960 * 4);
  _Float16* xs  = (_Float16*)alloc((size_t)N_NODES * 24 * 2);
  float* aggx   = (float*)alloc((size_t)N_NODES * 24 * 4);
  _Float16* h1  = (_Float16*)alloc((size_t)N_NODES * 256 * 2);  // f16; reused as h3
  _Float16* t2a = (_Float16*)alloc((size_t)N_NODES * 64 * 2);   // split ch 0-55 (+pad)
  _Float16* t2b = (_Float16*)alloc((size_t)N_NODES * 64 * 2);   // split ch 56-111 (+pad)
  _Float16* g2h = (_Float16*)alloc((size_t)N_NODES * 112 * 2);  // f16 conv2 output
  float* h4     = (float*)alloc((size_t)N_NODES * 112 * 4);
  _Float16* wt2 = (_Float16*)alloc(112 * 256 * 2);
  _Float16* wt3 = (_Float16*)alloc(256 * 128 * 2);
  _Float16* wt4 = (_Float16*)alloc(112 * 256 * 2);

  float* sums1 = stats;
  float* sqs1  = sums1 + NREP * 112;
  float* sums2 = sqs1 + NREP * 112;
  float* sqs2  = sums2 + NREP * 256;
  float* sums3 = sqs2 + NREP * 256;
  float* sqs3  = sums3 + NREP * 112;
  float* bn_a1 = bnco + 0,   *bn_c1 = bnco + 112;
  float* bn_a2 = bnco + 224, *bn_c2 = bnco + 480;
  float* bn_a3 = bnco + 736, *bn_c3 = bnco + 848;

  hipMemsetAsync(gcount, 0, NBUCK * 4, stream);
  hipMemsetAsync(stats, 0, (size_t)NREP * 960 * 4, stream);

  k_bin<<<NBUCK, 256, 0, stream>>>(ei, binned, gcount);
  k_bscan<<<1, 256, 0, stream>>>(gcount, gbase);
  k_csr<<<NBUCK, 256, 0, stream>>>(binned, gcount, gbase, rowoff, cnt, dinv, csr);

  k_wcvt<256, 256, 112, 112><<<112, 256, 0, stream>>>(W2, wt2);
  k_wcvt<112, 128, 256, 256><<<128, 256, 0, stream>>>(l2w, wt3);
  k_wcvt<256, 256, 100, 112><<<112, 256, 0, stream>>>(l3w, wt4);

  k_xpad<<<(N_NODES * 24 + 255) / 256, 256, 0, stream>>>(x, dinv, xs);
  k_aggx<<<(N_NODES + 83) / 84, 256, 0, stream>>>((const f16x8*)xs, dinv, rowoff,
                                                  cnt, csr, aggx);
  k_gemm1<<<3125, 256, 0, stream>>>((const float4*)aggx, W1, b1, h1);

  // t2 = dinv*(h1@W2), f16 split to t2a/t2b [N,64] (128 B aligned rows)
  k_mgemm<256, 256, 7, 2, 4, 1, 4, false, false, true, true, true>
      <<<782, 256, 0, stream>>>(h1, wt2, nullptr, nullptr, nullptr, dinv,
                                t2a, t2b, 112, nullptr, nullptr);
  k_agg2<<<3125, 256, 0, stream>>>((const f16x8*)t2a, dinv, rowoff, cnt, csr, b2,
                                   g2h, 0);
  k_agg2<<<3125, 256, 0, stream>>>((const f16x8*)t2b, dinv, rowoff, cnt, csr, b2,
                                   g2h, 56);

  k_colstats16<112><<<1600, 128, 0, stream>>>(g2h, sums1, sqs1);
  k_bnfinal<112><<<1, 128, 0, stream>>>(sums1, sqs1, g1, be1, bn_a1, bn_c1);

  // h3 = relu(bn1(g2))@lin2_w + b: K=112, f16-in+BN, stats, f16-out -> h1 buffer
  k_mgemm<112, 128, 8, 2, 2, 2, 4, true, true, true, true, false>
      <<<1563, 256, 0, stream>>>(g2h, wt3, l2b, bn_a1, bn_c1, nullptr,
                                 h1, nullptr, 256, sums2, sqs2);
  k_bnfinal<256><<<1, 256, 0, stream>>>(sums2, sqs2, g2w, be2, bn_a2, bn_c2);

  // h4 = relu(bn2(h3))@lin3_w + b: K=256, f16-in+BN, stats, fp32-out
  k_mgemm<256, 256, 7, 2, 4, 1, 4, true, true, true, false, false>
      <<<782, 256, 0, stream>>>(h1, wt4, l3b, bn_a2, bn_c2, nullptr,
                                h4, nullptr, 100, sums3, sqs3);
  k_bnfinal<100><<<1, 128, 0, stream>>>(sums3, sqs3, g3, be3, bn_a3, bn_c3);

  k_final<<<25000, 256, 0, stream>>>(h4, bn_a3, bn_c3, l4w, l4b, out);
}